// Round 16
// baseline (304.156 us; speedup 1.0000x reference)
//
#include <hip/hip_runtime.h>
#include <cmath>

// Problem constants (fixed by the reference file)
#define B_   8
#define N_   512
#define D_   1024
#define H_   16
#define HD_  64
#define NI_  4
#define BN_  (B_*N_)      // 4096 rows when [B,N,*] is flattened
#define KVLEN (NI_*N_)    // 2048 keys per attention group

typedef __attribute__((ext_vector_type(8)))  short  bf16x8;   // 8 bf16 bit patterns
typedef __attribute__((ext_vector_type(8)))  __bf16 bf16x8_t; // builtin operand type
typedef __attribute__((ext_vector_type(16))) float  f32x16;
typedef __attribute__((ext_vector_type(4)))  short  s16x4;
typedef __attribute__((ext_vector_type(2)))  unsigned u32x2;

// round-to-nearest-even bf16 conversion (bit trick)
__device__ __forceinline__ short bf16_rn(float x) {
  unsigned u = __float_as_uint(x);
  unsigned r = (u + 0x7FFFu + ((u >> 16) & 1u)) >> 16;
  return (short)r;
}

// RN hi/lo split: x = hi + lo + eps, |eps| <~ 2^-18 |x|.
__device__ __forceinline__ void split2(float x, short& hi, short& lo) {
  hi = bf16_rn(x);
  float h = __uint_as_float(((unsigned)(unsigned short)hi) << 16);
  float r = x - h;              // exact (Dekker-style split)
  lo = bf16_rn(r);
}

__device__ __forceinline__ f32x16 mfma_bf16(bf16x8 a, bf16x8 b, f32x16 c) {
  return __builtin_amdgcn_mfma_f32_32x32x16_bf16(
      __builtin_bit_cast(bf16x8_t, a), __builtin_bit_cast(bf16x8_t, b), c, 0, 0, 0);
}

#define GLOAD16(gp, lp) __builtin_amdgcn_global_load_lds( \
  (const __attribute__((address_space(1))) unsigned*)(gp), \
  (__attribute__((address_space(3))) unsigned*)(lp), 16, 0, 0)

// TILED layout for all bf16 GEMM operands (K = 1024):
// addr(row,k) = (((row>>7)*128 + (k>>3))*128 + (row&127))*8 + (k&7).
// GEMM staging is then a LINEAR copy -> fully coalesced global_load_lds.
__device__ __forceinline__ long tiled_off(int row, int k) {
  return ((((long)(row >> 7) * 128 + (k >> 3)) * 128 + (row & 127)) * 8 + (k & 7));
}

// T1 XCD-aware block swizzle (MI355X: 8 XCDs, private L2s). Remap so each
// XCD gets a CONTIGUOUS tile range. REQUIRES nwg % 8 == 0.
__device__ __forceinline__ void xcd_swizzle(int& bx, int& by, int& bz) {
  const int gx = gridDim.x, gy = gridDim.y;
  const int nwg = gx * gy * gridDim.z;
  const int lin = blockIdx.x + gx * (blockIdx.y + gy * blockIdx.z);
  const int swz = (lin & 7) * (nwg >> 3) + (lin >> 3);
  bx = swz % gx;
  const int rest = swz / gx;
  by = rest % gy;
  bz = rest / gy;
}

// =====================================================================
// Weight prep: z=0..2 Wq/Wk/Wv -> QKVh (combined [3072][1024] tiled);
// z=3 Wo -> WoH. All hi-only bf16. (Wiq/Wik tiled forms are GONE —
// the gate path is now rank-5 algebra via fprep/hprep.)
// =====================================================================
__global__ __launch_bounds__(256) void wsplitAll(
    const float* __restrict__ Wq, const float* __restrict__ Wk,
    const float* __restrict__ Wv, const float* __restrict__ Wo,
    short* __restrict__ QKVh, short* __restrict__ WoH)
{
  __shared__ float tile[64][65];
  const int z = blockIdx.z;
  const float* W = (z == 0) ? Wq : (z == 1) ? Wk : (z == 2) ? Wv : Wo;
  const int t  = threadIdx.x;
  const int kb = blockIdx.y * 64;
  const int cb = blockIdx.x * 64;
  const int r0 = t >> 4;
  const int c4 = t & 15;
  #pragma unroll
  for (int i = 0; i < 4; i++) {
    const int r = r0 + i * 16;
    *(float4*)&tile[r][c4 * 4] = *(const float4*)&W[(long)(kb + r) * D_ + cb + c4 * 4];
  }
  __syncthreads();
  #pragma unroll
  for (int i = 0; i < 4; i++) {
    const int c = r0 + i * 16;
    short hi[4];
    #pragma unroll
    for (int e = 0; e < 4; e++)
      hi[e] = bf16_rn(tile[c4 * 4 + e][c]);
    if (z < 3)
      *(s16x4*)&QKVh[tiled_off(z * D_ + cb + c, kb + c4 * 4)] = *(s16x4*)hi;
    else
      *(s16x4*)&WoH[tiled_off(cb + c, kb + c4 * 4)] = *(s16x4*)hi;
  }
}

// =====================================================================
// Gate-path prep A: F4[j][d] = sum_e emb[j][e] * Wik[e][d]  (j=0..3).
// inst_feat = mask@emb is rank-4, so ik = mask@F4 + bik — the whole
// ik GEMM collapses to this 8.4 MFLOP product. grid 4 x 256.
// =====================================================================
__global__ __launch_bounds__(256) void fprep(
    const float* __restrict__ Wik, const float* __restrict__ emb,
    float* __restrict__ F4)
{
  const int d = blockIdx.x * 256 + threadIdx.x;
  float s0 = 0, s1 = 0, s2 = 0, s3 = 0;
  for (int e = 0; e < D_; e++) {
    const float w = Wik[(long)e * D_ + d];
    s0 = fmaf(emb[e], w, s0);
    s1 = fmaf(emb[D_ + e], w, s1);
    s2 = fmaf(emb[2 * D_ + e], w, s2);
    s3 = fmaf(emb[3 * D_ + e], w, s3);
  }
  F4[d] = s0;  F4[D_ + d] = s1;  F4[2 * D_ + d] = s2;  F4[3 * D_ + d] = s3;
}

// =====================================================================
// Gate-path prep B: H5[d][j] = sum_e Wiq[d][e]*F4[j][e] (j<4);
// H5[d][4] = Wiq[d]·bik. Consts row H5[1024][j] = F4[j]·biq (j<4),
// H5[1024][4] = biq·bik.  Then z[n,m] = (o[n]@H5[:,0:4]+cb)·mask[m]
// + (o[n]@H5[:,4]+c0): the iq GEMM and z GEMM both collapse into a
// [4096x1024]@[1024x5] skinny product (gproj). grid 5 blocks.
// =====================================================================
__global__ __launch_bounds__(256) void hprep(
    const float* __restrict__ Wiq, const float* __restrict__ F4,
    const float* __restrict__ bik, const float* __restrict__ biq,
    float* __restrict__ H5)
{
  const int t = threadIdx.x;
  if (blockIdx.x < 4) {
    const int d = blockIdx.x * 256 + t;
    float s0 = 0, s1 = 0, s2 = 0, s3 = 0, s4 = 0;
    const float* wr = Wiq + (long)d * D_;
    for (int e = 0; e < D_; e++) {
      const float w = wr[e];
      s0 = fmaf(w, F4[e], s0);
      s1 = fmaf(w, F4[D_ + e], s1);
      s2 = fmaf(w, F4[2 * D_ + e], s2);
      s3 = fmaf(w, F4[3 * D_ + e], s3);
      s4 = fmaf(w, bik[e], s4);
    }
    float* h = &H5[(long)d * 5];
    h[0] = s0; h[1] = s1; h[2] = s2; h[3] = s3; h[4] = s4;
  } else {
    __shared__ float red[256][5];
    float s0 = 0, s1 = 0, s2 = 0, s3 = 0, s4 = 0;
    for (int e = t; e < D_; e += 256) {
      const float b = biq[e];
      s0 = fmaf(b, F4[e], s0);
      s1 = fmaf(b, F4[D_ + e], s1);
      s2 = fmaf(b, F4[2 * D_ + e], s2);
      s3 = fmaf(b, F4[3 * D_ + e], s3);
      s4 = fmaf(b, bik[e], s4);
    }
    red[t][0] = s0; red[t][1] = s1; red[t][2] = s2; red[t][3] = s3; red[t][4] = s4;
    __syncthreads();
    for (int stride = 128; stride > 0; stride >>= 1) {
      if (t < stride)
        #pragma unroll
        for (int j = 0; j < 5; j++) red[t][j] += red[t + stride][j];
      __syncthreads();
    }
    if (t < 5) H5[5120 + t] = red[0][t];
  }
}

// =====================================================================
// Elementwise fp32 -> tiled bf16 (hi only — QKV is plain bf16).
// =====================================================================
__global__ __launch_bounds__(256) void asplit(const float* __restrict__ in,
                                              short* __restrict__ hi)
{
  const long i4 = ((long)blockIdx.x * 256 + threadIdx.x) * 4;
  const int row = (int)(i4 >> 10);
  const int kk  = (int)(i4 & 1023);
  float4 v = *(const float4*)&in[i4];
  short h[4];
  h[0] = bf16_rn(v.x);
  h[1] = bf16_rn(v.y);
  h[2] = bf16_rn(v.z);
  h[3] = bf16_rn(v.w);
  *(s16x4*)&hi[tiled_off(row, kk)] = *(s16x4*)h;
}

// =====================================================================
// MFMA GEMM v6. Tiled bf16 operands, linear global_load_lds staging,
// double-buffered LDS, counted vmcnt, XCD-swizzled blocks.
// SPLIT=2: A hi/lo, B hi (2 MFMAs/pair); waves 0-2 stage {Ahi,Alo,Bhi},
//          wave 3 idle, vmcnt(8). 48 KB LDS.
// SPLIT=0: plain bf16 (1 MFMA/pair); waves 0,1 stage A halves, waves
//          2,3 stage B halves, vmcnt(4). 32 KB LDS.
// MODE 0: C[bz*sC + row*D + col] = A@B + bias(bz)     (QKV fused)
// MODE 2: C = gate[row]*(A@B) + bias                  (final, SPLIT=2)
// =====================================================================
template<int MODE, int SPLIT>
__global__ __launch_bounds__(256) void mfgemm2(
    const short* __restrict__ Ahi, const short* __restrict__ Alo,
    const short* __restrict__ Bhi,
    const float* __restrict__ b0, const float* __restrict__ b1,
    const float* __restrict__ b2,
    float* __restrict__ C, int bBlk, long sC,
    const float* __restrict__ gate_in)
{
  constexpr int NOPS = (SPLIT == 2) ? 3 : 2;
  __shared__ short lds[2][NOPS][4096];
  const int t = threadIdx.x, w = t >> 6, lane = t & 63;
  int bx, by, bz;
  xcd_swizzle(bx, by, bz);
  const int rowBase = by * 128;
  const int colBase = bx * 128;
  const long aoff = (long)by * 131072;   // 128 oct * 128 rows * 8
  const long boff = (long)(bz * bBlk + bx) * 131072;

  const short* mySrc;
  int op, half;
  if (SPLIT == 2) {
    op = (w < 3) ? w : 0; half = 0;
    mySrc = (w == 0) ? Ahi + aoff : (w == 1) ? Alo + aoff : Bhi + boff;
  } else {
    op = w >> 1; half = w & 1;
    mySrc = op ? Bhi + boff : Ahi + aoff;
  }

  auto stage = [&](int buf, int tt) {
    if (SPLIT == 2) {
      if (w == 3) return;   // 3 operands, wave 3 idle
      const short* g = mySrc + ((long)tt * 512 + lane) * 8;
      #pragma unroll
      for (int i = 0; i < 8; i++)
        GLOAD16(g + i * 512, &lds[buf][op][i * 512]);
    } else {
      const short* g = mySrc + ((long)tt * 512 + half * 256 + lane) * 8;
      #pragma unroll
      for (int i = 0; i < 4; i++)
        GLOAD16(g + i * 512, &lds[buf][op][(half * 256 + i * 64) * 8]);
    }
  };

  const int wr = w >> 1, wc = w & 1;
  const int lrow = lane & 31, lk = lane >> 5;

  f32x16 acc[2][2] = {};

  auto compute = [&](int buf) {
    #pragma unroll
    for (int kh = 0; kh < 2; kh++) {
      const int kq = 2 * kh + lk;
      bf16x8 ah[2], bh[2];
      #pragma unroll
      for (int m = 0; m < 2; m++)
        ah[m] = *(const bf16x8*)&lds[buf][0][(kq * 128 + wr * 64 + m * 32 + lrow) * 8];
      #pragma unroll
      for (int n = 0; n < 2; n++)
        bh[n] = *(const bf16x8*)&lds[buf][(SPLIT == 2) ? 2 : 1][(kq * 128 + wc * 64 + n * 32 + lrow) * 8];
      if (SPLIT == 2) {
        bf16x8 al[2];
        #pragma unroll
        for (int m = 0; m < 2; m++)
          al[m] = *(const bf16x8*)&lds[buf][1][(kq * 128 + wr * 64 + m * 32 + lrow) * 8];
        #pragma unroll
        for (int m = 0; m < 2; m++)
          #pragma unroll
          for (int n = 0; n < 2; n++) {
            acc[m][n] = mfma_bf16(al[m], bh[n], acc[m][n]);
            acc[m][n] = mfma_bf16(ah[m], bh[n], acc[m][n]);
          }
      } else {
        #pragma unroll
        for (int m = 0; m < 2; m++)
          #pragma unroll
          for (int n = 0; n < 2; n++)
            acc[m][n] = mfma_bf16(ah[m], bh[n], acc[m][n]);
      }
    }
  };

  const int NT = 32;   // K=1024 / BK=32
  stage(0, 0);
  for (int tt = 0; tt < NT - 1; ++tt) {
    stage((tt + 1) & 1, tt + 1);
    if (SPLIT == 2) asm volatile("s_waitcnt vmcnt(8)" ::: "memory");
    else            asm volatile("s_waitcnt vmcnt(4)" ::: "memory");
    __builtin_amdgcn_s_barrier();
    __builtin_amdgcn_sched_barrier(0);
    compute(tt & 1);
    __builtin_amdgcn_s_barrier();
  }
  asm volatile("s_waitcnt vmcnt(0)" ::: "memory");
  __builtin_amdgcn_s_barrier();
  __builtin_amdgcn_sched_barrier(0);
  compute((NT - 1) & 1);

  // ---------------- epilogue ----------------
  const float* bias = (bz == 1) ? b1 : (bz == 2) ? b2 : b0;
  float bcol[2];
  #pragma unroll
  for (int n = 0; n < 2; n++)
    bcol[n] = bias[colBase + wc * 64 + n * 32 + lrow];

  float* Cb = C + (long)bz * sC;

  #pragma unroll
  for (int m = 0; m < 2; m++) {
    #pragma unroll
    for (int r = 0; r < 16; r++) {
      const int row = rowBase + wr * 64 + m * 32 + (r & 3) + 8 * (r >> 2) + 4 * lk;
      float g = 1.f;
      if (MODE == 2) g = gate_in[row];
      #pragma unroll
      for (int n = 0; n < 2; n++) {
        const int col = colBase + wc * 64 + n * 32 + lrow;
        Cb[(long)row * D_ + col] = acc[m][n][r] * g + bcol[n];
      }
    }
  }
}

// =====================================================================
// KV prep: K RMSNorm->bf16 swizzled [g][h][m][64]; V transposed bf16
// tiles [g][h][tile][d][32kv], chunk-swizzled. Both linear per 4KB tile
// for coalesced global_load_lds in attention.
// =====================================================================
__global__ __launch_bounds__(256) void kvprep(
    const float* __restrict__ kf, const float* __restrict__ vf,
    const float* __restrict__ knw, short* __restrict__ Knb,
    short* __restrict__ Vtb)
{
  const int tile = blockIdx.x, h = blockIdx.y, g = blockIdx.z;
  const int t = threadIdx.x;
  // ---- K ----
  const int skv = t >> 3, sg = t & 7;
  const int m  = tile * 32 + skv;
  const int bb = g * NI_ + (m >> 9), nn = m & (N_ - 1);
  const float* kp = kf + ((long)(bb * N_ + nn)) * D_ + h * HD_ + sg * 8;
  float k8[8];
  *(float4*)&k8[0] = *(const float4*)&kp[0];
  *(float4*)&k8[4] = *(const float4*)&kp[4];
  float ks2 = 0.f;
  #pragma unroll
  for (int j = 0; j < 8; j++) ks2 += k8[j] * k8[j];
  ks2 += __shfl_xor(ks2, 1);
  ks2 += __shfl_xor(ks2, 2);
  ks2 += __shfl_xor(ks2, 4);
  const float kr = rsqrtf(ks2 * (1.f / 64.f) + 1e-6f);
  bf16x8 kb;
  #pragma unroll
  for (int j = 0; j < 8; j++) kb[j] = bf16_rn(k8[j] * kr * knw[sg * 8 + j]);
  *(bf16x8*)&Knb[((long)(g * H_ + h) * KVLEN + m) * 64 + ((sg ^ (m & 7)) * 8)] = kb;
  // ---- V ----
  const int vkv = t & 31, vg = t >> 5;
  const int m2  = tile * 32 + vkv;
  const int bb2 = g * NI_ + (m2 >> 9), nn2 = m2 & (N_ - 1);
  const float* vp = vf + ((long)(bb2 * N_ + nn2)) * D_ + h * HD_ + vg * 8;
  float v8[8];
  *(float4*)&v8[0] = *(const float4*)&vp[0];
  *(float4*)&v8[4] = *(const float4*)&vp[4];
  const long vbase = ((long)(g * H_ + h) * 64 + tile) * 2048;
  #pragma unroll
  for (int e = 0; e < 8; e++) {
    const int d = vg * 8 + e;
    Vtb[vbase + d * 32 + (((vkv >> 3) ^ ((d >> 1) & 3)) * 8) + (vkv & 7)] = bf16_rn(v8[e]);
  }
}

// =====================================================================
// MFMA grouped flash attention (round-15 proven structure, unchanged):
// 2-deep double-buffer, scalar l, VGPR<=64, permlane32_swap half-swap,
// KV-SPLIT x2, XCD-swizzled. STATIC softmax max (-8): partials combine
// exactly (o=o0+o1, l=l0+l1).
// =====================================================================
__global__ __launch_bounds__(256) void attn3(
    const float* __restrict__ q, const short* __restrict__ Knb,
    const short* __restrict__ Vtb, const float* __restrict__ qnw,
    float* __restrict__ opart, float* __restrict__ lpart)
{
  int qb, h, bz;
  xcd_swizzle(qb, h, bz);
  const int b  = bz >> 1, s = bz & 1;
  const int g  = b >> 2;
  const int t  = threadIdx.x;
  const int w  = t >> 6;
  const int lane = t & 63;
  const int l31 = lane & 31, hi = lane >> 5;

  __shared__ short Kt[2][2048];
  __shared__ short Vt[2][2048];

  // ---- Q: load + RMSNorm + B-operand frags ----
  const int qrow = qb * 128 + w * 32 + l31;
  const float* qp = q + ((long)b * N_ + qrow) * D_ + h * HD_ + hi * 8;
  float qv[4][8];
  float ss = 0.f;
  #pragma unroll
  for (int c = 0; c < 4; c++) {
    *(float4*)&qv[c][0] = *(const float4*)&qp[c * 16];
    *(float4*)&qv[c][4] = *(const float4*)&qp[c * 16 + 4];
    #pragma unroll
    for (int j = 0; j < 8; j++) ss += qv[c][j] * qv[c][j];
  }
  ss += __shfl_xor(ss, 32);
  const float qr = rsqrtf(ss * (1.f / 64.f) + 1e-6f);
  bf16x8 qf[4];
  #pragma unroll
  for (int c = 0; c < 4; c++)
    #pragma unroll
    for (int j = 0; j < 8; j++)
      qf[c][j] = bf16_rn(qv[c][j] * qr * qnw[c * 16 + hi * 8 + j]);

  const short* Kg = Knb + (long)(g * H_ + h) * KVLEN * 64 + (long)s * 32 * 2048;
  const short* Vg = Vtb + (long)(g * H_ + h) * 64 * 2048 + (long)s * 32 * 2048;

  auto stage = [&](int buf, int i) {
    GLOAD16(Kg + (long)i * 2048 + t * 8, &Kt[buf][w * 512]);
    GLOAD16(Vg + (long)i * 2048 + t * 8, &Vt[buf][w * 512]);
  };

  f32x16 oacc[2] = {};
  float l = 0.f;

  stage(0, 0);
  for (int i = 0; i < 32; ++i) {
    const int buf = i & 1;
    if (i + 1 < 32) {
      stage(buf ^ 1, i + 1);
      asm volatile("s_waitcnt vmcnt(2)" ::: "memory");
    } else {
      asm volatile("s_waitcnt vmcnt(0)" ::: "memory");
    }
    __builtin_amdgcn_s_barrier();
    __builtin_amdgcn_sched_barrier(0);

    // ---- QK^T: scores[kv][q] ----
    f32x16 sc = {};
    #pragma unroll
    for (int c = 0; c < 4; c++) {
      bf16x8 kfr = *(const bf16x8*)&Kt[buf][l31 * 64 + (((2 * c + hi) * 8) ^ ((l31 & 7) << 3))];
      sc = mfma_bf16(kfr, qf[c], sc);
    }
    // ---- softmax, static max: p = exp2(s*0.125*log2e - 8*log2e) ----
    float p[16];
    #pragma unroll
    for (int r = 0; r < 16; r++) {
      p[r] = exp2f(fmaf(sc[r], 0.1803368801111244f, -11.541560327111961f));
      l += p[r];
    }
    // ---- pack P pairs to bf16 (cvt_pk), half-swap via permlane32 ----
    unsigned wd[8];
    #pragma unroll
    for (int i2 = 0; i2 < 8; i2++)
      asm("v_cvt_pk_bf16_f32 %0, %1, %2" : "=v"(wd[i2]) : "v"(p[2 * i2]), "v"(p[2 * i2 + 1]));
    u32x2 r0 = __builtin_amdgcn_permlane32_swap(wd[0], wd[2], false, false);
    u32x2 r1 = __builtin_amdgcn_permlane32_swap(wd[1], wd[3], false, false);
    u32x2 r2 = __builtin_amdgcn_permlane32_swap(wd[4], wd[6], false, false);
    u32x2 r3 = __builtin_amdgcn_permlane32_swap(wd[5], wd[7], false, false);
    int4 f0 = { (int)r0.x, (int)r1.x, (int)r0.y, (int)r1.y };
    int4 f1 = { (int)r2.x, (int)r3.x, (int)r2.y, (int)r3.y };
    // ---- PV ----
    #pragma unroll
    for (int n = 0; n < 2; n++) {
      const int d = n * 32 + l31;
      const int fd = (d >> 1) & 3;
      bf16x8 v0 = *(const bf16x8*)&Vt[buf][d * 32 + ((hi ^ fd) * 8)];
      bf16x8 v1 = *(const bf16x8*)&Vt[buf][d * 32 + (((2 | hi) ^ fd) * 8)];
      oacc[n] = mfma_bf16(__builtin_bit_cast(bf16x8, f0), v0, oacc[n]);
      oacc[n] = mfma_bf16(__builtin_bit_cast(bf16x8, f1), v1, oacc[n]);
    }
    __builtin_amdgcn_s_barrier();
  }

  // ---- epilogue: write PARTIAL o (no divide) + l ----
  l += __shfl_xor(l, 32);
  #pragma unroll
  for (int r = 0; r < 16; r++) {
    const int qg = qb * 128 + w * 32 + (r & 3) + 8 * (r >> 2) + 4 * hi;
    float* op = opart + ((long)s * BN_ + b * N_ + qg) * D_ + h * HD_ + l31;
    op[0]  = oacc[0][r];
    op[32] = oacc[1][r];
  }
  if (hi == 0)
    lpart[((long)s * BN_ + b * N_ + qb * 128 + w * 32 + l31) * H_ + h] = l;
}

// =====================================================================
// attn_reduce: o = (o0+o1)/(l0+l1), split2 -> tiled bf16 hi/lo.
// =====================================================================
__global__ __launch_bounds__(256) void attn_reduce(
    const float* __restrict__ opart, const float* __restrict__ lpart,
    short* __restrict__ ohi, short* __restrict__ olo)
{
  const int row = blockIdx.x;
  const int col = threadIdx.x * 4;
  const int h   = col >> 6;
  const float l = lpart[(long)row * H_ + h] + lpart[((long)BN_ + row) * H_ + h];
  const float inv = 1.f / l;
  float4 a = *(const float4*)&opart[(long)row * D_ + col];
  float4 b = *(const float4*)&opart[((long)BN_ + row) * D_ + col];
  short hh[4], ll[4];
  split2((a.x + b.x) * inv, hh[0], ll[0]);
  split2((a.y + b.y) * inv, hh[1], ll[1]);
  split2((a.z + b.z) * inv, hh[2], ll[2]);
  split2((a.w + b.w) * inv, hh[3], ll[3]);
  const long o = tiled_off(row, col);
  *(s16x4*)&ohi[o] = *(s16x4*)hh;
  *(s16x4*)&olo[o] = *(s16x4*)ll;
}

// =====================================================================
// gproj: G[row][0:5] = o[row] @ H5 (+const row H5[1024]).
// Block = 128-row tile of the tiled ohi layout; thread = (row, d-half).
// H5 staged in LDS (broadcast reads); ohi reads fully coalesced
// (consecutive rows = consecutive 16B within an octet column).
// =====================================================================
__global__ __launch_bounds__(256) void gproj(
    const short* __restrict__ ohi, const float* __restrict__ H5,
    float* __restrict__ G)
{
  __shared__ float Hl[5125];
  __shared__ float gpart[128][5];
  const int t = threadIdx.x;
  for (int i = t; i < 5125; i += 256) Hl[i] = H5[i];
  __syncthreads();
  const int rb = blockIdx.x;            // 0..31 (128-row tile)
  const int row = t & 127, half = t >> 7;
  float s0 = 0, s1 = 0, s2 = 0, s3 = 0, s4 = 0;
  const short* base = ohi + (long)rb * 131072 + row * 8;
  for (int qo = half * 64; qo < half * 64 + 64; qo++) {
    bf16x8 ov = *(const bf16x8*)&base[qo * 1024];
    #pragma unroll
    for (int e = 0; e < 8; e++) {
      const float of = __uint_as_float(((unsigned)(unsigned short)ov[e]) << 16);
      const float* hp = &Hl[(qo * 8 + e) * 5];
      s0 = fmaf(of, hp[0], s0);
      s1 = fmaf(of, hp[1], s1);
      s2 = fmaf(of, hp[2], s2);
      s3 = fmaf(of, hp[3], s3);
      s4 = fmaf(of, hp[4], s4);
    }
  }
  if (half == 0) {
    gpart[row][0] = s0; gpart[row][1] = s1; gpart[row][2] = s2;
    gpart[row][3] = s3; gpart[row][4] = s4;
  }
  __syncthreads();
  if (half == 1) {
    float* g = &G[(long)(rb * 128 + row) * 5];
    g[0] = gpart[row][0] + s0 + Hl[5120];
    g[1] = gpart[row][1] + s1 + Hl[5121];
    g[2] = gpart[row][2] + s2 + Hl[5122];
    g[3] = gpart[row][3] + s3 + Hl[5123];
    g[4] = gpart[row][4] + s4 + Hl[5124];
  }
}

// =====================================================================
// gate_finish2: gate[row] = 1 + mean_m sigmoid(sc*(G[row,0:4]·mask[b,m]
// + G[row,4])).  Block = 128 rows (one batch-quarter); mask[b] in LDS.
// =====================================================================
__global__ __launch_bounds__(256) void gate_finish2(
    const float* __restrict__ G, const float* __restrict__ mask,
    float* __restrict__ gate)
{
  __shared__ float mk[512][4];
  __shared__ float spart[128];
  const int t = threadIdx.x;
  const int rb = blockIdx.x;            // 0..31; rows rb*128..+127
  const int batch = rb >> 2;
  const float* msrc = mask + (long)batch * N_ * NI_;
  for (int i = t; i < 2048; i += 256) ((float*)mk)[i] = msrc[i];
  __syncthreads();
  const int row = t & 127, half = t >> 7;
  const float* g = &G[(long)(rb * 128 + row) * 5];
  const float g0 = g[0], g1 = g[1], g2 = g[2], g3 = g[3], g4 = g[4];
  const float sc = 0.125f / 16.f;       // SCALE/H
  float s = 0.f;
  for (int m = half * 256; m < half * 256 + 256; m++) {
    const float z = fmaf(g0, mk[m][0], fmaf(g1, mk[m][1],
                    fmaf(g2, mk[m][2], fmaf(g3, mk[m][3], g4))));
    s += 1.f / (1.f + __expf(-z * sc));
  }
  if (half == 0) spart[row] = s;
  __syncthreads();
  if (half == 1)
    gate[rb * 128 + row] = 1.f + (spart[row] + s) * (1.f / 512.f);
}

// =====================================================================
extern "C" void kernel_launch(void* const* d_in, const int* in_sizes, int n_in,
                              void* d_out, int out_size, void* d_ws, size_t ws_size,
                              hipStream_t stream)
{
  const float* x    = (const float*)d_in[0];
  const float* mask = (const float*)d_in[1];
  const float* Wq   = (const float*)d_in[2];
  const float* bq   = (const float*)d_in[3];
  const float* Wk   = (const float*)d_in[4];
  const float* bk   = (const float*)d_in[5];
  const float* Wv   = (const float*)d_in[6];
  const float* bv   = (const float*)d_in[7];
  const float* Wo   = (const float*)d_in[8];
  const float* bo   = (const float*)d_in[9];
  const float* Wiq  = (const float*)d_in[10];
  const float* biq  = (const float*)d_in[11];
  const float* Wik  = (const float*)d_in[12];
  const float* bik  = (const float*)d_in[13];
  const float* emb  = (const float*)d_in[14];
  const float* qnw  = (const float*)d_in[15];
  const float* knw  = (const float*)d_in[16];
  float* out = (float*)d_out;

  // Workspace (identical extents to the round-9-proven footprint).
  // Lifetime audit:
  //  qbuf: fp32 q (w:5 r:7)
  //  kbuf/vbuf: fp32 k,v (w:5 r:6) -> opart[2 planes] (w:7 r:8)
  //  ohi/olo: tiled split-bf16 o (w:8 r:9,11)
  //  xhi/xlo: x tiled bf16 (w:4 r:5) -> Knb/Vtb (w:6 r:7)
  //  Wbig_hi: QKV weights (w:3 r:5) -> gate + lpart (w:10/7 r:11/8)
  //  Wbig_lo: WoH (w:3 r:11) | F4 (w:1 r:2) | H5 (w:2 r:9) | G (w:9 r:10)
  float* ws = (float*)d_ws;
  const size_t SZ = (size_t)BN_ * D_;
  float* qbuf = ws;
  float* kbuf = qbuf + SZ;
  float* vbuf = kbuf + SZ;
  float* opart = kbuf;                  // [2][BN][D] fp32 attn partials
  short* ohi  = (short*)(vbuf + SZ);
  short* olo  = ohi + SZ;
  short* xhi  = (short*)(ws + 4 * SZ);
  short* xlo  = xhi + SZ;
  short* Knb  = xhi;                    // [2][16][2048][64] bf16
  short* Vtb  = xlo;                    // [2][16][64][64][32] bf16
  short* Wbig_hi = (short*)(ws + 5 * SZ);
  short* Wbig_lo = Wbig_hi + (size_t)3 * D_ * D_;
  float* gate  = (float*)Wbig_hi;                       // [BN] (post-QKV)
  float* lpart = gate + BN_;                            // [2][BN][16]
  short* WoH = Wbig_lo;                                 // [D][D] tiled
  float* F4  = (float*)(Wbig_lo + (size_t)D_ * D_);     // [4][1024]
  float* H5  = F4 + 4 * D_;                             // [1025][5]
  float* G   = H5 + 1025 * 5;                           // [BN][5]

  const dim3 blk(256);

  // 1-2) gate-path algebra prep (rank-5 collapse of iq/ik/z GEMMs)
  fprep<<<dim3(4), blk, 0, stream>>>(Wik, emb, F4);
  hprep<<<dim3(5), blk, 0, stream>>>(Wiq, F4, bik, biq, H5);

  // 3-4) weight prep (Wq,Wk,Wv,Wo) + x -> tiled bf16
  wsplitAll<<<dim3(16, 16, 4), blk, 0, stream>>>(Wq, Wk, Wv, Wo, Wbig_hi, WoH);
  asplit<<<(BN_ * D_ / 4) / 256, blk, 0, stream>>>(x, xhi);

  // 5) fused QKV projection (plain bf16, 1 MFMA/pair)
  mfgemm2<0, 0><<<dim3(8, 32, 3), blk, 0, stream>>>(
      xhi, nullptr, Wbig_hi, bq, bk, bv,
      qbuf, 8, (long)SZ, nullptr);

  // 6) KV prep (norm K, transpose V, bf16, swizzled; group-indexed)
  kvprep<<<dim3(KVLEN / 32, H_, 2), blk, 0, stream>>>(kbuf, vbuf, knw, Knb, Vtb);

  // 7) attention, KV-split x2 -> fp32 partials (over dead kbuf/vbuf)
  attn3<<<dim3(N_ / 128, H_, B_ * 2), blk, 0, stream>>>(
      qbuf, Knb, Vtb, qnw, opart, lpart);

  // 8) combine partials -> tiled split bf16 o
  attn_reduce<<<BN_, blk, 0, stream>>>(opart, lpart, ohi, olo);

  // 9) G = o @ H5 (the collapsed gate path: 42 MFLOP skinny product)
  gproj<<<dim3(32), blk, 0, stream>>>(ohi, H5, G);

  // 10) gate[row] = 1 + mean_m sigmoid(sc*(G·mask + c))
  gate_finish2<<<dim3(32), blk, 0, stream>>>(G, mask, gate);

  // 11) final: gate[row]*(o@Wo) + bo -> d_out (SPLIT=2: o hi/lo x Wo hi)
  mfgemm2<2, 2><<<dim3(8, 32, 1), blk, 0, stream>>>(
      ohi, olo, WoH, bo, nullptr, nullptr,
      out, 0, 0, gate);
}

// Round 17
// 221.983 us; speedup vs baseline: 1.3702x; 1.3702x over previous
//
#include <hip/hip_runtime.h>
#include <cmath>

// Problem constants (fixed by the reference file)
#define B_   8
#define N_   512
#define D_   1024
#define H_   16
#define HD_  64
#define NI_  4
#define BN_  (B_*N_)      // 4096 rows when [B,N,*] is flattened
#define KVLEN (NI_*N_)    // 2048 keys per attention group

typedef __attribute__((ext_vector_type(8)))  short  bf16x8;   // 8 bf16 bit patterns
typedef __attribute__((ext_vector_type(8)))  __bf16 bf16x8_t; // builtin operand type
typedef __attribute__((ext_vector_type(16))) float  f32x16;
typedef __attribute__((ext_vector_type(4)))  short  s16x4;
typedef __attribute__((ext_vector_type(2)))  unsigned u32x2;

// round-to-nearest-even bf16 conversion (bit trick)
__device__ __forceinline__ short bf16_rn(float x) {
  unsigned u = __float_as_uint(x);
  unsigned r = (u + 0x7FFFu + ((u >> 16) & 1u)) >> 16;
  return (short)r;
}

// RN hi/lo split: x = hi + lo + eps, |eps| <~ 2^-18 |x|.
__device__ __forceinline__ void split2(float x, short& hi, short& lo) {
  hi = bf16_rn(x);
  float h = __uint_as_float(((unsigned)(unsigned short)hi) << 16);
  float r = x - h;              // exact (Dekker-style split)
  lo = bf16_rn(r);
}

__device__ __forceinline__ f32x16 mfma_bf16(bf16x8 a, bf16x8 b, f32x16 c) {
  return __builtin_amdgcn_mfma_f32_32x32x16_bf16(
      __builtin_bit_cast(bf16x8_t, a), __builtin_bit_cast(bf16x8_t, b), c, 0, 0, 0);
}

#define GLOAD16(gp, lp) __builtin_amdgcn_global_load_lds( \
  (const __attribute__((address_space(1))) unsigned*)(gp), \
  (__attribute__((address_space(3))) unsigned*)(lp), 16, 0, 0)

// TILED layout for all bf16 GEMM operands (K = 1024):
// addr(row,k) = (((row>>7)*128 + (k>>3))*128 + (row&127))*8 + (k&7).
// GEMM staging is then a LINEAR copy -> fully coalesced global_load_lds.
__device__ __forceinline__ long tiled_off(int row, int k) {
  return ((((long)(row >> 7) * 128 + (k >> 3)) * 128 + (row & 127)) * 8 + (k & 7));
}

// T1 XCD-aware block swizzle (MI355X: 8 XCDs, private L2s). Remap so each
// XCD gets a CONTIGUOUS tile range. REQUIRES nwg % 8 == 0.
__device__ __forceinline__ void xcd_swizzle(int& bx, int& by, int& bz) {
  const int gx = gridDim.x, gy = gridDim.y;
  const int nwg = gx * gy * gridDim.z;
  const int lin = blockIdx.x + gx * (blockIdx.y + gy * blockIdx.z);
  const int swz = (lin & 7) * (nwg >> 3) + (lin >> 3);
  bx = swz % gx;
  const int rest = swz / gx;
  by = rest % gy;
  bz = rest / gy;
}

// =====================================================================
// Weight prep: z=0..2 Wq/Wk/Wv -> QKVh (combined [3072][1024] tiled);
// z=3 Wo -> WoH. All hi-only bf16.
// =====================================================================
__global__ __launch_bounds__(256) void wsplitAll(
    const float* __restrict__ Wq, const float* __restrict__ Wk,
    const float* __restrict__ Wv, const float* __restrict__ Wo,
    short* __restrict__ QKVh, short* __restrict__ WoH)
{
  __shared__ float tile[64][65];
  const int z = blockIdx.z;
  const float* W = (z == 0) ? Wq : (z == 1) ? Wk : (z == 2) ? Wv : Wo;
  const int t  = threadIdx.x;
  const int kb = blockIdx.y * 64;
  const int cb = blockIdx.x * 64;
  const int r0 = t >> 4;
  const int c4 = t & 15;
  #pragma unroll
  for (int i = 0; i < 4; i++) {
    const int r = r0 + i * 16;
    *(float4*)&tile[r][c4 * 4] = *(const float4*)&W[(long)(kb + r) * D_ + cb + c4 * 4];
  }
  __syncthreads();
  #pragma unroll
  for (int i = 0; i < 4; i++) {
    const int c = r0 + i * 16;
    short hi[4];
    #pragma unroll
    for (int e = 0; e < 4; e++)
      hi[e] = bf16_rn(tile[c4 * 4 + e][c]);
    if (z < 3)
      *(s16x4*)&QKVh[tiled_off(z * D_ + cb + c, kb + c4 * 4)] = *(s16x4*)hi;
    else
      *(s16x4*)&WoH[tiled_off(cb + c, kb + c4 * 4)] = *(s16x4*)hi;
  }
}

// =====================================================================
// Gate-path prep A (ROUND-16 LESSON: the rank-5 algebra was right but
// fprep/hprep ran on 4-5 blocks — 1024-iter serial loops on <2% of the
// machine cost ~140us. Same math, proper grids now.)
// fprep_p: partial F4 over 16 e-chunks. grid (4,16)=64 blocks; each
// iteration reads a coalesced 1KB row segment of Wik.
// F4p[eb][j][d] = sum_{e in chunk eb} emb[j][e] * Wik[e][d]
// =====================================================================
__global__ __launch_bounds__(256) void fprep_p(
    const float* __restrict__ Wik, const float* __restrict__ emb,
    float* __restrict__ F4p)
{
  const int d  = blockIdx.x * 256 + threadIdx.x;
  const int eb = blockIdx.y;
  float s0 = 0, s1 = 0, s2 = 0, s3 = 0;
  for (int e = eb * 64; e < eb * 64 + 64; e++) {
    const float w = Wik[(long)e * D_ + d];
    s0 = fmaf(emb[e], w, s0);
    s1 = fmaf(emb[D_ + e], w, s1);
    s2 = fmaf(emb[2 * D_ + e], w, s2);
    s3 = fmaf(emb[3 * D_ + e], w, s3);
  }
  float* p = F4p + (long)eb * 4 * D_;
  p[d] = s0;  p[D_ + d] = s1;  p[2 * D_ + d] = s2;  p[3 * D_ + d] = s3;
}

// freduce: F4[j][d] = sum over the 16 e-chunk partials (fixed order ->
// deterministic). 16 blocks x 256 threads.
__global__ __launch_bounds__(256) void freduce(
    const float* __restrict__ F4p, float* __restrict__ F4)
{
  const int i = blockIdx.x * 256 + threadIdx.x;   // 0..4095
  float s = 0.f;
  #pragma unroll
  for (int eb = 0; eb < 16; eb++) s += F4p[(long)eb * 4096 + i];
  F4[i] = s;
}

// =====================================================================
// Gate-path prep B: H5[d][j] = Wiq[d]·F4[j] (j<4); H5[d][4] = Wiq[d]·bik.
// Consts row H5[1024][j] = F4[j]·biq (j<4), H5[1024][4] = biq·bik.
// ONE BLOCK PER d-ROW (1024 + 1 consts): 256 threads read the 4KB Wiq
// row coalesced; 5 sums reduced via shfl + LDS.
// =====================================================================
__global__ __launch_bounds__(256) void hprep2(
    const float* __restrict__ Wiq, const float* __restrict__ F4,
    const float* __restrict__ bik, const float* __restrict__ biq,
    float* __restrict__ H5)
{
  __shared__ float red[4][5];
  const int t = threadIdx.x;
  const int blk = blockIdx.x;
  float s[5] = {0.f, 0.f, 0.f, 0.f, 0.f};
  if (blk < 1024) {
    const float* wr = Wiq + (long)blk * D_;
    for (int e = t; e < D_; e += 256) {
      const float w = wr[e];
      s[0] = fmaf(w, F4[e], s[0]);
      s[1] = fmaf(w, F4[D_ + e], s[1]);
      s[2] = fmaf(w, F4[2 * D_ + e], s[2]);
      s[3] = fmaf(w, F4[3 * D_ + e], s[3]);
      s[4] = fmaf(w, bik[e], s[4]);
    }
  } else {
    for (int e = t; e < D_; e += 256) {
      const float b = biq[e];
      s[0] = fmaf(b, F4[e], s[0]);
      s[1] = fmaf(b, F4[D_ + e], s[1]);
      s[2] = fmaf(b, F4[2 * D_ + e], s[2]);
      s[3] = fmaf(b, F4[3 * D_ + e], s[3]);
      s[4] = fmaf(b, bik[e], s[4]);
    }
  }
  #pragma unroll
  for (int j = 0; j < 5; j++)
    #pragma unroll
    for (int m = 1; m < 64; m <<= 1) s[j] += __shfl_xor(s[j], m);
  const int w64 = t >> 6, lane = t & 63;
  if (lane == 0)
    #pragma unroll
    for (int j = 0; j < 5; j++) red[w64][j] = s[j];
  __syncthreads();
  if (t < 5)
    H5[(long)blk * 5 + t] = red[0][t] + red[1][t] + red[2][t] + red[3][t];
}

// =====================================================================
// Elementwise fp32 -> tiled bf16 (hi only — QKV is plain bf16).
// =====================================================================
__global__ __launch_bounds__(256) void asplit(const float* __restrict__ in,
                                              short* __restrict__ hi)
{
  const long i4 = ((long)blockIdx.x * 256 + threadIdx.x) * 4;
  const int row = (int)(i4 >> 10);
  const int kk  = (int)(i4 & 1023);
  float4 v = *(const float4*)&in[i4];
  short h[4];
  h[0] = bf16_rn(v.x);
  h[1] = bf16_rn(v.y);
  h[2] = bf16_rn(v.z);
  h[3] = bf16_rn(v.w);
  *(s16x4*)&hi[tiled_off(row, kk)] = *(s16x4*)h;
}

// =====================================================================
// MFMA GEMM v6. Tiled bf16 operands, linear global_load_lds staging,
// double-buffered LDS, counted vmcnt, XCD-swizzled blocks.
// SPLIT=2: A hi/lo, B hi (2 MFMAs/pair); waves 0-2 stage {Ahi,Alo,Bhi},
//          wave 3 idle, vmcnt(8). 48 KB LDS.
// SPLIT=0: plain bf16 (1 MFMA/pair); waves 0,1 stage A halves, waves
//          2,3 stage B halves, vmcnt(4). 32 KB LDS.
// MODE 0: C[bz*sC + row*D + col] = A@B + bias(bz)     (QKV fused)
// MODE 2: C = gate[row]*(A@B) + bias                  (final, SPLIT=2)
// =====================================================================
template<int MODE, int SPLIT>
__global__ __launch_bounds__(256) void mfgemm2(
    const short* __restrict__ Ahi, const short* __restrict__ Alo,
    const short* __restrict__ Bhi,
    const float* __restrict__ b0, const float* __restrict__ b1,
    const float* __restrict__ b2,
    float* __restrict__ C, int bBlk, long sC,
    const float* __restrict__ gate_in)
{
  constexpr int NOPS = (SPLIT == 2) ? 3 : 2;
  __shared__ short lds[2][NOPS][4096];
  const int t = threadIdx.x, w = t >> 6, lane = t & 63;
  int bx, by, bz;
  xcd_swizzle(bx, by, bz);
  const int rowBase = by * 128;
  const int colBase = bx * 128;
  const long aoff = (long)by * 131072;   // 128 oct * 128 rows * 8
  const long boff = (long)(bz * bBlk + bx) * 131072;

  const short* mySrc;
  int op, half;
  if (SPLIT == 2) {
    op = (w < 3) ? w : 0; half = 0;
    mySrc = (w == 0) ? Ahi + aoff : (w == 1) ? Alo + aoff : Bhi + boff;
  } else {
    op = w >> 1; half = w & 1;
    mySrc = op ? Bhi + boff : Ahi + aoff;
  }

  auto stage = [&](int buf, int tt) {
    if (SPLIT == 2) {
      if (w == 3) return;   // 3 operands, wave 3 idle
      const short* g = mySrc + ((long)tt * 512 + lane) * 8;
      #pragma unroll
      for (int i = 0; i < 8; i++)
        GLOAD16(g + i * 512, &lds[buf][op][i * 512]);
    } else {
      const short* g = mySrc + ((long)tt * 512 + half * 256 + lane) * 8;
      #pragma unroll
      for (int i = 0; i < 4; i++)
        GLOAD16(g + i * 512, &lds[buf][op][(half * 256 + i * 64) * 8]);
    }
  };

  const int wr = w >> 1, wc = w & 1;
  const int lrow = lane & 31, lk = lane >> 5;

  f32x16 acc[2][2] = {};

  auto compute = [&](int buf) {
    #pragma unroll
    for (int kh = 0; kh < 2; kh++) {
      const int kq = 2 * kh + lk;
      bf16x8 ah[2], bh[2];
      #pragma unroll
      for (int m = 0; m < 2; m++)
        ah[m] = *(const bf16x8*)&lds[buf][0][(kq * 128 + wr * 64 + m * 32 + lrow) * 8];
      #pragma unroll
      for (int n = 0; n < 2; n++)
        bh[n] = *(const bf16x8*)&lds[buf][(SPLIT == 2) ? 2 : 1][(kq * 128 + wc * 64 + n * 32 + lrow) * 8];
      if (SPLIT == 2) {
        bf16x8 al[2];
        #pragma unroll
        for (int m = 0; m < 2; m++)
          al[m] = *(const bf16x8*)&lds[buf][1][(kq * 128 + wr * 64 + m * 32 + lrow) * 8];
        #pragma unroll
        for (int m = 0; m < 2; m++)
          #pragma unroll
          for (int n = 0; n < 2; n++) {
            acc[m][n] = mfma_bf16(al[m], bh[n], acc[m][n]);
            acc[m][n] = mfma_bf16(ah[m], bh[n], acc[m][n]);
          }
      } else {
        #pragma unroll
        for (int m = 0; m < 2; m++)
          #pragma unroll
          for (int n = 0; n < 2; n++)
            acc[m][n] = mfma_bf16(ah[m], bh[n], acc[m][n]);
      }
    }
  };

  const int NT = 32;   // K=1024 / BK=32
  stage(0, 0);
  for (int tt = 0; tt < NT - 1; ++tt) {
    stage((tt + 1) & 1, tt + 1);
    if (SPLIT == 2) asm volatile("s_waitcnt vmcnt(8)" ::: "memory");
    else            asm volatile("s_waitcnt vmcnt(4)" ::: "memory");
    __builtin_amdgcn_s_barrier();
    __builtin_amdgcn_sched_barrier(0);
    compute(tt & 1);
    __builtin_amdgcn_s_barrier();
  }
  asm volatile("s_waitcnt vmcnt(0)" ::: "memory");
  __builtin_amdgcn_s_barrier();
  __builtin_amdgcn_sched_barrier(0);
  compute((NT - 1) & 1);

  // ---------------- epilogue ----------------
  const float* bias = (bz == 1) ? b1 : (bz == 2) ? b2 : b0;
  float bcol[2];
  #pragma unroll
  for (int n = 0; n < 2; n++)
    bcol[n] = bias[colBase + wc * 64 + n * 32 + lrow];

  float* Cb = C + (long)bz * sC;

  #pragma unroll
  for (int m = 0; m < 2; m++) {
    #pragma unroll
    for (int r = 0; r < 16; r++) {
      const int row = rowBase + wr * 64 + m * 32 + (r & 3) + 8 * (r >> 2) + 4 * lk;
      float g = 1.f;
      if (MODE == 2) g = gate_in[row];
      #pragma unroll
      for (int n = 0; n < 2; n++) {
        const int col = colBase + wc * 64 + n * 32 + lrow;
        Cb[(long)row * D_ + col] = acc[m][n][r] * g + bcol[n];
      }
    }
  }
}

// =====================================================================
// KV prep: K RMSNorm->bf16 swizzled [g][h][m][64]; V transposed bf16
// tiles [g][h][tile][d][32kv], chunk-swizzled. Both linear per 4KB tile
// for coalesced global_load_lds in attention.
// =====================================================================
__global__ __launch_bounds__(256) void kvprep(
    const float* __restrict__ kf, const float* __restrict__ vf,
    const float* __restrict__ knw, short* __restrict__ Knb,
    short* __restrict__ Vtb)
{
  const int tile = blockIdx.x, h = blockIdx.y, g = blockIdx.z;
  const int t = threadIdx.x;
  // ---- K ----
  const int skv = t >> 3, sg = t & 7;
  const int m  = tile * 32 + skv;
  const int bb = g * NI_ + (m >> 9), nn = m & (N_ - 1);
  const float* kp = kf + ((long)(bb * N_ + nn)) * D_ + h * HD_ + sg * 8;
  float k8[8];
  *(float4*)&k8[0] = *(const float4*)&kp[0];
  *(float4*)&k8[4] = *(const float4*)&kp[4];
  float ks2 = 0.f;
  #pragma unroll
  for (int j = 0; j < 8; j++) ks2 += k8[j] * k8[j];
  ks2 += __shfl_xor(ks2, 1);
  ks2 += __shfl_xor(ks2, 2);
  ks2 += __shfl_xor(ks2, 4);
  const float kr = rsqrtf(ks2 * (1.f / 64.f) + 1e-6f);
  bf16x8 kb;
  #pragma unroll
  for (int j = 0; j < 8; j++) kb[j] = bf16_rn(k8[j] * kr * knw[sg * 8 + j]);
  *(bf16x8*)&Knb[((long)(g * H_ + h) * KVLEN + m) * 64 + ((sg ^ (m & 7)) * 8)] = kb;
  // ---- V ----
  const int vkv = t & 31, vg = t >> 5;
  const int m2  = tile * 32 + vkv;
  const int bb2 = g * NI_ + (m2 >> 9), nn2 = m2 & (N_ - 1);
  const float* vp = vf + ((long)(bb2 * N_ + nn2)) * D_ + h * HD_ + vg * 8;
  float v8[8];
  *(float4*)&v8[0] = *(const float4*)&vp[0];
  *(float4*)&v8[4] = *(const float4*)&vp[4];
  const long vbase = ((long)(g * H_ + h) * 64 + tile) * 2048;
  #pragma unroll
  for (int e = 0; e < 8; e++) {
    const int d = vg * 8 + e;
    Vtb[vbase + d * 32 + (((vkv >> 3) ^ ((d >> 1) & 3)) * 8) + (vkv & 7)] = bf16_rn(v8[e]);
  }
}

// =====================================================================
// MFMA grouped flash attention (round-15 proven structure, unchanged):
// 2-deep double-buffer, scalar l, VGPR<=64, permlane32_swap half-swap,
// KV-SPLIT x2, XCD-swizzled. STATIC softmax max (-8): partials combine
// exactly (o=o0+o1, l=l0+l1).
// =====================================================================
__global__ __launch_bounds__(256) void attn3(
    const float* __restrict__ q, const short* __restrict__ Knb,
    const short* __restrict__ Vtb, const float* __restrict__ qnw,
    float* __restrict__ opart, float* __restrict__ lpart)
{
  int qb, h, bz;
  xcd_swizzle(qb, h, bz);
  const int b  = bz >> 1, s = bz & 1;
  const int g  = b >> 2;
  const int t  = threadIdx.x;
  const int w  = t >> 6;
  const int lane = t & 63;
  const int l31 = lane & 31, hi = lane >> 5;

  __shared__ short Kt[2][2048];
  __shared__ short Vt[2][2048];

  // ---- Q: load + RMSNorm + B-operand frags ----
  const int qrow = qb * 128 + w * 32 + l31;
  const float* qp = q + ((long)b * N_ + qrow) * D_ + h * HD_ + hi * 8;
  float qv[4][8];
  float ss = 0.f;
  #pragma unroll
  for (int c = 0; c < 4; c++) {
    *(float4*)&qv[c][0] = *(const float4*)&qp[c * 16];
    *(float4*)&qv[c][4] = *(const float4*)&qp[c * 16 + 4];
    #pragma unroll
    for (int j = 0; j < 8; j++) ss += qv[c][j] * qv[c][j];
  }
  ss += __shfl_xor(ss, 32);
  const float qr = rsqrtf(ss * (1.f / 64.f) + 1e-6f);
  bf16x8 qf[4];
  #pragma unroll
  for (int c = 0; c < 4; c++)
    #pragma unroll
    for (int j = 0; j < 8; j++)
      qf[c][j] = bf16_rn(qv[c][j] * qr * qnw[c * 16 + hi * 8 + j]);

  const short* Kg = Knb + (long)(g * H_ + h) * KVLEN * 64 + (long)s * 32 * 2048;
  const short* Vg = Vtb + (long)(g * H_ + h) * 64 * 2048 + (long)s * 32 * 2048;

  auto stage = [&](int buf, int i) {
    GLOAD16(Kg + (long)i * 2048 + t * 8, &Kt[buf][w * 512]);
    GLOAD16(Vg + (long)i * 2048 + t * 8, &Vt[buf][w * 512]);
  };

  f32x16 oacc[2] = {};
  float l = 0.f;

  stage(0, 0);
  for (int i = 0; i < 32; ++i) {
    const int buf = i & 1;
    if (i + 1 < 32) {
      stage(buf ^ 1, i + 1);
      asm volatile("s_waitcnt vmcnt(2)" ::: "memory");
    } else {
      asm volatile("s_waitcnt vmcnt(0)" ::: "memory");
    }
    __builtin_amdgcn_s_barrier();
    __builtin_amdgcn_sched_barrier(0);

    // ---- QK^T: scores[kv][q] ----
    f32x16 sc = {};
    #pragma unroll
    for (int c = 0; c < 4; c++) {
      bf16x8 kfr = *(const bf16x8*)&Kt[buf][l31 * 64 + (((2 * c + hi) * 8) ^ ((l31 & 7) << 3))];
      sc = mfma_bf16(kfr, qf[c], sc);
    }
    // ---- softmax, static max: p = exp2(s*0.125*log2e - 8*log2e) ----
    float p[16];
    #pragma unroll
    for (int r = 0; r < 16; r++) {
      p[r] = exp2f(fmaf(sc[r], 0.1803368801111244f, -11.541560327111961f));
      l += p[r];
    }
    // ---- pack P pairs to bf16 (cvt_pk), half-swap via permlane32 ----
    unsigned wd[8];
    #pragma unroll
    for (int i2 = 0; i2 < 8; i2++)
      asm("v_cvt_pk_bf16_f32 %0, %1, %2" : "=v"(wd[i2]) : "v"(p[2 * i2]), "v"(p[2 * i2 + 1]));
    u32x2 r0 = __builtin_amdgcn_permlane32_swap(wd[0], wd[2], false, false);
    u32x2 r1 = __builtin_amdgcn_permlane32_swap(wd[1], wd[3], false, false);
    u32x2 r2 = __builtin_amdgcn_permlane32_swap(wd[4], wd[6], false, false);
    u32x2 r3 = __builtin_amdgcn_permlane32_swap(wd[5], wd[7], false, false);
    int4 f0 = { (int)r0.x, (int)r1.x, (int)r0.y, (int)r1.y };
    int4 f1 = { (int)r2.x, (int)r3.x, (int)r2.y, (int)r3.y };
    // ---- PV ----
    #pragma unroll
    for (int n = 0; n < 2; n++) {
      const int d = n * 32 + l31;
      const int fd = (d >> 1) & 3;
      bf16x8 v0 = *(const bf16x8*)&Vt[buf][d * 32 + ((hi ^ fd) * 8)];
      bf16x8 v1 = *(const bf16x8*)&Vt[buf][d * 32 + (((2 | hi) ^ fd) * 8)];
      oacc[n] = mfma_bf16(__builtin_bit_cast(bf16x8, f0), v0, oacc[n]);
      oacc[n] = mfma_bf16(__builtin_bit_cast(bf16x8, f1), v1, oacc[n]);
    }
    __builtin_amdgcn_s_barrier();
  }

  // ---- epilogue: write PARTIAL o (no divide) + l ----
  l += __shfl_xor(l, 32);
  #pragma unroll
  for (int r = 0; r < 16; r++) {
    const int qg = qb * 128 + w * 32 + (r & 3) + 8 * (r >> 2) + 4 * hi;
    float* op = opart + ((long)s * BN_ + b * N_ + qg) * D_ + h * HD_ + l31;
    op[0]  = oacc[0][r];
    op[32] = oacc[1][r];
  }
  if (hi == 0)
    lpart[((long)s * BN_ + b * N_ + qb * 128 + w * 32 + l31) * H_ + h] = l;
}

// =====================================================================
// attn_reduce: o = (o0+o1)/(l0+l1), split2 -> tiled bf16 hi/lo.
// =====================================================================
__global__ __launch_bounds__(256) void attn_reduce(
    const float* __restrict__ opart, const float* __restrict__ lpart,
    short* __restrict__ ohi, short* __restrict__ olo)
{
  const int row = blockIdx.x;
  const int col = threadIdx.x * 4;
  const int h   = col >> 6;
  const float l = lpart[(long)row * H_ + h] + lpart[((long)BN_ + row) * H_ + h];
  const float inv = 1.f / l;
  float4 a = *(const float4*)&opart[(long)row * D_ + col];
  float4 b = *(const float4*)&opart[((long)BN_ + row) * D_ + col];
  short hh[4], ll[4];
  split2((a.x + b.x) * inv, hh[0], ll[0]);
  split2((a.y + b.y) * inv, hh[1], ll[1]);
  split2((a.z + b.z) * inv, hh[2], ll[2]);
  split2((a.w + b.w) * inv, hh[3], ll[3]);
  const long o = tiled_off(row, col);
  *(s16x4*)&ohi[o] = *(s16x4*)hh;
  *(s16x4*)&olo[o] = *(s16x4*)ll;
}

// =====================================================================
// gproj: G[row][0:5] = o[row] @ H5 (+const row H5[1024]).
// Block = 128-row tile of the tiled ohi layout; H5 staged in LDS.
// =====================================================================
__global__ __launch_bounds__(256) void gproj(
    const short* __restrict__ ohi, const float* __restrict__ H5,
    float* __restrict__ G)
{
  __shared__ float Hl[5125];
  __shared__ float gpart[128][5];
  const int t = threadIdx.x;
  for (int i = t; i < 5125; i += 256) Hl[i] = H5[i];
  __syncthreads();
  const int rb = blockIdx.x;            // 0..31 (128-row tile)
  const int row = t & 127, half = t >> 7;
  float s0 = 0, s1 = 0, s2 = 0, s3 = 0, s4 = 0;
  const short* base = ohi + (long)rb * 131072 + row * 8;
  for (int qo = half * 64; qo < half * 64 + 64; qo++) {
    bf16x8 ov = *(const bf16x8*)&base[qo * 1024];
    #pragma unroll
    for (int e = 0; e < 8; e++) {
      const float of = __uint_as_float(((unsigned)(unsigned short)ov[e]) << 16);
      const float* hp = &Hl[(qo * 8 + e) * 5];
      s0 = fmaf(of, hp[0], s0);
      s1 = fmaf(of, hp[1], s1);
      s2 = fmaf(of, hp[2], s2);
      s3 = fmaf(of, hp[3], s3);
      s4 = fmaf(of, hp[4], s4);
    }
  }
  if (half == 0) {
    gpart[row][0] = s0; gpart[row][1] = s1; gpart[row][2] = s2;
    gpart[row][3] = s3; gpart[row][4] = s4;
  }
  __syncthreads();
  if (half == 1) {
    float* g = &G[(long)(rb * 128 + row) * 5];
    g[0] = gpart[row][0] + s0 + Hl[5120];
    g[1] = gpart[row][1] + s1 + Hl[5121];
    g[2] = gpart[row][2] + s2 + Hl[5122];
    g[3] = gpart[row][3] + s3 + Hl[5123];
    g[4] = gpart[row][4] + s4 + Hl[5124];
  }
}

// =====================================================================
// gate_finish2: gate[row] = 1 + mean_m sigmoid(sc*(G[row,0:4]·mask[b,m]
// + G[row,4])).  Block = 128 rows (one batch-quarter); mask[b] in LDS.
// =====================================================================
__global__ __launch_bounds__(256) void gate_finish2(
    const float* __restrict__ G, const float* __restrict__ mask,
    float* __restrict__ gate)
{
  __shared__ float mk[512][4];
  __shared__ float spart[128];
  const int t = threadIdx.x;
  const int rb = blockIdx.x;            // 0..31; rows rb*128..+127
  const int batch = rb >> 2;
  const float* msrc = mask + (long)batch * N_ * NI_;
  for (int i = t; i < 2048; i += 256) ((float*)mk)[i] = msrc[i];
  __syncthreads();
  const int row = t & 127, half = t >> 7;
  const float* g = &G[(long)(rb * 128 + row) * 5];
  const float g0 = g[0], g1 = g[1], g2 = g[2], g3 = g[3], g4 = g[4];
  const float sc = 0.125f / 16.f;       // SCALE/H
  float s = 0.f;
  for (int m = half * 256; m < half * 256 + 256; m++) {
    const float z = fmaf(g0, mk[m][0], fmaf(g1, mk[m][1],
                    fmaf(g2, mk[m][2], fmaf(g3, mk[m][3], g4))));
    s += 1.f / (1.f + __expf(-z * sc));
  }
  if (half == 0) spart[row] = s;
  __syncthreads();
  if (half == 1)
    gate[rb * 128 + row] = 1.f + (spart[row] + s) * (1.f / 512.f);
}

// =====================================================================
extern "C" void kernel_launch(void* const* d_in, const int* in_sizes, int n_in,
                              void* d_out, int out_size, void* d_ws, size_t ws_size,
                              hipStream_t stream)
{
  const float* x    = (const float*)d_in[0];
  const float* mask = (const float*)d_in[1];
  const float* Wq   = (const float*)d_in[2];
  const float* bq   = (const float*)d_in[3];
  const float* Wk   = (const float*)d_in[4];
  const float* bk   = (const float*)d_in[5];
  const float* Wv   = (const float*)d_in[6];
  const float* bv   = (const float*)d_in[7];
  const float* Wo   = (const float*)d_in[8];
  const float* bo   = (const float*)d_in[9];
  const float* Wiq  = (const float*)d_in[10];
  const float* biq  = (const float*)d_in[11];
  const float* Wik  = (const float*)d_in[12];
  const float* bik  = (const float*)d_in[13];
  const float* emb  = (const float*)d_in[14];
  const float* qnw  = (const float*)d_in[15];
  const float* knw  = (const float*)d_in[16];
  float* out = (float*)d_out;

  // Workspace (identical extents to the round-9-proven footprint).
  // Lifetime audit:
  //  qbuf: fp32 q (w:7 r:9)
  //  kbuf/vbuf: fp32 k,v (w:7 r:8) -> opart[2 planes] (w:9 r:10)
  //  ohi/olo: tiled split-bf16 o (w:10 r:11,13)
  //  xhi/xlo: x tiled bf16 (w:6 r:7) -> Knb/Vtb (w:8 r:9)
  //  Wbig_hi: QKV weights (w:5 r:7) -> gate + lpart (w:12/9 r:13/10)
  //  Wbig_lo: WoH (w:5 r:13) | F4 (w:2 r:3,4) | H5 (w:4 r:11) |
  //           G (w:11 r:12) | F4p (w:1 r:2)
  float* ws = (float*)d_ws;
  const size_t SZ = (size_t)BN_ * D_;
  float* qbuf = ws;
  float* kbuf = qbuf + SZ;
  float* vbuf = kbuf + SZ;
  float* opart = kbuf;                  // [2][BN][D] fp32 attn partials
  short* ohi  = (short*)(vbuf + SZ);
  short* olo  = ohi + SZ;
  short* xhi  = (short*)(ws + 4 * SZ);
  short* xlo  = xhi + SZ;
  short* Knb  = xhi;                    // [2][16][2048][64] bf16
  short* Vtb  = xlo;                    // [2][16][64][64][32] bf16
  short* Wbig_hi = (short*)(ws + 5 * SZ);
  short* Wbig_lo = Wbig_hi + (size_t)3 * D_ * D_;
  float* gate  = (float*)Wbig_hi;                       // [BN] (post-QKV)
  float* lpart = gate + BN_;                            // [2][BN][16]
  short* WoH = Wbig_lo;                                 // [D][D] tiled
  float* F4  = (float*)(Wbig_lo + (size_t)D_ * D_);     // [4][1024]
  float* H5  = F4 + 4 * D_;                             // [1025][5]
  float* G   = H5 + 1025 * 5;                           // [BN][5]
  float* F4p = G + (size_t)BN_ * 5;                     // [16][4][1024]

  const dim3 blk(256);

  // 1-4) gate-path algebra prep (rank-5 collapse), PARALLELIZED:
  fprep_p<<<dim3(4, 16), blk, 0, stream>>>(Wik, emb, F4p);
  freduce<<<dim3(16), blk, 0, stream>>>(F4p, F4);
  hprep2<<<dim3(1025), blk, 0, stream>>>(Wiq, F4, bik, biq, H5);

  // 5-6) weight prep (Wq,Wk,Wv,Wo) + x -> tiled bf16
  wsplitAll<<<dim3(16, 16, 4), blk, 0, stream>>>(Wq, Wk, Wv, Wo, Wbig_hi, WoH);
  asplit<<<(BN_ * D_ / 4) / 256, blk, 0, stream>>>(x, xhi);

  // 7) fused QKV projection (plain bf16, 1 MFMA/pair)
  mfgemm2<0, 0><<<dim3(8, 32, 3), blk, 0, stream>>>(
      xhi, nullptr, Wbig_hi, bq, bk, bv,
      qbuf, 8, (long)SZ, nullptr);

  // 8) KV prep (norm K, transpose V, bf16, swizzled; group-indexed)
  kvprep<<<dim3(KVLEN / 32, H_, 2), blk, 0, stream>>>(kbuf, vbuf, knw, Knb, Vtb);

  // 9) attention, KV-split x2 -> fp32 partials (over dead kbuf/vbuf)
  attn3<<<dim3(N_ / 128, H_, B_ * 2), blk, 0, stream>>>(
      qbuf, Knb, Vtb, qnw, opart, lpart);

  // 10) combine partials -> tiled split bf16 o
  attn_reduce<<<BN_, blk, 0, stream>>>(opart, lpart, ohi, olo);

  // 11) G = o @ H5 (the collapsed gate path: 42 MFLOP skinny product)
  gproj<<<dim3(32), blk, 0, stream>>>(ohi, H5, G);

  // 12) gate[row] = 1 + mean_m sigmoid(sc*(G·mask + c))
  gate_finish2<<<dim3(32), blk, 0, stream>>>(G, mask, gate);

  // 13) final: gate[row]*(o@Wo) + bo -> d_out (SPLIT=2: o hi/lo x Wo hi)
  mfgemm2<2, 2><<<dim3(8, 32, 1), blk, 0, stream>>>(
      ohi, olo, WoH, bo, nullptr, nullptr,
      out, 0, 0, gate);
}

// Round 18
// 204.267 us; speedup vs baseline: 1.4890x; 1.0867x over previous
//
#include <hip/hip_runtime.h>
#include <cmath>

// Problem constants (fixed by the reference file)
#define B_   8
#define N_   512
#define D_   1024
#define H_   16
#define HD_  64
#define NI_  4
#define BN_  (B_*N_)      // 4096 rows when [B,N,*] is flattened
#define KVLEN (NI_*N_)    // 2048 keys per attention group

typedef __attribute__((ext_vector_type(8)))  short  bf16x8;   // 8 bf16 bit patterns
typedef __attribute__((ext_vector_type(8)))  __bf16 bf16x8_t; // builtin operand type
typedef __attribute__((ext_vector_type(16))) float  f32x16;
typedef __attribute__((ext_vector_type(4)))  short  s16x4;
typedef __attribute__((ext_vector_type(2)))  unsigned u32x2;

// round-to-nearest-even bf16 conversion (bit trick)
__device__ __forceinline__ short bf16_rn(float x) {
  unsigned u = __float_as_uint(x);
  unsigned r = (u + 0x7FFFu + ((u >> 16) & 1u)) >> 16;
  return (short)r;
}

// RN hi/lo split: x = hi + lo + eps, |eps| <~ 2^-18 |x|.
__device__ __forceinline__ void split2(float x, short& hi, short& lo) {
  hi = bf16_rn(x);
  float h = __uint_as_float(((unsigned)(unsigned short)hi) << 16);
  float r = x - h;              // exact (Dekker-style split)
  lo = bf16_rn(r);
}

__device__ __forceinline__ f32x16 mfma_bf16(bf16x8 a, bf16x8 b, f32x16 c) {
  return __builtin_amdgcn_mfma_f32_32x32x16_bf16(
      __builtin_bit_cast(bf16x8_t, a), __builtin_bit_cast(bf16x8_t, b), c, 0, 0, 0);
}

#define GLOAD16(gp, lp) __builtin_amdgcn_global_load_lds( \
  (const __attribute__((address_space(1))) unsigned*)(gp), \
  (__attribute__((address_space(3))) unsigned*)(lp), 16, 0, 0)

// TILED layout for all bf16 GEMM operands (K = 1024):
// addr(row,k) = (((row>>7)*128 + (k>>3))*128 + (row&127))*8 + (k&7).
// GEMM staging is then a LINEAR copy -> fully coalesced global_load_lds.
__device__ __forceinline__ long tiled_off(int row, int k) {
  return ((((long)(row >> 7) * 128 + (k >> 3)) * 128 + (row & 127)) * 8 + (k & 7));
}

// T1 XCD-aware block swizzle (MI355X: 8 XCDs, private L2s). Remap so each
// XCD gets a CONTIGUOUS tile range. REQUIRES nwg % 8 == 0.
__device__ __forceinline__ void xcd_swizzle(int& bx, int& by, int& bz) {
  const int gx = gridDim.x, gy = gridDim.y;
  const int nwg = gx * gy * gridDim.z;
  const int lin = blockIdx.x + gx * (blockIdx.y + gy * blockIdx.z);
  const int swz = (lin & 7) * (nwg >> 3) + (lin >> 3);
  bx = swz % gx;
  const int rest = swz / gx;
  by = rest % gy;
  bz = rest / gy;
}

// =====================================================================
// Weight prep: z=0..2 Wq/Wk/Wv -> QKVh (combined [3072][1024] tiled);
// z=3 Wo -> WoH. All hi-only bf16.
// =====================================================================
__global__ __launch_bounds__(256) void wsplitAll(
    const float* __restrict__ Wq, const float* __restrict__ Wk,
    const float* __restrict__ Wv, const float* __restrict__ Wo,
    short* __restrict__ QKVh, short* __restrict__ WoH)
{
  __shared__ float tile[64][65];
  const int z = blockIdx.z;
  const float* W = (z == 0) ? Wq : (z == 1) ? Wk : (z == 2) ? Wv : Wo;
  const int t  = threadIdx.x;
  const int kb = blockIdx.y * 64;
  const int cb = blockIdx.x * 64;
  const int r0 = t >> 4;
  const int c4 = t & 15;
  #pragma unroll
  for (int i = 0; i < 4; i++) {
    const int r = r0 + i * 16;
    *(float4*)&tile[r][c4 * 4] = *(const float4*)&W[(long)(kb + r) * D_ + cb + c4 * 4];
  }
  __syncthreads();
  #pragma unroll
  for (int i = 0; i < 4; i++) {
    const int c = r0 + i * 16;
    short hi[4];
    #pragma unroll
    for (int e = 0; e < 4; e++)
      hi[e] = bf16_rn(tile[c4 * 4 + e][c]);
    if (z < 3)
      *(s16x4*)&QKVh[tiled_off(z * D_ + cb + c, kb + c4 * 4)] = *(s16x4*)hi;
    else
      *(s16x4*)&WoH[tiled_off(cb + c, kb + c4 * 4)] = *(s16x4*)hi;
  }
}

// =====================================================================
// Gate-path prep A: F4p[eb][j][d] = sum_{e in 16-chunk eb} emb[j][e] *
// Wik[e][d].  grid (4,64) = 256 blocks (r17 lesson: 64 blocks was
// latency-bound); each iteration reads a coalesced 1KB row segment.
// =====================================================================
__global__ __launch_bounds__(256) void fprep_p(
    const float* __restrict__ Wik, const float* __restrict__ emb,
    float* __restrict__ F4p)
{
  const int d  = blockIdx.x * 256 + threadIdx.x;
  const int eb = blockIdx.y;
  float s0 = 0, s1 = 0, s2 = 0, s3 = 0;
  for (int e = eb * 16; e < eb * 16 + 16; e++) {
    const float w = Wik[(long)e * D_ + d];
    s0 = fmaf(emb[e], w, s0);
    s1 = fmaf(emb[D_ + e], w, s1);
    s2 = fmaf(emb[2 * D_ + e], w, s2);
    s3 = fmaf(emb[3 * D_ + e], w, s3);
  }
  float* p = F4p + (long)eb * 4 * D_;
  p[d] = s0;  p[D_ + d] = s1;  p[2 * D_ + d] = s2;  p[3 * D_ + d] = s3;
}

// freduce: F4[j][d] = sum of 64 e-chunk partials (fixed order).
__global__ __launch_bounds__(256) void freduce(
    const float* __restrict__ F4p, float* __restrict__ F4)
{
  const int i = blockIdx.x * 256 + threadIdx.x;   // 0..4095
  float s = 0.f;
  #pragma unroll
  for (int eb = 0; eb < 64; eb++) s += F4p[(long)eb * 4096 + i];
  F4[i] = s;
}

// =====================================================================
// Gate-path prep B: H5[d][j] = Wiq[d]·F4[j] (j<4); H5[d][4]=Wiq[d]·bik.
// Consts row H5[1024][j] = F4[j]·biq (j<4), H5[1024][4] = biq·bik.
// One block per d-row (1024 + 1 consts): coalesced 4KB row reads.
// =====================================================================
__global__ __launch_bounds__(256) void hprep2(
    const float* __restrict__ Wiq, const float* __restrict__ F4,
    const float* __restrict__ bik, const float* __restrict__ biq,
    float* __restrict__ H5)
{
  __shared__ float red[4][5];
  const int t = threadIdx.x;
  const int blk = blockIdx.x;
  float s[5] = {0.f, 0.f, 0.f, 0.f, 0.f};
  const float* vr = (blk < 1024) ? Wiq + (long)blk * D_ : biq;
  for (int e = t; e < D_; e += 256) {
    const float w = vr[e];
    s[0] = fmaf(w, F4[e], s[0]);
    s[1] = fmaf(w, F4[D_ + e], s[1]);
    s[2] = fmaf(w, F4[2 * D_ + e], s[2]);
    s[3] = fmaf(w, F4[3 * D_ + e], s[3]);
    s[4] = fmaf(w, bik[e], s[4]);
  }
  #pragma unroll
  for (int j = 0; j < 5; j++)
    #pragma unroll
    for (int m = 1; m < 64; m <<= 1) s[j] += __shfl_xor(s[j], m);
  const int w64 = t >> 6, lane = t & 63;
  if (lane == 0)
    #pragma unroll
    for (int j = 0; j < 5; j++) red[w64][j] = s[j];
  __syncthreads();
  if (t < 5)
    H5[(long)blk * 5 + t] = red[0][t] + red[1][t] + red[2][t] + red[3][t];
}

// =====================================================================
// Elementwise fp32 -> tiled bf16 (hi only — QKV is plain bf16).
// =====================================================================
__global__ __launch_bounds__(256) void asplit(const float* __restrict__ in,
                                              short* __restrict__ hi)
{
  const long i4 = ((long)blockIdx.x * 256 + threadIdx.x) * 4;
  const int row = (int)(i4 >> 10);
  const int kk  = (int)(i4 & 1023);
  float4 v = *(const float4*)&in[i4];
  short h[4];
  h[0] = bf16_rn(v.x);
  h[1] = bf16_rn(v.y);
  h[2] = bf16_rn(v.z);
  h[3] = bf16_rn(v.w);
  *(s16x4*)&hi[tiled_off(row, kk)] = *(s16x4*)h;
}

// =====================================================================
// MFMA GEMM v7. Tiled bf16 operands, linear global_load_lds staging,
// double-buffered LDS, counted vmcnt, XCD-swizzled blocks.
// SPLIT=2: A hi/lo, B hi (2 MFMAs/pair); waves 0-2 stage {Ahi,Alo,Bhi},
//          wave 3 idle, vmcnt(8). 48 KB LDS.
// SPLIT=0: plain bf16 (1 MFMA/pair); waves 0,1 stage A halves, waves
//          2,3 stage B halves, vmcnt(4). 32 KB LDS.
// MODE 6: QKV fused. z=0: qbuf fp32; z=1: kbuf fp32; z=2: V written
//         DIRECTLY to Vtb (bf16, transposed+swizzled) — bit-identical
//         to the old kvprep rounding, deletes vbuf's 32MB round-trip.
// MODE 2: C = gate[row]*(A@B) + bias                  (final, SPLIT=2)
// =====================================================================
template<int MODE, int SPLIT>
__global__ __launch_bounds__(256) void mfgemm2(
    const short* __restrict__ Ahi, const short* __restrict__ Alo,
    const short* __restrict__ Bhi,
    const float* __restrict__ b0, const float* __restrict__ b1,
    const float* __restrict__ b2,
    float* __restrict__ C, short* __restrict__ Vout,
    int bBlk, long sC, const float* __restrict__ gate_in)
{
  constexpr int NOPS = (SPLIT == 2) ? 3 : 2;
  __shared__ short lds[2][NOPS][4096];
  const int t = threadIdx.x, w = t >> 6, lane = t & 63;
  int bx, by, bz;
  xcd_swizzle(bx, by, bz);
  const int rowBase = by * 128;
  const int colBase = bx * 128;
  const long aoff = (long)by * 131072;   // 128 oct * 128 rows * 8
  const long boff = (long)(bz * bBlk + bx) * 131072;

  const short* mySrc;
  int op, half;
  if (SPLIT == 2) {
    op = (w < 3) ? w : 0; half = 0;
    mySrc = (w == 0) ? Ahi + aoff : (w == 1) ? Alo + aoff : Bhi + boff;
  } else {
    op = w >> 1; half = w & 1;
    mySrc = op ? Bhi + boff : Ahi + aoff;
  }

  auto stage = [&](int buf, int tt) {
    if (SPLIT == 2) {
      if (w == 3) return;   // 3 operands, wave 3 idle
      const short* g = mySrc + ((long)tt * 512 + lane) * 8;
      #pragma unroll
      for (int i = 0; i < 8; i++)
        GLOAD16(g + i * 512, &lds[buf][op][i * 512]);
    } else {
      const short* g = mySrc + ((long)tt * 512 + half * 256 + lane) * 8;
      #pragma unroll
      for (int i = 0; i < 4; i++)
        GLOAD16(g + i * 512, &lds[buf][op][(half * 256 + i * 64) * 8]);
    }
  };

  const int wr = w >> 1, wc = w & 1;
  const int lrow = lane & 31, lk = lane >> 5;

  f32x16 acc[2][2] = {};

  auto compute = [&](int buf) {
    #pragma unroll
    for (int kh = 0; kh < 2; kh++) {
      const int kq = 2 * kh + lk;
      bf16x8 ah[2], bh[2];
      #pragma unroll
      for (int m = 0; m < 2; m++)
        ah[m] = *(const bf16x8*)&lds[buf][0][(kq * 128 + wr * 64 + m * 32 + lrow) * 8];
      #pragma unroll
      for (int n = 0; n < 2; n++)
        bh[n] = *(const bf16x8*)&lds[buf][(SPLIT == 2) ? 2 : 1][(kq * 128 + wc * 64 + n * 32 + lrow) * 8];
      if (SPLIT == 2) {
        bf16x8 al[2];
        #pragma unroll
        for (int m = 0; m < 2; m++)
          al[m] = *(const bf16x8*)&lds[buf][1][(kq * 128 + wr * 64 + m * 32 + lrow) * 8];
        #pragma unroll
        for (int m = 0; m < 2; m++)
          #pragma unroll
          for (int n = 0; n < 2; n++) {
            acc[m][n] = mfma_bf16(al[m], bh[n], acc[m][n]);
            acc[m][n] = mfma_bf16(ah[m], bh[n], acc[m][n]);
          }
      } else {
        #pragma unroll
        for (int m = 0; m < 2; m++)
          #pragma unroll
          for (int n = 0; n < 2; n++)
            acc[m][n] = mfma_bf16(ah[m], bh[n], acc[m][n]);
      }
    }
  };

  const int NT = 32;   // K=1024 / BK=32
  stage(0, 0);
  for (int tt = 0; tt < NT - 1; ++tt) {
    stage((tt + 1) & 1, tt + 1);
    if (SPLIT == 2) asm volatile("s_waitcnt vmcnt(8)" ::: "memory");
    else            asm volatile("s_waitcnt vmcnt(4)" ::: "memory");
    __builtin_amdgcn_s_barrier();
    __builtin_amdgcn_sched_barrier(0);
    compute(tt & 1);
    __builtin_amdgcn_s_barrier();
  }
  asm volatile("s_waitcnt vmcnt(0)" ::: "memory");
  __builtin_amdgcn_s_barrier();
  __builtin_amdgcn_sched_barrier(0);
  compute((NT - 1) & 1);

  // ---------------- epilogue ----------------
  const float* bias = (bz == 1) ? b1 : (bz == 2) ? b2 : b0;
  float bcol[2];
  #pragma unroll
  for (int n = 0; n < 2; n++)
    bcol[n] = bias[colBase + wc * 64 + n * 32 + lrow];

  if (MODE == 6 && bz == 2) {
    // V plane: write straight to Vtb [g][h][tile][d][32kv] swizzled.
    #pragma unroll
    for (int m = 0; m < 2; m++)
      #pragma unroll
      for (int r = 0; r < 16; r++) {
        const int row = rowBase + wr * 64 + m * 32 + (r & 3) + 8 * (r >> 2) + 4 * lk;
        const int bb = row >> 9, g = bb >> 2;
        const int kv = (bb & 3) * 512 + (row & 511);
        const int tile = kv >> 5, vkv = kv & 31;
        #pragma unroll
        for (int n = 0; n < 2; n++) {
          const int col = colBase + wc * 64 + n * 32 + lrow;
          const int h = col >> 6, dl = col & 63;
          const long idx = ((long)(g * H_ + h) * 64 + tile) * 2048
                         + dl * 32 + (((vkv >> 3) ^ ((dl >> 1) & 3)) * 8) + (vkv & 7);
          Vout[idx] = bf16_rn(acc[m][n][r] + bcol[n]);
        }
      }
    return;
  }

  float* Cb = C + (long)bz * sC;
  #pragma unroll
  for (int m = 0; m < 2; m++) {
    #pragma unroll
    for (int r = 0; r < 16; r++) {
      const int row = rowBase + wr * 64 + m * 32 + (r & 3) + 8 * (r >> 2) + 4 * lk;
      float g = 1.f;
      if (MODE == 2) g = gate_in[row];
      #pragma unroll
      for (int n = 0; n < 2; n++) {
        const int col = colBase + wc * 64 + n * 32 + lrow;
        Cb[(long)row * D_ + col] = acc[m][n][r] * g + bcol[n];
      }
    }
  }
}

// =====================================================================
// K prep only (V now written by the QKV GEMM epilogue): RMSNorm (+knw)
// -> bf16 swizzled [g][h][m][64], linear per 4KB tile.
// =====================================================================
__global__ __launch_bounds__(256) void kvprepK(
    const float* __restrict__ kf, const float* __restrict__ knw,
    short* __restrict__ Knb)
{
  const int tile = blockIdx.x, h = blockIdx.y, g = blockIdx.z;
  const int t = threadIdx.x;
  const int skv = t >> 3, sg = t & 7;
  const int m  = tile * 32 + skv;
  const int bb = g * NI_ + (m >> 9), nn = m & (N_ - 1);
  const float* kp = kf + ((long)(bb * N_ + nn)) * D_ + h * HD_ + sg * 8;
  float k8[8];
  *(float4*)&k8[0] = *(const float4*)&kp[0];
  *(float4*)&k8[4] = *(const float4*)&kp[4];
  float ks2 = 0.f;
  #pragma unroll
  for (int j = 0; j < 8; j++) ks2 += k8[j] * k8[j];
  ks2 += __shfl_xor(ks2, 1);
  ks2 += __shfl_xor(ks2, 2);
  ks2 += __shfl_xor(ks2, 4);
  const float kr = rsqrtf(ks2 * (1.f / 64.f) + 1e-6f);
  bf16x8 kb;
  #pragma unroll
  for (int j = 0; j < 8; j++) kb[j] = bf16_rn(k8[j] * kr * knw[sg * 8 + j]);
  *(bf16x8*)&Knb[((long)(g * H_ + h) * KVLEN + m) * 64 + ((sg ^ (m & 7)) * 8)] = kb;
}

// =====================================================================
// MFMA grouped flash attention (round-15 proven structure, unchanged):
// 2-deep double-buffer, scalar l, VGPR<=64, permlane32_swap half-swap,
// KV-SPLIT x2, XCD-swizzled. STATIC softmax max (-8): partials combine
// exactly (o=o0+o1, l=l0+l1).
// =====================================================================
__global__ __launch_bounds__(256) void attn3(
    const float* __restrict__ q, const short* __restrict__ Knb,
    const short* __restrict__ Vtb, const float* __restrict__ qnw,
    float* __restrict__ opart, float* __restrict__ lpart)
{
  int qb, h, bz;
  xcd_swizzle(qb, h, bz);
  const int b  = bz >> 1, s = bz & 1;
  const int g  = b >> 2;
  const int t  = threadIdx.x;
  const int w  = t >> 6;
  const int lane = t & 63;
  const int l31 = lane & 31, hi = lane >> 5;

  __shared__ short Kt[2][2048];
  __shared__ short Vt[2][2048];

  // ---- Q: load + RMSNorm + B-operand frags ----
  const int qrow = qb * 128 + w * 32 + l31;
  const float* qp = q + ((long)b * N_ + qrow) * D_ + h * HD_ + hi * 8;
  float qv[4][8];
  float ss = 0.f;
  #pragma unroll
  for (int c = 0; c < 4; c++) {
    *(float4*)&qv[c][0] = *(const float4*)&qp[c * 16];
    *(float4*)&qv[c][4] = *(const float4*)&qp[c * 16 + 4];
    #pragma unroll
    for (int j = 0; j < 8; j++) ss += qv[c][j] * qv[c][j];
  }
  ss += __shfl_xor(ss, 32);
  const float qr = rsqrtf(ss * (1.f / 64.f) + 1e-6f);
  bf16x8 qf[4];
  #pragma unroll
  for (int c = 0; c < 4; c++)
    #pragma unroll
    for (int j = 0; j < 8; j++)
      qf[c][j] = bf16_rn(qv[c][j] * qr * qnw[c * 16 + hi * 8 + j]);

  const short* Kg = Knb + (long)(g * H_ + h) * KVLEN * 64 + (long)s * 32 * 2048;
  const short* Vg = Vtb + (long)(g * H_ + h) * 64 * 2048 + (long)s * 32 * 2048;

  auto stage = [&](int buf, int i) {
    GLOAD16(Kg + (long)i * 2048 + t * 8, &Kt[buf][w * 512]);
    GLOAD16(Vg + (long)i * 2048 + t * 8, &Vt[buf][w * 512]);
  };

  f32x16 oacc[2] = {};
  float l = 0.f;

  stage(0, 0);
  for (int i = 0; i < 32; ++i) {
    const int buf = i & 1;
    if (i + 1 < 32) {
      stage(buf ^ 1, i + 1);
      asm volatile("s_waitcnt vmcnt(2)" ::: "memory");
    } else {
      asm volatile("s_waitcnt vmcnt(0)" ::: "memory");
    }
    __builtin_amdgcn_s_barrier();
    __builtin_amdgcn_sched_barrier(0);

    // ---- QK^T: scores[kv][q] ----
    f32x16 sc = {};
    #pragma unroll
    for (int c = 0; c < 4; c++) {
      bf16x8 kfr = *(const bf16x8*)&Kt[buf][l31 * 64 + (((2 * c + hi) * 8) ^ ((l31 & 7) << 3))];
      sc = mfma_bf16(kfr, qf[c], sc);
    }
    // ---- softmax, static max: p = exp2(s*0.125*log2e - 8*log2e) ----
    float p[16];
    #pragma unroll
    for (int r = 0; r < 16; r++) {
      p[r] = exp2f(fmaf(sc[r], 0.1803368801111244f, -11.541560327111961f));
      l += p[r];
    }
    // ---- pack P pairs to bf16 (cvt_pk), half-swap via permlane32 ----
    unsigned wd[8];
    #pragma unroll
    for (int i2 = 0; i2 < 8; i2++)
      asm("v_cvt_pk_bf16_f32 %0, %1, %2" : "=v"(wd[i2]) : "v"(p[2 * i2]), "v"(p[2 * i2 + 1]));
    u32x2 r0 = __builtin_amdgcn_permlane32_swap(wd[0], wd[2], false, false);
    u32x2 r1 = __builtin_amdgcn_permlane32_swap(wd[1], wd[3], false, false);
    u32x2 r2 = __builtin_amdgcn_permlane32_swap(wd[4], wd[6], false, false);
    u32x2 r3 = __builtin_amdgcn_permlane32_swap(wd[5], wd[7], false, false);
    int4 f0 = { (int)r0.x, (int)r1.x, (int)r0.y, (int)r1.y };
    int4 f1 = { (int)r2.x, (int)r3.x, (int)r2.y, (int)r3.y };
    // ---- PV ----
    #pragma unroll
    for (int n = 0; n < 2; n++) {
      const int d = n * 32 + l31;
      const int fd = (d >> 1) & 3;
      bf16x8 v0 = *(const bf16x8*)&Vt[buf][d * 32 + ((hi ^ fd) * 8)];
      bf16x8 v1 = *(const bf16x8*)&Vt[buf][d * 32 + (((2 | hi) ^ fd) * 8)];
      oacc[n] = mfma_bf16(__builtin_bit_cast(bf16x8, f0), v0, oacc[n]);
      oacc[n] = mfma_bf16(__builtin_bit_cast(bf16x8, f1), v1, oacc[n]);
    }
    __builtin_amdgcn_s_barrier();
  }

  // ---- epilogue: write PARTIAL o (no divide) + l ----
  l += __shfl_xor(l, 32);
  #pragma unroll
  for (int r = 0; r < 16; r++) {
    const int qg = qb * 128 + w * 32 + (r & 3) + 8 * (r >> 2) + 4 * hi;
    float* op = opart + ((long)s * BN_ + b * N_ + qg) * D_ + h * HD_ + l31;
    op[0]  = oacc[0][r];
    op[32] = oacc[1][r];
  }
  if (hi == 0)
    lpart[((long)s * BN_ + b * N_ + qb * 128 + w * 32 + l31) * H_ + h] = l;
}

// =====================================================================
// attn_reduce2 — FUSED attn_reduce + gproj + gate_finish2 (r17 lesson:
// the gate tail was 3 serialized small kernels re-reading ohi; the
// reduce block already owns the whole row, so G and gate are computed
// in-block and G never touches memory).
//  A: o = (o0+o1)/(l0+l1), split2 -> tiled bf16 hi/lo
//  B: G[0:5] = o·H5[:,j] + H5[1024][j]  (20 fma/thread + block reduce)
//  C: gate[row] = 1 + mean_m sigmoid(sc*(G·mask[b][m] + G4))
//     (2 sigmoids/thread + block reduce)
// =====================================================================
__global__ __launch_bounds__(256) void attn_reduce2(
    const float* __restrict__ opart, const float* __restrict__ lpart,
    const float* __restrict__ H5, const float* __restrict__ mask,
    short* __restrict__ ohi, short* __restrict__ olo,
    float* __restrict__ gate)
{
  __shared__ float red[4][5];
  __shared__ float Gs[5];
  __shared__ float sred[4];
  const int t = threadIdx.x;
  const int row = blockIdx.x;
  const int bb = row >> 9;
  const int col = t * 4;
  const int h   = col >> 6;
  // ---- A: combine partials ----
  const float l = lpart[(long)row * H_ + h] + lpart[((long)BN_ + row) * H_ + h];
  const float inv = 1.f / l;
  float4 a = *(const float4*)&opart[(long)row * D_ + col];
  float4 b = *(const float4*)&opart[((long)BN_ + row) * D_ + col];
  float o4[4] = { (a.x + b.x) * inv, (a.y + b.y) * inv,
                  (a.z + b.z) * inv, (a.w + b.w) * inv };
  short hh[4], ll[4];
  split2(o4[0], hh[0], ll[0]);
  split2(o4[1], hh[1], ll[1]);
  split2(o4[2], hh[2], ll[2]);
  split2(o4[3], hh[3], ll[3]);
  const long o = tiled_off(row, col);
  *(s16x4*)&ohi[o] = *(s16x4*)hh;
  *(s16x4*)&olo[o] = *(s16x4*)ll;
  // ---- B: G = o . H5 (block reduce) ----
  float s[5] = {0.f, 0.f, 0.f, 0.f, 0.f};
  #pragma unroll
  for (int c = 0; c < 4; c++) {
    const float* hp = &H5[(long)(col + c) * 5];
    #pragma unroll
    for (int j = 0; j < 5; j++) s[j] = fmaf(o4[c], hp[j], s[j]);
  }
  #pragma unroll
  for (int j = 0; j < 5; j++)
    #pragma unroll
    for (int m = 1; m < 64; m <<= 1) s[j] += __shfl_xor(s[j], m);
  const int w64 = t >> 6, lane = t & 63;
  if (lane == 0)
    #pragma unroll
    for (int j = 0; j < 5; j++) red[w64][j] = s[j];
  __syncthreads();
  if (t < 5) Gs[t] = red[0][t] + red[1][t] + red[2][t] + red[3][t] + H5[5120 + t];
  __syncthreads();
  const float g0 = Gs[0], g1 = Gs[1], g2 = Gs[2], g3 = Gs[3], g4 = Gs[4];
  // ---- C: gate via 512 sigmoids spread over the block ----
  const float sc = 0.125f / 16.f;       // SCALE/H
  const float* mrow = mask + (long)bb * N_ * NI_;
  float sg = 0.f;
  #pragma unroll
  for (int q = 0; q < 2; q++) {
    const float4 mk = *(const float4*)&mrow[(t * 2 + q) * 4];
    const float z = fmaf(g0, mk.x, fmaf(g1, mk.y, fmaf(g2, mk.z, fmaf(g3, mk.w, g4))));
    sg += 1.f / (1.f + __expf(-z * sc));
  }
  #pragma unroll
  for (int m = 1; m < 64; m <<= 1) sg += __shfl_xor(sg, m);
  if (lane == 0) sred[w64] = sg;
  __syncthreads();
  if (t == 0)
    gate[row] = 1.f + (sred[0] + sred[1] + sred[2] + sred[3]) * (1.f / 512.f);
}

// =====================================================================
extern "C" void kernel_launch(void* const* d_in, const int* in_sizes, int n_in,
                              void* d_out, int out_size, void* d_ws, size_t ws_size,
                              hipStream_t stream)
{
  const float* x    = (const float*)d_in[0];
  const float* mask = (const float*)d_in[1];
  const float* Wq   = (const float*)d_in[2];
  const float* bq   = (const float*)d_in[3];
  const float* Wk   = (const float*)d_in[4];
  const float* bk   = (const float*)d_in[5];
  const float* Wv   = (const float*)d_in[6];
  const float* bv   = (const float*)d_in[7];
  const float* Wo   = (const float*)d_in[8];
  const float* bo   = (const float*)d_in[9];
  const float* Wiq  = (const float*)d_in[10];
  const float* biq  = (const float*)d_in[11];
  const float* Wik  = (const float*)d_in[12];
  const float* bik  = (const float*)d_in[13];
  const float* emb  = (const float*)d_in[14];
  const float* qnw  = (const float*)d_in[15];
  const float* knw  = (const float*)d_in[16];
  float* out = (float*)d_out;

  // Workspace (identical extents to the round-9-proven footprint).
  // Lifetime audit:
  //  qbuf: fp32 q (w:7 r:9)
  //  kbuf: fp32 k (w:7 r:8) -> opart plane 0 (w:9 r:10)
  //  vbuf: UNWRITTEN by QKV now (V goes straight to Vtb) -> opart
  //        plane 1 (w:9 r:10)
  //  ohi/olo: tiled split-bf16 o (w:10 r:11)
  //  xhi: x tiled bf16 (w:6 r:7) -> Knb (w:8 r:9)
  //  xlo: dead during QKV -> Vtb (w:7(QKV z=2) r:9)
  //  Wbig_hi: QKV weights (w:5 r:7) -> gate + lpart (w:10/9 r:11/10)
  //  Wbig_lo: WoH (w:5 r:11) | F4 (w:2 r:3) | H5 (w:3 r:10) | F4p (w:1 r:2)
  float* ws = (float*)d_ws;
  const size_t SZ = (size_t)BN_ * D_;
  float* qbuf = ws;
  float* kbuf = qbuf + SZ;
  float* vbuf = kbuf + SZ;
  float* opart = kbuf;                  // [2][BN][D] fp32 attn partials
  short* ohi  = (short*)(vbuf + SZ);
  short* olo  = ohi + SZ;
  short* xhi  = (short*)(ws + 4 * SZ);
  short* xlo  = xhi + SZ;
  short* Knb  = xhi;                    // [2][16][2048][64] bf16
  short* Vtb  = xlo;                    // [2][16][64][64][32] bf16
  short* Wbig_hi = (short*)(ws + 5 * SZ);
  short* Wbig_lo = Wbig_hi + (size_t)3 * D_ * D_;
  float* gate  = (float*)Wbig_hi;                       // [BN] (post-QKV)
  float* lpart = gate + BN_;                            // [2][BN][16]
  short* WoH = Wbig_lo;                                 // [D][D] tiled
  float* F4  = (float*)(Wbig_lo + (size_t)D_ * D_);     // [4][1024]
  float* H5  = F4 + 4 * D_;                             // [1025][5]
  float* F4p = H5 + 1025 * 5;                           // [64][4][1024]

  const dim3 blk(256);

  // 1-3) gate-path algebra prep (rank-5 collapse), parallel grids
  fprep_p<<<dim3(4, 64), blk, 0, stream>>>(Wik, emb, F4p);
  freduce<<<dim3(16), blk, 0, stream>>>(F4p, F4);
  hprep2<<<dim3(1025), blk, 0, stream>>>(Wiq, F4, bik, biq, H5);

  // 4-5) weight prep (Wq,Wk,Wv,Wo) + x -> tiled bf16
  wsplitAll<<<dim3(16, 16, 4), blk, 0, stream>>>(Wq, Wk, Wv, Wo, Wbig_hi, WoH);
  asplit<<<(BN_ * D_ / 4) / 256, blk, 0, stream>>>(x, xhi);

  // 6) fused QKV projection; V plane writes Vtb directly (MODE 6)
  mfgemm2<6, 0><<<dim3(8, 32, 3), blk, 0, stream>>>(
      xhi, nullptr, Wbig_hi, bq, bk, bv,
      qbuf, Vtb, 8, (long)SZ, nullptr);

  // 7) K prep (norm + bf16 + swizzle; V already done)
  kvprepK<<<dim3(KVLEN / 32, H_, 2), blk, 0, stream>>>(kbuf, knw, Knb);

  // 8) attention, KV-split x2 -> fp32 partials (over dead kbuf/vbuf)
  attn3<<<dim3(N_ / 128, H_, B_ * 2), blk, 0, stream>>>(
      qbuf, Knb, Vtb, qnw, opart, lpart);

  // 9) combine partials -> o, and compute gate in-block (G never stored)
  attn_reduce2<<<BN_, blk, 0, stream>>>(opart, lpart, H5, mask, ohi, olo, gate);

  // 10) final: gate[row]*(o@Wo) + bo -> d_out (SPLIT=2: o hi/lo x Wo hi)
  mfgemm2<2, 2><<<dim3(8, 32, 1), blk, 0, stream>>>(
      ohi, olo, WoH, bo, nullptr, nullptr,
      out, nullptr, 0, 0, gate);
}

// Round 19
// 195.475 us; speedup vs baseline: 1.5560x; 1.0450x over previous
//
#include <hip/hip_runtime.h>
#include <cmath>

// Problem constants (fixed by the reference file)
#define B_   8
#define N_   512
#define D_   1024
#define H_   16
#define HD_  64
#define NI_  4
#define BN_  (B_*N_)      // 4096 rows when [B,N,*] is flattened
#define KVLEN (NI_*N_)    // 2048 keys per attention group

typedef __attribute__((ext_vector_type(8)))  short  bf16x8;   // 8 bf16 bit patterns
typedef __attribute__((ext_vector_type(8)))  __bf16 bf16x8_t; // builtin operand type
typedef __attribute__((ext_vector_type(16))) float  f32x16;
typedef __attribute__((ext_vector_type(4)))  short  s16x4;
typedef __attribute__((ext_vector_type(2)))  unsigned u32x2;

// round-to-nearest-even bf16 conversion (bit trick)
__device__ __forceinline__ short bf16_rn(float x) {
  unsigned u = __float_as_uint(x);
  unsigned r = (u + 0x7FFFu + ((u >> 16) & 1u)) >> 16;
  return (short)r;
}

// RN hi/lo split: x = hi + lo + eps, |eps| <~ 2^-18 |x|.
__device__ __forceinline__ void split2(float x, short& hi, short& lo) {
  hi = bf16_rn(x);
  float h = __uint_as_float(((unsigned)(unsigned short)hi) << 16);
  float r = x - h;              // exact (Dekker-style split)
  lo = bf16_rn(r);
}

__device__ __forceinline__ f32x16 mfma_bf16(bf16x8 a, bf16x8 b, f32x16 c) {
  return __builtin_amdgcn_mfma_f32_32x32x16_bf16(
      __builtin_bit_cast(bf16x8_t, a), __builtin_bit_cast(bf16x8_t, b), c, 0, 0, 0);
}

#define GLOAD16(gp, lp) __builtin_amdgcn_global_load_lds( \
  (const __attribute__((address_space(1))) unsigned*)(gp), \
  (__attribute__((address_space(3))) unsigned*)(lp), 16, 0, 0)

// TILED layout for all bf16 GEMM operands (K = 1024):
// addr(row,k) = (((row>>7)*128 + (k>>3))*128 + (row&127))*8 + (k&7).
// GEMM staging is then a LINEAR copy -> fully coalesced global_load_lds.
__device__ __forceinline__ long tiled_off(int row, int k) {
  return ((((long)(row >> 7) * 128 + (k >> 3)) * 128 + (row & 127)) * 8 + (k & 7));
}

// T1 XCD-aware block swizzle (MI355X: 8 XCDs, private L2s). Remap so each
// XCD gets a CONTIGUOUS tile range. REQUIRES nwg % 8 == 0.
__device__ __forceinline__ void xcd_swizzle(int& bx, int& by, int& bz) {
  const int gx = gridDim.x, gy = gridDim.y;
  const int nwg = gx * gy * gridDim.z;
  const int lin = blockIdx.x + gx * (blockIdx.y + gy * blockIdx.z);
  const int swz = (lin & 7) * (nwg >> 3) + (lin >> 3);
  bx = swz % gx;
  const int rest = swz / gx;
  by = rest % gy;
  bz = rest / gy;
}

// =====================================================================
// Weight + x prep, ONE dispatch (z=0..7):
//  z=0..2: Wq/Wk/Wv -> QKVh (combined [3072][1024] tiled, transposed)
//  z=3:    Wo -> WoH (tiled, transposed)
//  z=4..7: x rows (z-4)*1024.. -> Xh (tiled, NO transpose — direct
//          convert; r18's separate asplit launch fused away)
// All hi-only bf16.
// =====================================================================
__global__ __launch_bounds__(256) void wsplitAll(
    const float* __restrict__ Wq, const float* __restrict__ Wk,
    const float* __restrict__ Wv, const float* __restrict__ Wo,
    const float* __restrict__ x,
    short* __restrict__ QKVh, short* __restrict__ WoH,
    short* __restrict__ Xh)
{
  const int z = blockIdx.z;
  const int t  = threadIdx.x;
  if (z >= 4) {
    // ---- x plane: direct tiled convert (no transpose) ----
    const int rowB = (z - 4) * 1024 + blockIdx.y * 64;
    const int colB = blockIdx.x * 64;
    const int r0 = t >> 4;           // 0..15
    const int c4 = t & 15;           // float4 index
    #pragma unroll
    for (int i = 0; i < 4; i++) {
      const int row = rowB + r0 + i * 16;
      float4 v = *(const float4*)&x[(long)row * D_ + colB + c4 * 4];
      short h[4];
      h[0] = bf16_rn(v.x);  h[1] = bf16_rn(v.y);
      h[2] = bf16_rn(v.z);  h[3] = bf16_rn(v.w);
      *(s16x4*)&Xh[tiled_off(row, colB + c4 * 4)] = *(s16x4*)h;
    }
    return;
  }
  __shared__ float tile[64][65];
  const float* W = (z == 0) ? Wq : (z == 1) ? Wk : (z == 2) ? Wv : Wo;
  const int kb = blockIdx.y * 64;
  const int cb = blockIdx.x * 64;
  const int r0 = t >> 4;
  const int c4 = t & 15;
  #pragma unroll
  for (int i = 0; i < 4; i++) {
    const int r = r0 + i * 16;
    *(float4*)&tile[r][c4 * 4] = *(const float4*)&W[(long)(kb + r) * D_ + cb + c4 * 4];
  }
  __syncthreads();
  #pragma unroll
  for (int i = 0; i < 4; i++) {
    const int c = r0 + i * 16;
    short hi[4];
    #pragma unroll
    for (int e = 0; e < 4; e++)
      hi[e] = bf16_rn(tile[c4 * 4 + e][c]);
    if (z < 3)
      *(s16x4*)&QKVh[tiled_off(z * D_ + cb + c, kb + c4 * 4)] = *(s16x4*)hi;
    else
      *(s16x4*)&WoH[tiled_off(cb + c, kb + c4 * 4)] = *(s16x4*)hi;
  }
}

// =====================================================================
// Gate-path prep A: F4p[eb][j][d] = sum_{e in 16-chunk eb} emb[j][e] *
// Wik[e][d].  grid (4,64) = 256 blocks; coalesced 1KB row segments.
// =====================================================================
__global__ __launch_bounds__(256) void fprep_p(
    const float* __restrict__ Wik, const float* __restrict__ emb,
    float* __restrict__ F4p)
{
  const int d  = blockIdx.x * 256 + threadIdx.x;
  const int eb = blockIdx.y;
  float s0 = 0, s1 = 0, s2 = 0, s3 = 0;
  for (int e = eb * 16; e < eb * 16 + 16; e++) {
    const float w = Wik[(long)e * D_ + d];
    s0 = fmaf(emb[e], w, s0);
    s1 = fmaf(emb[D_ + e], w, s1);
    s2 = fmaf(emb[2 * D_ + e], w, s2);
    s3 = fmaf(emb[3 * D_ + e], w, s3);
  }
  float* p = F4p + (long)eb * 4 * D_;
  p[d] = s0;  p[D_ + d] = s1;  p[2 * D_ + d] = s2;  p[3 * D_ + d] = s3;
}

// freduce: F4[j][d] = sum of 64 e-chunk partials (fixed order).
__global__ __launch_bounds__(256) void freduce(
    const float* __restrict__ F4p, float* __restrict__ F4)
{
  const int i = blockIdx.x * 256 + threadIdx.x;   // 0..4095
  float s = 0.f;
  #pragma unroll
  for (int eb = 0; eb < 64; eb++) s += F4p[(long)eb * 4096 + i];
  F4[i] = s;
}

// =====================================================================
// Gate-path prep B: H5[d][j] = Wiq[d]·F4[j] (j<4); H5[d][4]=Wiq[d]·bik.
// Consts row H5[1024][j] = F4[j]·biq (j<4), H5[1024][4] = biq·bik.
// One block per d-row (1024 + 1 consts): coalesced 4KB row reads.
// =====================================================================
__global__ __launch_bounds__(256) void hprep2(
    const float* __restrict__ Wiq, const float* __restrict__ F4,
    const float* __restrict__ bik, const float* __restrict__ biq,
    float* __restrict__ H5)
{
  __shared__ float red[4][5];
  const int t = threadIdx.x;
  const int blk = blockIdx.x;
  float s[5] = {0.f, 0.f, 0.f, 0.f, 0.f};
  const float* vr = (blk < 1024) ? Wiq + (long)blk * D_ : biq;
  for (int e = t; e < D_; e += 256) {
    const float w = vr[e];
    s[0] = fmaf(w, F4[e], s[0]);
    s[1] = fmaf(w, F4[D_ + e], s[1]);
    s[2] = fmaf(w, F4[2 * D_ + e], s[2]);
    s[3] = fmaf(w, F4[3 * D_ + e], s[3]);
    s[4] = fmaf(w, bik[e], s[4]);
  }
  #pragma unroll
  for (int j = 0; j < 5; j++)
    #pragma unroll
    for (int m = 1; m < 64; m <<= 1) s[j] += __shfl_xor(s[j], m);
  const int w64 = t >> 6, lane = t & 63;
  if (lane == 0)
    #pragma unroll
    for (int j = 0; j < 5; j++) red[w64][j] = s[j];
  __syncthreads();
  if (t < 5)
    H5[(long)blk * 5 + t] = red[0][t] + red[1][t] + red[2][t] + red[3][t];
}

// =====================================================================
// MFMA GEMM v7. Tiled bf16 operands, linear global_load_lds staging,
// double-buffered LDS, counted vmcnt, XCD-swizzled blocks.
// SPLIT=2: A hi/lo, B hi (2 MFMAs/pair); waves 0-2 stage {Ahi,Alo,Bhi},
//          wave 3 idle, vmcnt(8). 48 KB LDS.
// SPLIT=0: plain bf16 (1 MFMA/pair); waves 0,1 stage A halves, waves
//          2,3 stage B halves, vmcnt(4). 32 KB LDS.
// MODE 6: QKV fused. z=0: qbuf fp32; z=1: kbuf fp32; z=2: V written
//         DIRECTLY to Vtb (bf16, transposed+swizzled).
// MODE 2: C = gate[row]*(A@B) + bias                  (final, SPLIT=2)
// =====================================================================
template<int MODE, int SPLIT>
__global__ __launch_bounds__(256) void mfgemm2(
    const short* __restrict__ Ahi, const short* __restrict__ Alo,
    const short* __restrict__ Bhi,
    const float* __restrict__ b0, const float* __restrict__ b1,
    const float* __restrict__ b2,
    float* __restrict__ C, short* __restrict__ Vout,
    int bBlk, long sC, const float* __restrict__ gate_in)
{
  constexpr int NOPS = (SPLIT == 2) ? 3 : 2;
  __shared__ short lds[2][NOPS][4096];
  const int t = threadIdx.x, w = t >> 6, lane = t & 63;
  int bx, by, bz;
  xcd_swizzle(bx, by, bz);
  const int rowBase = by * 128;
  const int colBase = bx * 128;
  const long aoff = (long)by * 131072;   // 128 oct * 128 rows * 8
  const long boff = (long)(bz * bBlk + bx) * 131072;

  const short* mySrc;
  int op, half;
  if (SPLIT == 2) {
    op = (w < 3) ? w : 0; half = 0;
    mySrc = (w == 0) ? Ahi + aoff : (w == 1) ? Alo + aoff : Bhi + boff;
  } else {
    op = w >> 1; half = w & 1;
    mySrc = op ? Bhi + boff : Ahi + aoff;
  }

  auto stage = [&](int buf, int tt) {
    if (SPLIT == 2) {
      if (w == 3) return;   // 3 operands, wave 3 idle
      const short* g = mySrc + ((long)tt * 512 + lane) * 8;
      #pragma unroll
      for (int i = 0; i < 8; i++)
        GLOAD16(g + i * 512, &lds[buf][op][i * 512]);
    } else {
      const short* g = mySrc + ((long)tt * 512 + half * 256 + lane) * 8;
      #pragma unroll
      for (int i = 0; i < 4; i++)
        GLOAD16(g + i * 512, &lds[buf][op][(half * 256 + i * 64) * 8]);
    }
  };

  const int wr = w >> 1, wc = w & 1;
  const int lrow = lane & 31, lk = lane >> 5;

  f32x16 acc[2][2] = {};

  auto compute = [&](int buf) {
    #pragma unroll
    for (int kh = 0; kh < 2; kh++) {
      const int kq = 2 * kh + lk;
      bf16x8 ah[2], bh[2];
      #pragma unroll
      for (int m = 0; m < 2; m++)
        ah[m] = *(const bf16x8*)&lds[buf][0][(kq * 128 + wr * 64 + m * 32 + lrow) * 8];
      #pragma unroll
      for (int n = 0; n < 2; n++)
        bh[n] = *(const bf16x8*)&lds[buf][(SPLIT == 2) ? 2 : 1][(kq * 128 + wc * 64 + n * 32 + lrow) * 8];
      if (SPLIT == 2) {
        bf16x8 al[2];
        #pragma unroll
        for (int m = 0; m < 2; m++)
          al[m] = *(const bf16x8*)&lds[buf][1][(kq * 128 + wr * 64 + m * 32 + lrow) * 8];
        #pragma unroll
        for (int m = 0; m < 2; m++)
          #pragma unroll
          for (int n = 0; n < 2; n++) {
            acc[m][n] = mfma_bf16(al[m], bh[n], acc[m][n]);
            acc[m][n] = mfma_bf16(ah[m], bh[n], acc[m][n]);
          }
      } else {
        #pragma unroll
        for (int m = 0; m < 2; m++)
          #pragma unroll
          for (int n = 0; n < 2; n++)
            acc[m][n] = mfma_bf16(ah[m], bh[n], acc[m][n]);
      }
    }
  };

  const int NT = 32;   // K=1024 / BK=32
  stage(0, 0);
  for (int tt = 0; tt < NT - 1; ++tt) {
    stage((tt + 1) & 1, tt + 1);
    if (SPLIT == 2) asm volatile("s_waitcnt vmcnt(8)" ::: "memory");
    else            asm volatile("s_waitcnt vmcnt(4)" ::: "memory");
    __builtin_amdgcn_s_barrier();
    __builtin_amdgcn_sched_barrier(0);
    compute(tt & 1);
    __builtin_amdgcn_s_barrier();
  }
  asm volatile("s_waitcnt vmcnt(0)" ::: "memory");
  __builtin_amdgcn_s_barrier();
  __builtin_amdgcn_sched_barrier(0);
  compute((NT - 1) & 1);

  // ---------------- epilogue ----------------
  const float* bias = (bz == 1) ? b1 : (bz == 2) ? b2 : b0;
  float bcol[2];
  #pragma unroll
  for (int n = 0; n < 2; n++)
    bcol[n] = bias[colBase + wc * 64 + n * 32 + lrow];

  if (MODE == 6 && bz == 2) {
    // V plane: write straight to Vtb [g][h][tile][d][32kv] swizzled.
    #pragma unroll
    for (int m = 0; m < 2; m++)
      #pragma unroll
      for (int r = 0; r < 16; r++) {
        const int row = rowBase + wr * 64 + m * 32 + (r & 3) + 8 * (r >> 2) + 4 * lk;
        const int bb = row >> 9, g = bb >> 2;
        const int kv = (bb & 3) * 512 + (row & 511);
        const int tile = kv >> 5, vkv = kv & 31;
        #pragma unroll
        for (int n = 0; n < 2; n++) {
          const int col = colBase + wc * 64 + n * 32 + lrow;
          const int h = col >> 6, dl = col & 63;
          const long idx = ((long)(g * H_ + h) * 64 + tile) * 2048
                         + dl * 32 + (((vkv >> 3) ^ ((dl >> 1) & 3)) * 8) + (vkv & 7);
          Vout[idx] = bf16_rn(acc[m][n][r] + bcol[n]);
        }
      }
    return;
  }

  float* Cb = C + (long)bz * sC;
  #pragma unroll
  for (int m = 0; m < 2; m++) {
    #pragma unroll
    for (int r = 0; r < 16; r++) {
      const int row = rowBase + wr * 64 + m * 32 + (r & 3) + 8 * (r >> 2) + 4 * lk;
      float g = 1.f;
      if (MODE == 2) g = gate_in[row];
      #pragma unroll
      for (int n = 0; n < 2; n++) {
        const int col = colBase + wc * 64 + n * 32 + lrow;
        Cb[(long)row * D_ + col] = acc[m][n][r] * g + bcol[n];
      }
    }
  }
}

// =====================================================================
// K prep only (V written by the QKV GEMM epilogue): RMSNorm (+knw)
// -> bf16 swizzled [g][h][m][64], linear per 4KB tile.
// =====================================================================
__global__ __launch_bounds__(256) void kvprepK(
    const float* __restrict__ kf, const float* __restrict__ knw,
    short* __restrict__ Knb)
{
  const int tile = blockIdx.x, h = blockIdx.y, g = blockIdx.z;
  const int t = threadIdx.x;
  const int skv = t >> 3, sg = t & 7;
  const int m  = tile * 32 + skv;
  const int bb = g * NI_ + (m >> 9), nn = m & (N_ - 1);
  const float* kp = kf + ((long)(bb * N_ + nn)) * D_ + h * HD_ + sg * 8;
  float k8[8];
  *(float4*)&k8[0] = *(const float4*)&kp[0];
  *(float4*)&k8[4] = *(const float4*)&kp[4];
  float ks2 = 0.f;
  #pragma unroll
  for (int j = 0; j < 8; j++) ks2 += k8[j] * k8[j];
  ks2 += __shfl_xor(ks2, 1);
  ks2 += __shfl_xor(ks2, 2);
  ks2 += __shfl_xor(ks2, 4);
  const float kr = rsqrtf(ks2 * (1.f / 64.f) + 1e-6f);
  bf16x8 kb;
  #pragma unroll
  for (int j = 0; j < 8; j++) kb[j] = bf16_rn(k8[j] * kr * knw[sg * 8 + j]);
  *(bf16x8*)&Knb[((long)(g * H_ + h) * KVLEN + m) * 64 + ((sg ^ (m & 7)) * 8)] = kb;
}

// =====================================================================
// MFMA grouped flash attention (round-15 proven structure) +
// ROUND-19: softmax scale/offset folded into the Q fragment.
//  - qf carries SCALE*log2e = 0.18033688 (qf feeds ONLY QK^T).
//  - p~ = exp2(sc) directly (1 op; the old per-element fmaf is gone).
//  - the 2^-11.54 static-max offset is a CONSTANT factor on every p;
//    o = sum(p v)/sum(p) cancels it EXACTLY, so it is simply dropped.
//    Ranges: p~ <= 2980, l <= 6.1e6, oacc <= ~1e7 — fp32/bf16-rel safe.
// 2-deep double-buffer, scalar l, VGPR<=64, permlane32_swap half-swap,
// KV-SPLIT x2, XCD-swizzled. Partials combine exactly (o=o0+o1, l=l0+l1).
// =====================================================================
__global__ __launch_bounds__(256) void attn3(
    const float* __restrict__ q, const short* __restrict__ Knb,
    const short* __restrict__ Vtb, const float* __restrict__ qnw,
    float* __restrict__ opart, float* __restrict__ lpart)
{
  int qb, h, bz;
  xcd_swizzle(qb, h, bz);
  const int b  = bz >> 1, s = bz & 1;
  const int g  = b >> 2;
  const int t  = threadIdx.x;
  const int w  = t >> 6;
  const int lane = t & 63;
  const int l31 = lane & 31, hi = lane >> 5;

  __shared__ short Kt[2][2048];
  __shared__ short Vt[2][2048];

  // ---- Q: load + RMSNorm (+ folded softmax scale) + B-operand frags ----
  const int qrow = qb * 128 + w * 32 + l31;
  const float* qp = q + ((long)b * N_ + qrow) * D_ + h * HD_ + hi * 8;
  float qv[4][8];
  float ss = 0.f;
  #pragma unroll
  for (int c = 0; c < 4; c++) {
    *(float4*)&qv[c][0] = *(const float4*)&qp[c * 16];
    *(float4*)&qv[c][4] = *(const float4*)&qp[c * 16 + 4];
    #pragma unroll
    for (int j = 0; j < 8; j++) ss += qv[c][j] * qv[c][j];
  }
  ss += __shfl_xor(ss, 32);
  const float qr = rsqrtf(ss * (1.f / 64.f) + 1e-6f) * 0.1803368801111244f;
  bf16x8 qf[4];
  #pragma unroll
  for (int c = 0; c < 4; c++)
    #pragma unroll
    for (int j = 0; j < 8; j++)
      qf[c][j] = bf16_rn(qv[c][j] * qr * qnw[c * 16 + hi * 8 + j]);

  const short* Kg = Knb + (long)(g * H_ + h) * KVLEN * 64 + (long)s * 32 * 2048;
  const short* Vg = Vtb + (long)(g * H_ + h) * 64 * 2048 + (long)s * 32 * 2048;

  auto stage = [&](int buf, int i) {
    GLOAD16(Kg + (long)i * 2048 + t * 8, &Kt[buf][w * 512]);
    GLOAD16(Vg + (long)i * 2048 + t * 8, &Vt[buf][w * 512]);
  };

  f32x16 oacc[2] = {};
  float l = 0.f;

  stage(0, 0);
  for (int i = 0; i < 32; ++i) {
    const int buf = i & 1;
    if (i + 1 < 32) {
      stage(buf ^ 1, i + 1);
      asm volatile("s_waitcnt vmcnt(2)" ::: "memory");
    } else {
      asm volatile("s_waitcnt vmcnt(0)" ::: "memory");
    }
    __builtin_amdgcn_s_barrier();
    __builtin_amdgcn_sched_barrier(0);

    // ---- QK^T: scores[kv][q], pre-scaled by folded 0.18033688 ----
    f32x16 sc = {};
    #pragma unroll
    for (int c = 0; c < 4; c++) {
      bf16x8 kfr = *(const bf16x8*)&Kt[buf][l31 * 64 + (((2 * c + hi) * 8) ^ ((l31 & 7) << 3))];
      sc = mfma_bf16(kfr, qf[c], sc);
    }
    // ---- softmax kernel: p~ = exp2(sc), constant offset cancels in o ----
    float p[16];
    #pragma unroll
    for (int r = 0; r < 16; r++) {
      p[r] = exp2f(sc[r]);
      l += p[r];
    }
    // ---- pack P pairs to bf16 (cvt_pk), half-swap via permlane32 ----
    unsigned wd[8];
    #pragma unroll
    for (int i2 = 0; i2 < 8; i2++)
      asm("v_cvt_pk_bf16_f32 %0, %1, %2" : "=v"(wd[i2]) : "v"(p[2 * i2]), "v"(p[2 * i2 + 1]));
    u32x2 r0 = __builtin_amdgcn_permlane32_swap(wd[0], wd[2], false, false);
    u32x2 r1 = __builtin_amdgcn_permlane32_swap(wd[1], wd[3], false, false);
    u32x2 r2 = __builtin_amdgcn_permlane32_swap(wd[4], wd[6], false, false);
    u32x2 r3 = __builtin_amdgcn_permlane32_swap(wd[5], wd[7], false, false);
    int4 f0 = { (int)r0.x, (int)r1.x, (int)r0.y, (int)r1.y };
    int4 f1 = { (int)r2.x, (int)r3.x, (int)r2.y, (int)r3.y };
    // ---- PV ----
    #pragma unroll
    for (int n = 0; n < 2; n++) {
      const int d = n * 32 + l31;
      const int fd = (d >> 1) & 3;
      bf16x8 v0 = *(const bf16x8*)&Vt[buf][d * 32 + ((hi ^ fd) * 8)];
      bf16x8 v1 = *(const bf16x8*)&Vt[buf][d * 32 + (((2 | hi) ^ fd) * 8)];
      oacc[n] = mfma_bf16(__builtin_bit_cast(bf16x8, f0), v0, oacc[n]);
      oacc[n] = mfma_bf16(__builtin_bit_cast(bf16x8, f1), v1, oacc[n]);
    }
    __builtin_amdgcn_s_barrier();
  }

  // ---- epilogue: write PARTIAL o (no divide) + l ----
  l += __shfl_xor(l, 32);
  #pragma unroll
  for (int r = 0; r < 16; r++) {
    const int qg = qb * 128 + w * 32 + (r & 3) + 8 * (r >> 2) + 4 * hi;
    float* op = opart + ((long)s * BN_ + b * N_ + qg) * D_ + h * HD_ + l31;
    op[0]  = oacc[0][r];
    op[32] = oacc[1][r];
  }
  if (hi == 0)
    lpart[((long)s * BN_ + b * N_ + qb * 128 + w * 32 + l31) * H_ + h] = l;
}

// =====================================================================
// attn_reduce2 — FUSED attn_reduce + gproj + gate_finish2.
//  A: o = (o0+o1)/(l0+l1), split2 -> tiled bf16 hi/lo
//  B: G[0:5] = o·H5[:,j] + H5[1024][j]  (block reduce; G never stored)
//  C: gate[row] = 1 + mean_m sigmoid(sc*(G·mask[b][m] + G4))
// =====================================================================
__global__ __launch_bounds__(256) void attn_reduce2(
    const float* __restrict__ opart, const float* __restrict__ lpart,
    const float* __restrict__ H5, const float* __restrict__ mask,
    short* __restrict__ ohi, short* __restrict__ olo,
    float* __restrict__ gate)
{
  __shared__ float red[4][5];
  __shared__ float Gs[5];
  __shared__ float sred[4];
  const int t = threadIdx.x;
  const int row = blockIdx.x;
  const int bb = row >> 9;
  const int col = t * 4;
  const int h   = col >> 6;
  // ---- A: combine partials ----
  const float l = lpart[(long)row * H_ + h] + lpart[((long)BN_ + row) * H_ + h];
  const float inv = 1.f / l;
  float4 a = *(const float4*)&opart[(long)row * D_ + col];
  float4 b = *(const float4*)&opart[((long)BN_ + row) * D_ + col];
  float o4[4] = { (a.x + b.x) * inv, (a.y + b.y) * inv,
                  (a.z + b.z) * inv, (a.w + b.w) * inv };
  short hh[4], ll[4];
  split2(o4[0], hh[0], ll[0]);
  split2(o4[1], hh[1], ll[1]);
  split2(o4[2], hh[2], ll[2]);
  split2(o4[3], hh[3], ll[3]);
  const long o = tiled_off(row, col);
  *(s16x4*)&ohi[o] = *(s16x4*)hh;
  *(s16x4*)&olo[o] = *(s16x4*)ll;
  // ---- B: G = o . H5 (block reduce) ----
  float s[5] = {0.f, 0.f, 0.f, 0.f, 0.f};
  #pragma unroll
  for (int c = 0; c < 4; c++) {
    const float* hp = &H5[(long)(col + c) * 5];
    #pragma unroll
    for (int j = 0; j < 5; j++) s[j] = fmaf(o4[c], hp[j], s[j]);
  }
  #pragma unroll
  for (int j = 0; j < 5; j++)
    #pragma unroll
    for (int m = 1; m < 64; m <<= 1) s[j] += __shfl_xor(s[j], m);
  const int w64 = t >> 6, lane = t & 63;
  if (lane == 0)
    #pragma unroll
    for (int j = 0; j < 5; j++) red[w64][j] = s[j];
  __syncthreads();
  if (t < 5) Gs[t] = red[0][t] + red[1][t] + red[2][t] + red[3][t] + H5[5120 + t];
  __syncthreads();
  const float g0 = Gs[0], g1 = Gs[1], g2 = Gs[2], g3 = Gs[3], g4 = Gs[4];
  // ---- C: gate via 512 sigmoids spread over the block ----
  const float sc = 0.125f / 16.f;       // SCALE/H
  const float* mrow = mask + (long)bb * N_ * NI_;
  float sg = 0.f;
  #pragma unroll
  for (int q = 0; q < 2; q++) {
    const float4 mk = *(const float4*)&mrow[(t * 2 + q) * 4];
    const float z = fmaf(g0, mk.x, fmaf(g1, mk.y, fmaf(g2, mk.z, fmaf(g3, mk.w, g4))));
    sg += 1.f / (1.f + __expf(-z * sc));
  }
  #pragma unroll
  for (int m = 1; m < 64; m <<= 1) sg += __shfl_xor(sg, m);
  if (lane == 0) sred[w64] = sg;
  __syncthreads();
  if (t == 0)
    gate[row] = 1.f + (sred[0] + sred[1] + sred[2] + sred[3]) * (1.f / 512.f);
}

// =====================================================================
extern "C" void kernel_launch(void* const* d_in, const int* in_sizes, int n_in,
                              void* d_out, int out_size, void* d_ws, size_t ws_size,
                              hipStream_t stream)
{
  const float* x    = (const float*)d_in[0];
  const float* mask = (const float*)d_in[1];
  const float* Wq   = (const float*)d_in[2];
  const float* bq   = (const float*)d_in[3];
  const float* Wk   = (const float*)d_in[4];
  const float* bk   = (const float*)d_in[5];
  const float* Wv   = (const float*)d_in[6];
  const float* bv   = (const float*)d_in[7];
  const float* Wo   = (const float*)d_in[8];
  const float* bo   = (const float*)d_in[9];
  const float* Wiq  = (const float*)d_in[10];
  const float* biq  = (const float*)d_in[11];
  const float* Wik  = (const float*)d_in[12];
  const float* bik  = (const float*)d_in[13];
  const float* emb  = (const float*)d_in[14];
  const float* qnw  = (const float*)d_in[15];
  const float* knw  = (const float*)d_in[16];
  float* out = (float*)d_out;

  // Workspace (identical extents to the round-9-proven footprint).
  // Lifetime audit (launch #):
  //  qbuf: fp32 q (w:5 r:8)
  //  kbuf: fp32 k (w:5 r:6) -> opart plane 0 (w:7 r:8)
  //  vbuf: unwritten by QKV (V goes to Vtb) -> opart plane 1 (w:7 r:8)
  //  ohi/olo: tiled split-bf16 o (w:8 r:9)
  //  xhi: x tiled bf16 (w:4 r:5) -> Knb (w:6 r:7)
  //  xlo: dead -> Vtb (w:5(QKV z=2) r:7)
  //  Wbig_hi: QKV weights (w:4 r:5) -> gate + lpart (w:8/7 r:9/8)
  //  Wbig_lo: WoH (w:4 r:9) | F4 (w:2 r:3) | H5 (w:3 r:8) | F4p (w:1 r:2)
  float* ws = (float*)d_ws;
  const size_t SZ = (size_t)BN_ * D_;
  float* qbuf = ws;
  float* kbuf = qbuf + SZ;
  float* vbuf = kbuf + SZ;
  float* opart = kbuf;                  // [2][BN][D] fp32 attn partials
  short* ohi  = (short*)(vbuf + SZ);
  short* olo  = ohi + SZ;
  short* xhi  = (short*)(ws + 4 * SZ);
  short* xlo  = xhi + SZ;
  short* Knb  = xhi;                    // [2][16][2048][64] bf16
  short* Vtb  = xlo;                    // [2][16][64][64][32] bf16
  short* Wbig_hi = (short*)(ws + 5 * SZ);
  short* Wbig_lo = Wbig_hi + (size_t)3 * D_ * D_;
  float* gate  = (float*)Wbig_hi;                       // [BN] (post-QKV)
  float* lpart = gate + BN_;                            // [2][BN][16]
  short* WoH = Wbig_lo;                                 // [D][D] tiled
  float* F4  = (float*)(Wbig_lo + (size_t)D_ * D_);     // [4][1024]
  float* H5  = F4 + 4 * D_;                             // [1025][5]
  float* F4p = H5 + 1025 * 5;                           // [64][4][1024]

  const dim3 blk(256);

  // 1-3) gate-path algebra prep (rank-5 collapse), parallel grids
  fprep_p<<<dim3(4, 64), blk, 0, stream>>>(Wik, emb, F4p);
  freduce<<<dim3(16), blk, 0, stream>>>(F4p, F4);
  hprep2<<<dim3(1025), blk, 0, stream>>>(Wiq, F4, bik, biq, H5);

  // 4) weight prep (Wq,Wk,Wv,Wo) + x -> tiled bf16, ONE dispatch
  wsplitAll<<<dim3(16, 16, 8), blk, 0, stream>>>(
      Wq, Wk, Wv, Wo, x, Wbig_hi, WoH, xhi);

  // 5) fused QKV projection; V plane writes Vtb directly (MODE 6)
  mfgemm2<6, 0><<<dim3(8, 32, 3), blk, 0, stream>>>(
      xhi, nullptr, Wbig_hi, bq, bk, bv,
      qbuf, Vtb, 8, (long)SZ, nullptr);

  // 6) K prep (norm + bf16 + swizzle; V already done)
  kvprepK<<<dim3(KVLEN / 32, H_, 2), blk, 0, stream>>>(kbuf, knw, Knb);

  // 7) attention, KV-split x2 -> fp32 partials (over dead kbuf/vbuf)
  attn3<<<dim3(N_ / 128, H_, B_ * 2), blk, 0, stream>>>(
      qbuf, Knb, Vtb, qnw, opart, lpart);

  // 8) combine partials -> o, and compute gate in-block (G never stored)
  attn_reduce2<<<BN_, blk, 0, stream>>>(opart, lpart, H5, mask, ohi, olo, gate);

  // 9) final: gate[row]*(o@Wo) + bo -> d_out (SPLIT=2: o hi/lo x Wo hi)
  mfgemm2<2, 2><<<dim3(8, 32, 1), blk, 0, stream>>>(
      ohi, olo, WoH, bo, nullptr, nullptr,
      out, nullptr, 0, 0, gate);
}

// Round 20
// 188.686 us; speedup vs baseline: 1.6120x; 1.0360x over previous
//
#include <hip/hip_runtime.h>
#include <cmath>

// Problem constants (fixed by the reference file)
#define B_   8
#define N_   512
#define D_   1024
#define H_   16
#define HD_  64
#define NI_  4
#define BN_  (B_*N_)      // 4096 rows when [B,N,*] is flattened
#define KVLEN (NI_*N_)    // 2048 keys per attention group

typedef __attribute__((ext_vector_type(8)))  short  bf16x8;   // 8 bf16 bit patterns
typedef __attribute__((ext_vector_type(8)))  __bf16 bf16x8_t; // builtin operand type
typedef __attribute__((ext_vector_type(16))) float  f32x16;
typedef __attribute__((ext_vector_type(4)))  short  s16x4;
typedef __attribute__((ext_vector_type(2)))  unsigned u32x2;

// round-to-nearest-even bf16 conversion (bit trick)
__device__ __forceinline__ short bf16_rn(float x) {
  unsigned u = __float_as_uint(x);
  unsigned r = (u + 0x7FFFu + ((u >> 16) & 1u)) >> 16;
  return (short)r;
}

__device__ __forceinline__ f32x16 mfma_bf16(bf16x8 a, bf16x8 b, f32x16 c) {
  return __builtin_amdgcn_mfma_f32_32x32x16_bf16(
      __builtin_bit_cast(bf16x8_t, a), __builtin_bit_cast(bf16x8_t, b), c, 0, 0, 0);
}

#define GLOAD16(gp, lp) __builtin_amdgcn_global_load_lds( \
  (const __attribute__((address_space(1))) unsigned*)(gp), \
  (__attribute__((address_space(3))) unsigned*)(lp), 16, 0, 0)

// TILED layout for all bf16 GEMM operands (K = 1024):
// addr(row,k) = (((row>>7)*128 + (k>>3))*128 + (row&127))*8 + (k&7).
// GEMM staging is then a LINEAR copy -> fully coalesced global_load_lds.
__device__ __forceinline__ long tiled_off(int row, int k) {
  return ((((long)(row >> 7) * 128 + (k >> 3)) * 128 + (row & 127)) * 8 + (k & 7));
}

// T1 XCD-aware block swizzle (MI355X: 8 XCDs, private L2s). Remap so each
// XCD gets a CONTIGUOUS tile range. REQUIRES nwg % 8 == 0.
__device__ __forceinline__ void xcd_swizzle(int& bx, int& by, int& bz) {
  const int gx = gridDim.x, gy = gridDim.y;
  const int nwg = gx * gy * gridDim.z;
  const int lin = blockIdx.x + gx * (blockIdx.y + gy * blockIdx.z);
  const int swz = (lin & 7) * (nwg >> 3) + (lin >> 3);
  bx = swz % gx;
  const int rest = swz / gx;
  by = rest % gy;
  bz = rest / gy;
}

// =====================================================================
// Weight + x prep, ONE dispatch (z=0..7):
//  z=0..2: Wq/Wk/Wv -> QKVh (combined [3072][1024] tiled, transposed)
//  z=3:    Wo -> WoH (tiled, transposed)
//  z=4..7: x rows (z-4)*1024.. -> Xh (tiled, direct convert)
// All hi-only bf16.
// =====================================================================
__global__ __launch_bounds__(256) void wsplitAll(
    const float* __restrict__ Wq, const float* __restrict__ Wk,
    const float* __restrict__ Wv, const float* __restrict__ Wo,
    const float* __restrict__ x,
    short* __restrict__ QKVh, short* __restrict__ WoH,
    short* __restrict__ Xh)
{
  const int z = blockIdx.z;
  const int t  = threadIdx.x;
  if (z >= 4) {
    const int rowB = (z - 4) * 1024 + blockIdx.y * 64;
    const int colB = blockIdx.x * 64;
    const int r0 = t >> 4;
    const int c4 = t & 15;
    #pragma unroll
    for (int i = 0; i < 4; i++) {
      const int row = rowB + r0 + i * 16;
      float4 v = *(const float4*)&x[(long)row * D_ + colB + c4 * 4];
      short h[4];
      h[0] = bf16_rn(v.x);  h[1] = bf16_rn(v.y);
      h[2] = bf16_rn(v.z);  h[3] = bf16_rn(v.w);
      *(s16x4*)&Xh[tiled_off(row, colB + c4 * 4)] = *(s16x4*)h;
    }
    return;
  }
  __shared__ float tile[64][65];
  const float* W = (z == 0) ? Wq : (z == 1) ? Wk : (z == 2) ? Wv : Wo;
  const int kb = blockIdx.y * 64;
  const int cb = blockIdx.x * 64;
  const int r0 = t >> 4;
  const int c4 = t & 15;
  #pragma unroll
  for (int i = 0; i < 4; i++) {
    const int r = r0 + i * 16;
    *(float4*)&tile[r][c4 * 4] = *(const float4*)&W[(long)(kb + r) * D_ + cb + c4 * 4];
  }
  __syncthreads();
  #pragma unroll
  for (int i = 0; i < 4; i++) {
    const int c = r0 + i * 16;
    short hi[4];
    #pragma unroll
    for (int e = 0; e < 4; e++)
      hi[e] = bf16_rn(tile[c4 * 4 + e][c]);
    if (z < 3)
      *(s16x4*)&QKVh[tiled_off(z * D_ + cb + c, kb + c4 * 4)] = *(s16x4*)hi;
    else
      *(s16x4*)&WoH[tiled_off(cb + c, kb + c4 * 4)] = *(s16x4*)hi;
  }
}

// =====================================================================
// Gate-path prep A: F4p[eb][j][d] = sum_{e in 16-chunk eb} emb[j][e] *
// Wik[e][d].  grid (4,64) = 256 blocks; coalesced 1KB row segments.
// =====================================================================
__global__ __launch_bounds__(256) void fprep_p(
    const float* __restrict__ Wik, const float* __restrict__ emb,
    float* __restrict__ F4p)
{
  const int d  = blockIdx.x * 256 + threadIdx.x;
  const int eb = blockIdx.y;
  float s0 = 0, s1 = 0, s2 = 0, s3 = 0;
  for (int e = eb * 16; e < eb * 16 + 16; e++) {
    const float w = Wik[(long)e * D_ + d];
    s0 = fmaf(emb[e], w, s0);
    s1 = fmaf(emb[D_ + e], w, s1);
    s2 = fmaf(emb[2 * D_ + e], w, s2);
    s3 = fmaf(emb[3 * D_ + e], w, s3);
  }
  float* p = F4p + (long)eb * 4 * D_;
  p[d] = s0;  p[D_ + d] = s1;  p[2 * D_ + d] = s2;  p[3 * D_ + d] = s3;
}

// freduce: F4[j][d] = sum of 64 e-chunk partials (fixed order).
__global__ __launch_bounds__(256) void freduce(
    const float* __restrict__ F4p, float* __restrict__ F4)
{
  const int i = blockIdx.x * 256 + threadIdx.x;   // 0..4095
  float s = 0.f;
  #pragma unroll
  for (int eb = 0; eb < 64; eb++) s += F4p[(long)eb * 4096 + i];
  F4[i] = s;
}

// =====================================================================
// Gate-path prep B: H5[d][j] = Wiq[d]·F4[j] (j<4); H5[d][4]=Wiq[d]·bik.
// Consts row H5[1024][j] = F4[j]·biq (j<4), H5[1024][4] = biq·bik.
// One block per d-row (1024 + 1 consts): coalesced 4KB row reads.
// =====================================================================
__global__ __launch_bounds__(256) void hprep2(
    const float* __restrict__ Wiq, const float* __restrict__ F4,
    const float* __restrict__ bik, const float* __restrict__ biq,
    float* __restrict__ H5)
{
  __shared__ float red[4][5];
  const int t = threadIdx.x;
  const int blk = blockIdx.x;
  float s[5] = {0.f, 0.f, 0.f, 0.f, 0.f};
  const float* vr = (blk < 1024) ? Wiq + (long)blk * D_ : biq;
  for (int e = t; e < D_; e += 256) {
    const float w = vr[e];
    s[0] = fmaf(w, F4[e], s[0]);
    s[1] = fmaf(w, F4[D_ + e], s[1]);
    s[2] = fmaf(w, F4[2 * D_ + e], s[2]);
    s[3] = fmaf(w, F4[3 * D_ + e], s[3]);
    s[4] = fmaf(w, bik[e], s[4]);
  }
  #pragma unroll
  for (int j = 0; j < 5; j++)
    #pragma unroll
    for (int m = 1; m < 64; m <<= 1) s[j] += __shfl_xor(s[j], m);
  const int w64 = t >> 6, lane = t & 63;
  if (lane == 0)
    #pragma unroll
    for (int j = 0; j < 5; j++) red[w64][j] = s[j];
  __syncthreads();
  if (t < 5)
    H5[(long)blk * 5 + t] = red[0][t] + red[1][t] + red[2][t] + red[3][t];
}

// =====================================================================
// MFMA GEMM v8. Tiled bf16 operands, linear global_load_lds staging,
// double-buffered LDS, counted vmcnt, XCD-swizzled blocks.
// SPLIT=0: plain bf16 (1 MFMA/pair); waves 0,1 stage A halves, waves
//          2,3 stage B halves, vmcnt(4). 32 KB LDS.
// MODE 6: QKV fused. z=0: qbuf fp32; z=1: kbuf fp32; z=2: V written
//         DIRECTLY to Vtb (bf16, transposed+swizzled).
// MODE 2: C = gate[row]*(A@B) + bias  (final — now plain bf16: the
//         o-lo plane is dropped; Wo was already hi-only, and measured
//         absmax has sat at the bf16-compare floor since r4, so the
//         symmetric o-rounding term fits the budget).
// =====================================================================
template<int MODE, int SPLIT>
__global__ __launch_bounds__(256) void mfgemm2(
    const short* __restrict__ Ahi, const short* __restrict__ Alo,
    const short* __restrict__ Bhi,
    const float* __restrict__ b0, const float* __restrict__ b1,
    const float* __restrict__ b2,
    float* __restrict__ C, short* __restrict__ Vout,
    int bBlk, long sC, const float* __restrict__ gate_in)
{
  constexpr int NOPS = 2;
  __shared__ short lds[2][NOPS][4096];
  const int t = threadIdx.x, w = t >> 6, lane = t & 63;
  int bx, by, bz;
  xcd_swizzle(bx, by, bz);
  const int rowBase = by * 128;
  const int colBase = bx * 128;
  const long aoff = (long)by * 131072;   // 128 oct * 128 rows * 8
  const long boff = (long)(bz * bBlk + bx) * 131072;

  const int op = w >> 1, half = w & 1;
  const short* mySrc = op ? Bhi + boff : Ahi + aoff;

  auto stage = [&](int buf, int tt) {
    const short* g = mySrc + ((long)tt * 512 + half * 256 + lane) * 8;
    #pragma unroll
    for (int i = 0; i < 4; i++)
      GLOAD16(g + i * 512, &lds[buf][op][(half * 256 + i * 64) * 8]);
  };

  const int wr = w >> 1, wc = w & 1;
  const int lrow = lane & 31, lk = lane >> 5;

  f32x16 acc[2][2] = {};

  auto compute = [&](int buf) {
    #pragma unroll
    for (int kh = 0; kh < 2; kh++) {
      const int kq = 2 * kh + lk;
      bf16x8 ah[2], bh[2];
      #pragma unroll
      for (int m = 0; m < 2; m++)
        ah[m] = *(const bf16x8*)&lds[buf][0][(kq * 128 + wr * 64 + m * 32 + lrow) * 8];
      #pragma unroll
      for (int n = 0; n < 2; n++)
        bh[n] = *(const bf16x8*)&lds[buf][1][(kq * 128 + wc * 64 + n * 32 + lrow) * 8];
      #pragma unroll
      for (int m = 0; m < 2; m++)
        #pragma unroll
        for (int n = 0; n < 2; n++)
          acc[m][n] = mfma_bf16(ah[m], bh[n], acc[m][n]);
    }
  };

  const int NT = 32;   // K=1024 / BK=32
  stage(0, 0);
  for (int tt = 0; tt < NT - 1; ++tt) {
    stage((tt + 1) & 1, tt + 1);
    asm volatile("s_waitcnt vmcnt(4)" ::: "memory");
    __builtin_amdgcn_s_barrier();
    __builtin_amdgcn_sched_barrier(0);
    compute(tt & 1);
    __builtin_amdgcn_s_barrier();
  }
  asm volatile("s_waitcnt vmcnt(0)" ::: "memory");
  __builtin_amdgcn_s_barrier();
  __builtin_amdgcn_sched_barrier(0);
  compute((NT - 1) & 1);

  // ---------------- epilogue ----------------
  const float* bias = (bz == 1) ? b1 : (bz == 2) ? b2 : b0;
  float bcol[2];
  #pragma unroll
  for (int n = 0; n < 2; n++)
    bcol[n] = bias[colBase + wc * 64 + n * 32 + lrow];

  if (MODE == 6 && bz == 2) {
    // V plane: write straight to Vtb [g][h][tile][d][32kv] swizzled.
    #pragma unroll
    for (int m = 0; m < 2; m++)
      #pragma unroll
      for (int r = 0; r < 16; r++) {
        const int row = rowBase + wr * 64 + m * 32 + (r & 3) + 8 * (r >> 2) + 4 * lk;
        const int bb = row >> 9, g = bb >> 2;
        const int kv = (bb & 3) * 512 + (row & 511);
        const int tile = kv >> 5, vkv = kv & 31;
        #pragma unroll
        for (int n = 0; n < 2; n++) {
          const int col = colBase + wc * 64 + n * 32 + lrow;
          const int h = col >> 6, dl = col & 63;
          const long idx = ((long)(g * H_ + h) * 64 + tile) * 2048
                         + dl * 32 + (((vkv >> 3) ^ ((dl >> 1) & 3)) * 8) + (vkv & 7);
          Vout[idx] = bf16_rn(acc[m][n][r] + bcol[n]);
        }
      }
    return;
  }

  float* Cb = C + (long)bz * sC;
  #pragma unroll
  for (int m = 0; m < 2; m++) {
    #pragma unroll
    for (int r = 0; r < 16; r++) {
      const int row = rowBase + wr * 64 + m * 32 + (r & 3) + 8 * (r >> 2) + 4 * lk;
      float g = 1.f;
      if (MODE == 2) g = gate_in[row];
      #pragma unroll
      for (int n = 0; n < 2; n++) {
        const int col = colBase + wc * 64 + n * 32 + lrow;
        Cb[(long)row * D_ + col] = acc[m][n][r] * g + bcol[n];
      }
    }
  }
}

// =====================================================================
// K prep only (V written by the QKV GEMM epilogue): RMSNorm (+knw)
// -> bf16 swizzled [g][h][m][64], linear per 4KB tile.
// =====================================================================
__global__ __launch_bounds__(256) void kvprepK(
    const float* __restrict__ kf, const float* __restrict__ knw,
    short* __restrict__ Knb)
{
  const int tile = blockIdx.x, h = blockIdx.y, g = blockIdx.z;
  const int t = threadIdx.x;
  const int skv = t >> 3, sg = t & 7;
  const int m  = tile * 32 + skv;
  const int bb = g * NI_ + (m >> 9), nn = m & (N_ - 1);
  const float* kp = kf + ((long)(bb * N_ + nn)) * D_ + h * HD_ + sg * 8;
  float k8[8];
  *(float4*)&k8[0] = *(const float4*)&kp[0];
  *(float4*)&k8[4] = *(const float4*)&kp[4];
  float ks2 = 0.f;
  #pragma unroll
  for (int j = 0; j < 8; j++) ks2 += k8[j] * k8[j];
  ks2 += __shfl_xor(ks2, 1);
  ks2 += __shfl_xor(ks2, 2);
  ks2 += __shfl_xor(ks2, 4);
  const float kr = rsqrtf(ks2 * (1.f / 64.f) + 1e-6f);
  bf16x8 kb;
  #pragma unroll
  for (int j = 0; j < 8; j++) kb[j] = bf16_rn(k8[j] * kr * knw[sg * 8 + j]);
  *(bf16x8*)&Knb[((long)(g * H_ + h) * KVLEN + m) * 64 + ((sg ^ (m & 7)) * 8)] = kb;
}

// =====================================================================
// MFMA grouped flash attention — ROUND-20: KV-SPLIT x3 (grid z = B*3;
// s covers kv-tiles [s*64/3, (s+1)*64/3): 21/21/22 tiles). r19 showed
// attn3 grid-limited (1024 blocks = 4 waves/SIMD ceiling, 30% occ);
// 1536 blocks -> 6 waves/SIMD at VGPR 64. Folded softmax scale (r19),
// 2-deep double-buffer, scalar l, permlane32_swap half-swap,
// XCD-swizzled. STATIC max: partials combine exactly (o=sum, l=sum).
// =====================================================================
__global__ __launch_bounds__(256) void attn3(
    const float* __restrict__ q, const short* __restrict__ Knb,
    const short* __restrict__ Vtb, const float* __restrict__ qnw,
    float* __restrict__ opart, float* __restrict__ lpart)
{
  int qb, h, bz;
  xcd_swizzle(qb, h, bz);
  const int b  = bz / 3, s = bz - 3 * b;
  const int g  = b >> 2;
  const int t  = threadIdx.x;
  const int w  = t >> 6;
  const int lane = t & 63;
  const int l31 = lane & 31, hi = lane >> 5;

  __shared__ short Kt[2][2048];
  __shared__ short Vt[2][2048];

  // ---- Q: load + RMSNorm (+ folded softmax scale) + B-operand frags ----
  const int qrow = qb * 128 + w * 32 + l31;
  const float* qp = q + ((long)b * N_ + qrow) * D_ + h * HD_ + hi * 8;
  float qv[4][8];
  float ss = 0.f;
  #pragma unroll
  for (int c = 0; c < 4; c++) {
    *(float4*)&qv[c][0] = *(const float4*)&qp[c * 16];
    *(float4*)&qv[c][4] = *(const float4*)&qp[c * 16 + 4];
    #pragma unroll
    for (int j = 0; j < 8; j++) ss += qv[c][j] * qv[c][j];
  }
  ss += __shfl_xor(ss, 32);
  const float qr = rsqrtf(ss * (1.f / 64.f) + 1e-6f) * 0.1803368801111244f;
  bf16x8 qf[4];
  #pragma unroll
  for (int c = 0; c < 4; c++)
    #pragma unroll
    for (int j = 0; j < 8; j++)
      qf[c][j] = bf16_rn(qv[c][j] * qr * qnw[c * 16 + hi * 8 + j]);

  const short* Kg = Knb + (long)(g * H_ + h) * KVLEN * 64;
  const short* Vg = Vtb + (long)(g * H_ + h) * 64 * 2048;

  auto stage = [&](int buf, int i) {
    GLOAD16(Kg + (long)i * 2048 + t * 8, &Kt[buf][w * 512]);
    GLOAD16(Vg + (long)i * 2048 + t * 8, &Vt[buf][w * 512]);
  };

  const int it0 = (s * 64) / 3;         // 0, 21, 42
  const int it1 = ((s + 1) * 64) / 3;   // 21, 42, 64

  f32x16 oacc[2] = {};
  float l = 0.f;

  stage(0, it0);
  for (int i = it0; i < it1; ++i) {
    const int buf = (i - it0) & 1;
    if (i + 1 < it1) {
      stage(buf ^ 1, i + 1);
      asm volatile("s_waitcnt vmcnt(2)" ::: "memory");
    } else {
      asm volatile("s_waitcnt vmcnt(0)" ::: "memory");
    }
    __builtin_amdgcn_s_barrier();
    __builtin_amdgcn_sched_barrier(0);

    // ---- QK^T: scores[kv][q], pre-scaled by folded 0.18033688 ----
    f32x16 sc = {};
    #pragma unroll
    for (int c = 0; c < 4; c++) {
      bf16x8 kfr = *(const bf16x8*)&Kt[buf][l31 * 64 + (((2 * c + hi) * 8) ^ ((l31 & 7) << 3))];
      sc = mfma_bf16(kfr, qf[c], sc);
    }
    // ---- softmax kernel: p~ = exp2(sc), constant offset cancels in o ----
    float p[16];
    #pragma unroll
    for (int r = 0; r < 16; r++) {
      p[r] = exp2f(sc[r]);
      l += p[r];
    }
    // ---- pack P pairs to bf16 (cvt_pk), half-swap via permlane32 ----
    unsigned wd[8];
    #pragma unroll
    for (int i2 = 0; i2 < 8; i2++)
      asm("v_cvt_pk_bf16_f32 %0, %1, %2" : "=v"(wd[i2]) : "v"(p[2 * i2]), "v"(p[2 * i2 + 1]));
    u32x2 r0 = __builtin_amdgcn_permlane32_swap(wd[0], wd[2], false, false);
    u32x2 r1 = __builtin_amdgcn_permlane32_swap(wd[1], wd[3], false, false);
    u32x2 r2 = __builtin_amdgcn_permlane32_swap(wd[4], wd[6], false, false);
    u32x2 r3 = __builtin_amdgcn_permlane32_swap(wd[5], wd[7], false, false);
    int4 f0 = { (int)r0.x, (int)r1.x, (int)r0.y, (int)r1.y };
    int4 f1 = { (int)r2.x, (int)r3.x, (int)r2.y, (int)r3.y };
    // ---- PV ----
    #pragma unroll
    for (int n = 0; n < 2; n++) {
      const int d = n * 32 + l31;
      const int fd = (d >> 1) & 3;
      bf16x8 v0 = *(const bf16x8*)&Vt[buf][d * 32 + ((hi ^ fd) * 8)];
      bf16x8 v1 = *(const bf16x8*)&Vt[buf][d * 32 + (((2 | hi) ^ fd) * 8)];
      oacc[n] = mfma_bf16(__builtin_bit_cast(bf16x8, f0), v0, oacc[n]);
      oacc[n] = mfma_bf16(__builtin_bit_cast(bf16x8, f1), v1, oacc[n]);
    }
    __builtin_amdgcn_s_barrier();
  }

  // ---- epilogue: write PARTIAL o (no divide) + l, plane s ----
  l += __shfl_xor(l, 32);
  #pragma unroll
  for (int r = 0; r < 16; r++) {
    const int qg = qb * 128 + w * 32 + (r & 3) + 8 * (r >> 2) + 4 * hi;
    float* op = opart + ((long)s * BN_ + b * N_ + qg) * D_ + h * HD_ + l31;
    op[0]  = oacc[0][r];
    op[32] = oacc[1][r];
  }
  if (hi == 0)
    lpart[((long)s * BN_ + b * N_ + qb * 128 + w * 32 + l31) * H_ + h] = l;
}

// =====================================================================
// attn_reduce2 — FUSED reduce + gate (3 KV-split planes now; o emitted
// hi-only since the final GEMM is plain bf16).
//  A: o = (o0+o1+o2)/(l0+l1+l2) -> tiled bf16
//  B: G[0:5] = o·H5[:,j] + H5[1024][j]  (block reduce; G never stored)
//  C: gate[row] = 1 + mean_m sigmoid(sc*(G·mask[b][m] + G4))
// =====================================================================
__global__ __launch_bounds__(256) void attn_reduce2(
    const float* __restrict__ opart, const float* __restrict__ lpart,
    const float* __restrict__ H5, const float* __restrict__ mask,
    short* __restrict__ ohi, float* __restrict__ gate)
{
  __shared__ float red[4][5];
  __shared__ float Gs[5];
  __shared__ float sred[4];
  const int t = threadIdx.x;
  const int row = blockIdx.x;
  const int bb = row >> 9;
  const int col = t * 4;
  const int h   = col >> 6;
  // ---- A: combine 3 partial planes ----
  const float l = lpart[(long)row * H_ + h]
                + lpart[((long)BN_ + row) * H_ + h]
                + lpart[((long)2 * BN_ + row) * H_ + h];
  const float inv = 1.f / l;
  float4 a = *(const float4*)&opart[(long)row * D_ + col];
  float4 b = *(const float4*)&opart[((long)BN_ + row) * D_ + col];
  float4 c = *(const float4*)&opart[((long)2 * BN_ + row) * D_ + col];
  float o4[4] = { (a.x + b.x + c.x) * inv, (a.y + b.y + c.y) * inv,
                  (a.z + b.z + c.z) * inv, (a.w + b.w + c.w) * inv };
  short hh[4];
  hh[0] = bf16_rn(o4[0]);  hh[1] = bf16_rn(o4[1]);
  hh[2] = bf16_rn(o4[2]);  hh[3] = bf16_rn(o4[3]);
  *(s16x4*)&ohi[tiled_off(row, col)] = *(s16x4*)hh;
  // ---- B: G = o . H5 (block reduce) ----
  float s[5] = {0.f, 0.f, 0.f, 0.f, 0.f};
  #pragma unroll
  for (int cc = 0; cc < 4; cc++) {
    const float* hp = &H5[(long)(col + cc) * 5];
    #pragma unroll
    for (int j = 0; j < 5; j++) s[j] = fmaf(o4[cc], hp[j], s[j]);
  }
  #pragma unroll
  for (int j = 0; j < 5; j++)
    #pragma unroll
    for (int m = 1; m < 64; m <<= 1) s[j] += __shfl_xor(s[j], m);
  const int w64 = t >> 6, lane = t & 63;
  if (lane == 0)
    #pragma unroll
    for (int j = 0; j < 5; j++) red[w64][j] = s[j];
  __syncthreads();
  if (t < 5) Gs[t] = red[0][t] + red[1][t] + red[2][t] + red[3][t] + H5[5120 + t];
  __syncthreads();
  const float g0 = Gs[0], g1 = Gs[1], g2 = Gs[2], g3 = Gs[3], g4 = Gs[4];
  // ---- C: gate via 512 sigmoids spread over the block ----
  const float sc = 0.125f / 16.f;       // SCALE/H
  const float* mrow = mask + (long)bb * N_ * NI_;
  float sg = 0.f;
  #pragma unroll
  for (int q = 0; q < 2; q++) {
    const float4 mk = *(const float4*)&mrow[(t * 2 + q) * 4];
    const float z = fmaf(g0, mk.x, fmaf(g1, mk.y, fmaf(g2, mk.z, fmaf(g3, mk.w, g4))));
    sg += 1.f / (1.f + __expf(-z * sc));
  }
  #pragma unroll
  for (int m = 1; m < 64; m <<= 1) sg += __shfl_xor(sg, m);
  if (lane == 0) sred[w64] = sg;
  __syncthreads();
  if (t == 0)
    gate[row] = 1.f + (sred[0] + sred[1] + sred[2] + sred[3]) * (1.f / 512.f);
}

// =====================================================================
extern "C" void kernel_launch(void* const* d_in, const int* in_sizes, int n_in,
                              void* d_out, int out_size, void* d_ws, size_t ws_size,
                              hipStream_t stream)
{
  const float* x    = (const float*)d_in[0];
  const float* mask = (const float*)d_in[1];
  const float* Wq   = (const float*)d_in[2];
  const float* bq   = (const float*)d_in[3];
  const float* Wk   = (const float*)d_in[4];
  const float* bk   = (const float*)d_in[5];
  const float* Wv   = (const float*)d_in[6];
  const float* bv   = (const float*)d_in[7];
  const float* Wo   = (const float*)d_in[8];
  const float* bo   = (const float*)d_in[9];
  const float* Wiq  = (const float*)d_in[10];
  const float* biq  = (const float*)d_in[11];
  const float* Wik  = (const float*)d_in[12];
  const float* bik  = (const float*)d_in[13];
  const float* emb  = (const float*)d_in[14];
  const float* qnw  = (const float*)d_in[15];
  const float* knw  = (const float*)d_in[16];
  float* out = (float*)d_out;

  // Workspace (identical extents to the round-9-proven footprint).
  // Lifetime audit (launch #):
  //  [0,SZ)    qbuf: fp32 q (w:5 r:7) -> ohi bf16 tiled (w:8 r:9)
  //  [SZ,4SZ)  kbuf: fp32 k (w:5 r:6); then opart planes 0/1/2
  //            (w:7 r:8) — plane 2 sits over the old ohi/olo region
  //  [4SZ,5SZ) xhi: x tiled bf16 (w:4 r:5) -> Knb (w:6 r:7);
  //            xlo half -> Vtb (w:5(QKV z=2) r:7)
  //  Wbig_hi:  QKV weights (w:4 r:5) -> gate + lpart[3] (w:8/7 r:9/8)
  //  Wbig_lo:  WoH (w:4 r:9) | F4 (w:2 r:3) | H5 (w:3 r:8) | F4p (w:1 r:2)
  float* ws = (float*)d_ws;
  const size_t SZ = (size_t)BN_ * D_;
  float* qbuf = ws;
  float* kbuf = qbuf + SZ;
  float* opart = kbuf;                  // [3][BN][D] fp32 attn partials
  short* ohi  = (short*)qbuf;           // post-attn3: o bf16 tiled
  short* xhi  = (short*)(ws + 4 * SZ);
  short* xlo  = xhi + SZ;
  short* Knb  = xhi;                    // [2][16][2048][64] bf16
  short* Vtb  = xlo;                    // [2][16][64][64][32] bf16
  short* Wbig_hi = (short*)(ws + 5 * SZ);
  short* Wbig_lo = Wbig_hi + (size_t)3 * D_ * D_;
  float* gate  = (float*)Wbig_hi;                       // [BN] (post-QKV)
  float* lpart = gate + BN_;                            // [3][BN][16]
  short* WoH = Wbig_lo;                                 // [D][D] tiled
  float* F4  = (float*)(Wbig_lo + (size_t)D_ * D_);     // [4][1024]
  float* H5  = F4 + 4 * D_;                             // [1025][5]
  float* F4p = H5 + 1025 * 5;                           // [64][4][1024]

  const dim3 blk(256);

  // 1-3) gate-path algebra prep (rank-5 collapse), parallel grids
  fprep_p<<<dim3(4, 64), blk, 0, stream>>>(Wik, emb, F4p);
  freduce<<<dim3(16), blk, 0, stream>>>(F4p, F4);
  hprep2<<<dim3(1025), blk, 0, stream>>>(Wiq, F4, bik, biq, H5);

  // 4) weight prep (Wq,Wk,Wv,Wo) + x -> tiled bf16, ONE dispatch
  wsplitAll<<<dim3(16, 16, 8), blk, 0, stream>>>(
      Wq, Wk, Wv, Wo, x, Wbig_hi, WoH, xhi);

  // 5) fused QKV projection; V plane writes Vtb directly (MODE 6)
  mfgemm2<6, 0><<<dim3(8, 32, 3), blk, 0, stream>>>(
      xhi, nullptr, Wbig_hi, bq, bk, bv,
      qbuf, Vtb, 8, (long)SZ, nullptr);

  // 6) K prep (norm + bf16 + swizzle; V already done)
  kvprepK<<<dim3(KVLEN / 32, H_, 2), blk, 0, stream>>>(kbuf, knw, Knb);

  // 7) attention, KV-split x3 -> fp32 partials (planes over dead
  //    kbuf/vbuf/old-ohi regions)
  attn3<<<dim3(N_ / 128, H_, B_ * 3), blk, 0, stream>>>(
      qbuf, Knb, Vtb, qnw, opart, lpart);

  // 8) combine 3 partial planes -> o bf16 (into dead qbuf region),
  //    gate computed in-block (G never stored)
  attn_reduce2<<<BN_, blk, 0, stream>>>(opart, lpart, H5, mask, ohi, gate);

  // 9) final: gate[row]*(o@Wo) + bo -> d_out (plain bf16, 1 MFMA/pair)
  mfgemm2<2, 0><<<dim3(8, 32, 1), blk, 0, stream>>>(
      ohi, nullptr, WoH, bo, nullptr, nullptr,
      out, nullptr, 0, 0, gate);
}

// Round 21
// 182.832 us; speedup vs baseline: 1.6636x; 1.0320x over previous
//
#include <hip/hip_runtime.h>
#include <cmath>

// Problem constants (fixed by the reference file)
#define B_   8
#define N_   512
#define D_   1024
#define H_   16
#define HD_  64
#define NI_  4
#define BN_  (B_*N_)      // 4096 rows when [B,N,*] is flattened
#define KVLEN (NI_*N_)    // 2048 keys per attention group

typedef __attribute__((ext_vector_type(8)))  short  bf16x8;   // 8 bf16 bit patterns
typedef __attribute__((ext_vector_type(8)))  __bf16 bf16x8_t; // builtin operand type
typedef __attribute__((ext_vector_type(16))) float  f32x16;
typedef __attribute__((ext_vector_type(4)))  short  s16x4;
typedef __attribute__((ext_vector_type(2)))  unsigned u32x2;

// round-to-nearest-even bf16 conversion (bit trick)
__device__ __forceinline__ short bf16_rn(float x) {
  unsigned u = __float_as_uint(x);
  unsigned r = (u + 0x7FFFu + ((u >> 16) & 1u)) >> 16;
  return (short)r;
}

__device__ __forceinline__ f32x16 mfma_bf16(bf16x8 a, bf16x8 b, f32x16 c) {
  return __builtin_amdgcn_mfma_f32_32x32x16_bf16(
      __builtin_bit_cast(bf16x8_t, a), __builtin_bit_cast(bf16x8_t, b), c, 0, 0, 0);
}

#define GLOAD16(gp, lp) __builtin_amdgcn_global_load_lds( \
  (const __attribute__((address_space(1))) unsigned*)(gp), \
  (__attribute__((address_space(3))) unsigned*)(lp), 16, 0, 0)

// TILED layout for all bf16 GEMM operands (K = 1024):
// addr(row,k) = (((row>>7)*128 + (k>>3))*128 + (row&127))*8 + (k&7).
// GEMM staging is then a LINEAR copy -> fully coalesced global_load_lds.
__device__ __forceinline__ long tiled_off(int row, int k) {
  return ((((long)(row >> 7) * 128 + (k >> 3)) * 128 + (row & 127)) * 8 + (k & 7));
}

// T1 XCD-aware block swizzle (MI355X: 8 XCDs, private L2s). Remap so each
// XCD gets a CONTIGUOUS tile range. REQUIRES nwg % 8 == 0.
__device__ __forceinline__ void xcd_swizzle(int& bx, int& by, int& bz) {
  const int gx = gridDim.x, gy = gridDim.y;
  const int nwg = gx * gy * gridDim.z;
  const int lin = blockIdx.x + gx * (blockIdx.y + gy * blockIdx.z);
  const int swz = (lin & 7) * (nwg >> 3) + (lin >> 3);
  bx = swz % gx;
  const int rest = swz / gx;
  by = rest % gy;
  bz = rest / gy;
}

// =====================================================================
// Weight + x prep, ONE dispatch (z=0..7):
//  z=0..2: Wq/Wk/Wv -> QKVh (combined [3072][1024] tiled, transposed)
//  z=3:    Wo -> WoH (tiled, transposed)
//  z=4..7: x rows (z-4)*1024.. -> Xh (tiled, direct convert)
// All hi-only bf16.
// =====================================================================
__global__ __launch_bounds__(256) void wsplitAll(
    const float* __restrict__ Wq, const float* __restrict__ Wk,
    const float* __restrict__ Wv, const float* __restrict__ Wo,
    const float* __restrict__ x,
    short* __restrict__ QKVh, short* __restrict__ WoH,
    short* __restrict__ Xh)
{
  const int z = blockIdx.z;
  const int t  = threadIdx.x;
  if (z >= 4) {
    const int rowB = (z - 4) * 1024 + blockIdx.y * 64;
    const int colB = blockIdx.x * 64;
    const int r0 = t >> 4;
    const int c4 = t & 15;
    #pragma unroll
    for (int i = 0; i < 4; i++) {
      const int row = rowB + r0 + i * 16;
      float4 v = *(const float4*)&x[(long)row * D_ + colB + c4 * 4];
      short h[4];
      h[0] = bf16_rn(v.x);  h[1] = bf16_rn(v.y);
      h[2] = bf16_rn(v.z);  h[3] = bf16_rn(v.w);
      *(s16x4*)&Xh[tiled_off(row, colB + c4 * 4)] = *(s16x4*)h;
    }
    return;
  }
  __shared__ float tile[64][65];
  const float* W = (z == 0) ? Wq : (z == 1) ? Wk : (z == 2) ? Wv : Wo;
  const int kb = blockIdx.y * 64;
  const int cb = blockIdx.x * 64;
  const int r0 = t >> 4;
  const int c4 = t & 15;
  #pragma unroll
  for (int i = 0; i < 4; i++) {
    const int r = r0 + i * 16;
    *(float4*)&tile[r][c4 * 4] = *(const float4*)&W[(long)(kb + r) * D_ + cb + c4 * 4];
  }
  __syncthreads();
  #pragma unroll
  for (int i = 0; i < 4; i++) {
    const int c = r0 + i * 16;
    short hi[4];
    #pragma unroll
    for (int e = 0; e < 4; e++)
      hi[e] = bf16_rn(tile[c4 * 4 + e][c]);
    if (z < 3)
      *(s16x4*)&QKVh[tiled_off(z * D_ + cb + c, kb + c4 * 4)] = *(s16x4*)hi;
    else
      *(s16x4*)&WoH[tiled_off(cb + c, kb + c4 * 4)] = *(s16x4*)hi;
  }
}

// =====================================================================
// Gate-path prep A: F4p[eb][j][d] = sum_{e in 16-chunk eb} emb[j][e] *
// Wik[e][d].  grid (4,64) = 256 blocks; coalesced 1KB row segments.
// =====================================================================
__global__ __launch_bounds__(256) void fprep_p(
    const float* __restrict__ Wik, const float* __restrict__ emb,
    float* __restrict__ F4p)
{
  const int d  = blockIdx.x * 256 + threadIdx.x;
  const int eb = blockIdx.y;
  float s0 = 0, s1 = 0, s2 = 0, s3 = 0;
  for (int e = eb * 16; e < eb * 16 + 16; e++) {
    const float w = Wik[(long)e * D_ + d];
    s0 = fmaf(emb[e], w, s0);
    s1 = fmaf(emb[D_ + e], w, s1);
    s2 = fmaf(emb[2 * D_ + e], w, s2);
    s3 = fmaf(emb[3 * D_ + e], w, s3);
  }
  float* p = F4p + (long)eb * 4 * D_;
  p[d] = s0;  p[D_ + d] = s1;  p[2 * D_ + d] = s2;  p[3 * D_ + d] = s3;
}

// freduce: F4[j][d] = sum of 64 e-chunk partials (fixed order).
__global__ __launch_bounds__(256) void freduce(
    const float* __restrict__ F4p, float* __restrict__ F4)
{
  const int i = blockIdx.x * 256 + threadIdx.x;   // 0..4095
  float s = 0.f;
  #pragma unroll
  for (int eb = 0; eb < 64; eb++) s += F4p[(long)eb * 4096 + i];
  F4[i] = s;
}

// =====================================================================
// Gate-path prep B: H5[d][j] = Wiq[d]·F4[j] (j<4); H5[d][4]=Wiq[d]·bik.
// Consts row H5[1024][j] = F4[j]·biq (j<4), H5[1024][4] = biq·bik.
// One block per d-row (1024 + 1 consts): coalesced 4KB row reads.
// =====================================================================
__global__ __launch_bounds__(256) void hprep2(
    const float* __restrict__ Wiq, const float* __restrict__ F4,
    const float* __restrict__ bik, const float* __restrict__ biq,
    float* __restrict__ H5)
{
  __shared__ float red[4][5];
  const int t = threadIdx.x;
  const int blk = blockIdx.x;
  float s[5] = {0.f, 0.f, 0.f, 0.f, 0.f};
  const float* vr = (blk < 1024) ? Wiq + (long)blk * D_ : biq;
  for (int e = t; e < D_; e += 256) {
    const float w = vr[e];
    s[0] = fmaf(w, F4[e], s[0]);
    s[1] = fmaf(w, F4[D_ + e], s[1]);
    s[2] = fmaf(w, F4[2 * D_ + e], s[2]);
    s[3] = fmaf(w, F4[3 * D_ + e], s[3]);
    s[4] = fmaf(w, bik[e], s[4]);
  }
  #pragma unroll
  for (int j = 0; j < 5; j++)
    #pragma unroll
    for (int m = 1; m < 64; m <<= 1) s[j] += __shfl_xor(s[j], m);
  const int w64 = t >> 6, lane = t & 63;
  if (lane == 0)
    #pragma unroll
    for (int j = 0; j < 5; j++) red[w64][j] = s[j];
  __syncthreads();
  if (t < 5)
    H5[(long)blk * 5 + t] = red[0][t] + red[1][t] + red[2][t] + red[3][t];
}

// =====================================================================
// MFMA GEMM v9. Tiled bf16 operands, linear global_load_lds staging,
// double-buffered LDS, counted vmcnt(4), XCD-swizzled blocks.
// Plain bf16 (1 MFMA/pair); waves 0,1 stage A halves, waves 2,3 stage
// B halves. 32 KB LDS.
// MODE 6: QKV fused.
//   z=0: qbuf fp32.
//   z=1: K-RMSNorm FUSED into the epilogue (r21): each block's 128
//        cols = 2 complete heads; a row's 64 head-cols live across the
//        32 lrow-lanes (same lk), so Σv² = 5 shfl_xor. Normalized bf16
//        written DIRECTLY to Knb (same swizzled layout/values the old
//        kvprepK produced) — kvprepK + kbuf's 32MB round-trip deleted.
//   z=2: V written directly to Vtb (bf16, transposed+swizzled).
// MODE 2: C = gate[row]*(A@B) + bias                  (final)
// =====================================================================
template<int MODE>
__global__ __launch_bounds__(256) void mfgemm2(
    const short* __restrict__ Ahi, const short* __restrict__ Bhi,
    const float* __restrict__ b0, const float* __restrict__ b1,
    const float* __restrict__ b2,
    float* __restrict__ C, short* __restrict__ Vout,
    short* __restrict__ Kout, const float* __restrict__ knw,
    int bBlk, long sC, const float* __restrict__ gate_in)
{
  __shared__ short lds[2][2][4096];
  const int t = threadIdx.x, w = t >> 6, lane = t & 63;
  int bx, by, bz;
  xcd_swizzle(bx, by, bz);
  const int rowBase = by * 128;
  const int colBase = bx * 128;
  const long aoff = (long)by * 131072;   // 128 oct * 128 rows * 8
  const long boff = (long)(bz * bBlk + bx) * 131072;

  const int op = w >> 1, half = w & 1;
  const short* mySrc = op ? Bhi + boff : Ahi + aoff;

  auto stage = [&](int buf, int tt) {
    const short* g = mySrc + ((long)tt * 512 + half * 256 + lane) * 8;
    #pragma unroll
    for (int i = 0; i < 4; i++)
      GLOAD16(g + i * 512, &lds[buf][op][(half * 256 + i * 64) * 8]);
  };

  const int wr = w >> 1, wc = w & 1;
  const int lrow = lane & 31, lk = lane >> 5;

  f32x16 acc[2][2] = {};

  auto compute = [&](int buf) {
    #pragma unroll
    for (int kh = 0; kh < 2; kh++) {
      const int kq = 2 * kh + lk;
      bf16x8 ah[2], bh[2];
      #pragma unroll
      for (int m = 0; m < 2; m++)
        ah[m] = *(const bf16x8*)&lds[buf][0][(kq * 128 + wr * 64 + m * 32 + lrow) * 8];
      #pragma unroll
      for (int n = 0; n < 2; n++)
        bh[n] = *(const bf16x8*)&lds[buf][1][(kq * 128 + wc * 64 + n * 32 + lrow) * 8];
      #pragma unroll
      for (int m = 0; m < 2; m++)
        #pragma unroll
        for (int n = 0; n < 2; n++)
          acc[m][n] = mfma_bf16(ah[m], bh[n], acc[m][n]);
    }
  };

  const int NT = 32;   // K=1024 / BK=32
  stage(0, 0);
  for (int tt = 0; tt < NT - 1; ++tt) {
    stage((tt + 1) & 1, tt + 1);
    asm volatile("s_waitcnt vmcnt(4)" ::: "memory");
    __builtin_amdgcn_s_barrier();
    __builtin_amdgcn_sched_barrier(0);
    compute(tt & 1);
    __builtin_amdgcn_s_barrier();
  }
  asm volatile("s_waitcnt vmcnt(0)" ::: "memory");
  __builtin_amdgcn_s_barrier();
  __builtin_amdgcn_sched_barrier(0);
  compute((NT - 1) & 1);

  // ---------------- epilogue ----------------
  const float* bias = (bz == 1) ? b1 : (bz == 2) ? b2 : b0;
  float bcol[2];
  #pragma unroll
  for (int n = 0; n < 2; n++)
    bcol[n] = bias[colBase + wc * 64 + n * 32 + lrow];

  if (MODE == 6 && bz == 2) {
    // V plane: write straight to Vtb [g][h][tile][d][32kv] swizzled.
    #pragma unroll
    for (int m = 0; m < 2; m++)
      #pragma unroll
      for (int r = 0; r < 16; r++) {
        const int row = rowBase + wr * 64 + m * 32 + (r & 3) + 8 * (r >> 2) + 4 * lk;
        const int bb = row >> 9, g = bb >> 2;
        const int kv = (bb & 3) * 512 + (row & 511);
        const int tile = kv >> 5, vkv = kv & 31;
        #pragma unroll
        for (int n = 0; n < 2; n++) {
          const int col = colBase + wc * 64 + n * 32 + lrow;
          const int h = col >> 6, dl = col & 63;
          const long idx = ((long)(g * H_ + h) * 64 + tile) * 2048
                         + dl * 32 + (((vkv >> 3) ^ ((dl >> 1) & 3)) * 8) + (vkv & 7);
          Vout[idx] = bf16_rn(acc[m][n][r] + bcol[n]);
        }
      }
    return;
  }

  if (MODE == 6 && bz == 1) {
    // K plane: RMSNorm (per row-head) + knw, write swizzled Knb.
    // Row's 64 head-cols = {n*32+lrow} across the 32 lrow-lanes of
    // this lk group -> shfl_xor masks 1..16 stay within the group.
    const float kw0 = knw[lrow];
    const float kw1 = knw[32 + lrow];
    const int h = (colBase + wc * 64) >> 6;
    #pragma unroll
    for (int m = 0; m < 2; m++)
      #pragma unroll
      for (int r = 0; r < 16; r++) {
        const int row = rowBase + wr * 64 + m * 32 + (r & 3) + 8 * (r >> 2) + 4 * lk;
        const int bb = row >> 9, g = bb >> 2;
        const int mkv = (bb & 3) * 512 + (row & 511);
        const float v0 = acc[m][0][r] + bcol[0];
        const float v1 = acc[m][1][r] + bcol[1];
        float ks2 = v0 * v0 + v1 * v1;
        ks2 += __shfl_xor(ks2, 1);
        ks2 += __shfl_xor(ks2, 2);
        ks2 += __shfl_xor(ks2, 4);
        ks2 += __shfl_xor(ks2, 8);
        ks2 += __shfl_xor(ks2, 16);
        const float kr = rsqrtf(ks2 * (1.f / 64.f) + 1e-6f);
        const long base = ((long)(g * H_ + h) * KVLEN + mkv) * 64;
        const int d0 = lrow, d1 = 32 + lrow;
        Kout[base + (((d0 >> 3) ^ (mkv & 7)) << 3) + (d0 & 7)] = bf16_rn(v0 * kr * kw0);
        Kout[base + (((d1 >> 3) ^ (mkv & 7)) << 3) + (d1 & 7)] = bf16_rn(v1 * kr * kw1);
      }
    return;
  }

  float* Cb = C + (long)bz * sC;
  #pragma unroll
  for (int m = 0; m < 2; m++) {
    #pragma unroll
    for (int r = 0; r < 16; r++) {
      const int row = rowBase + wr * 64 + m * 32 + (r & 3) + 8 * (r >> 2) + 4 * lk;
      float g = 1.f;
      if (MODE == 2) g = gate_in[row];
      #pragma unroll
      for (int n = 0; n < 2; n++) {
        const int col = colBase + wc * 64 + n * 32 + lrow;
        Cb[(long)row * D_ + col] = acc[m][n][r] * g + bcol[n];
      }
    }
  }
}

// =====================================================================
// MFMA grouped flash attention — KV-SPLIT x2 (r19's measured-best;
// r20's x3 was a null for attn3 and taxed the reduce). Folded softmax
// scale, 2-deep double-buffer, scalar l, permlane32_swap half-swap,
// XCD-swizzled. STATIC max: partials combine exactly (o=sum, l=sum).
// =====================================================================
__global__ __launch_bounds__(256) void attn3(
    const float* __restrict__ q, const short* __restrict__ Knb,
    const short* __restrict__ Vtb, const float* __restrict__ qnw,
    float* __restrict__ opart, float* __restrict__ lpart)
{
  int qb, h, bz;
  xcd_swizzle(qb, h, bz);
  const int b  = bz >> 1, s = bz & 1;
  const int g  = b >> 2;
  const int t  = threadIdx.x;
  const int w  = t >> 6;
  const int lane = t & 63;
  const int l31 = lane & 31, hi = lane >> 5;

  __shared__ short Kt[2][2048];
  __shared__ short Vt[2][2048];

  // ---- Q: load + RMSNorm (+ folded softmax scale) + B-operand frags ----
  const int qrow = qb * 128 + w * 32 + l31;
  const float* qp = q + ((long)b * N_ + qrow) * D_ + h * HD_ + hi * 8;
  float qv[4][8];
  float ss = 0.f;
  #pragma unroll
  for (int c = 0; c < 4; c++) {
    *(float4*)&qv[c][0] = *(const float4*)&qp[c * 16];
    *(float4*)&qv[c][4] = *(const float4*)&qp[c * 16 + 4];
    #pragma unroll
    for (int j = 0; j < 8; j++) ss += qv[c][j] * qv[c][j];
  }
  ss += __shfl_xor(ss, 32);
  const float qr = rsqrtf(ss * (1.f / 64.f) + 1e-6f) * 0.1803368801111244f;
  bf16x8 qf[4];
  #pragma unroll
  for (int c = 0; c < 4; c++)
    #pragma unroll
    for (int j = 0; j < 8; j++)
      qf[c][j] = bf16_rn(qv[c][j] * qr * qnw[c * 16 + hi * 8 + j]);

  const short* Kg = Knb + (long)(g * H_ + h) * KVLEN * 64 + (long)s * 32 * 2048;
  const short* Vg = Vtb + (long)(g * H_ + h) * 64 * 2048 + (long)s * 32 * 2048;

  auto stage = [&](int buf, int i) {
    GLOAD16(Kg + (long)i * 2048 + t * 8, &Kt[buf][w * 512]);
    GLOAD16(Vg + (long)i * 2048 + t * 8, &Vt[buf][w * 512]);
  };

  f32x16 oacc[2] = {};
  float l = 0.f;

  stage(0, 0);
  for (int i = 0; i < 32; ++i) {
    const int buf = i & 1;
    if (i + 1 < 32) {
      stage(buf ^ 1, i + 1);
      asm volatile("s_waitcnt vmcnt(2)" ::: "memory");
    } else {
      asm volatile("s_waitcnt vmcnt(0)" ::: "memory");
    }
    __builtin_amdgcn_s_barrier();
    __builtin_amdgcn_sched_barrier(0);

    // ---- QK^T: scores[kv][q], pre-scaled by folded 0.18033688 ----
    f32x16 sc = {};
    #pragma unroll
    for (int c = 0; c < 4; c++) {
      bf16x8 kfr = *(const bf16x8*)&Kt[buf][l31 * 64 + (((2 * c + hi) * 8) ^ ((l31 & 7) << 3))];
      sc = mfma_bf16(kfr, qf[c], sc);
    }
    // ---- softmax kernel: p~ = exp2(sc), constant offset cancels in o ----
    float p[16];
    #pragma unroll
    for (int r = 0; r < 16; r++) {
      p[r] = exp2f(sc[r]);
      l += p[r];
    }
    // ---- pack P pairs to bf16 (cvt_pk), half-swap via permlane32 ----
    unsigned wd[8];
    #pragma unroll
    for (int i2 = 0; i2 < 8; i2++)
      asm("v_cvt_pk_bf16_f32 %0, %1, %2" : "=v"(wd[i2]) : "v"(p[2 * i2]), "v"(p[2 * i2 + 1]));
    u32x2 r0 = __builtin_amdgcn_permlane32_swap(wd[0], wd[2], false, false);
    u32x2 r1 = __builtin_amdgcn_permlane32_swap(wd[1], wd[3], false, false);
    u32x2 r2 = __builtin_amdgcn_permlane32_swap(wd[4], wd[6], false, false);
    u32x2 r3 = __builtin_amdgcn_permlane32_swap(wd[5], wd[7], false, false);
    int4 f0 = { (int)r0.x, (int)r1.x, (int)r0.y, (int)r1.y };
    int4 f1 = { (int)r2.x, (int)r3.x, (int)r2.y, (int)r3.y };
    // ---- PV ----
    #pragma unroll
    for (int n = 0; n < 2; n++) {
      const int d = n * 32 + l31;
      const int fd = (d >> 1) & 3;
      bf16x8 v0 = *(const bf16x8*)&Vt[buf][d * 32 + ((hi ^ fd) * 8)];
      bf16x8 v1 = *(const bf16x8*)&Vt[buf][d * 32 + (((2 | hi) ^ fd) * 8)];
      oacc[n] = mfma_bf16(__builtin_bit_cast(bf16x8, f0), v0, oacc[n]);
      oacc[n] = mfma_bf16(__builtin_bit_cast(bf16x8, f1), v1, oacc[n]);
    }
    __builtin_amdgcn_s_barrier();
  }

  // ---- epilogue: write PARTIAL o (no divide) + l, plane s ----
  l += __shfl_xor(l, 32);
  #pragma unroll
  for (int r = 0; r < 16; r++) {
    const int qg = qb * 128 + w * 32 + (r & 3) + 8 * (r >> 2) + 4 * hi;
    float* op = opart + ((long)s * BN_ + b * N_ + qg) * D_ + h * HD_ + l31;
    op[0]  = oacc[0][r];
    op[32] = oacc[1][r];
  }
  if (hi == 0)
    lpart[((long)s * BN_ + b * N_ + qb * 128 + w * 32 + l31) * H_ + h] = l;
}

// =====================================================================
// attn_reduce2 — FUSED reduce + gate (2 KV-split planes; o hi-only).
//  A: o = (o0+o1)/(l0+l1) -> tiled bf16
//  B: G[0:5] = o·H5[:,j] + H5[1024][j]  (block reduce; G never stored)
//  C: gate[row] = 1 + mean_m sigmoid(sc*(G·mask[b][m] + G4))
// =====================================================================
__global__ __launch_bounds__(256) void attn_reduce2(
    const float* __restrict__ opart, const float* __restrict__ lpart,
    const float* __restrict__ H5, const float* __restrict__ mask,
    short* __restrict__ ohi, float* __restrict__ gate)
{
  __shared__ float red[4][5];
  __shared__ float Gs[5];
  __shared__ float sred[4];
  const int t = threadIdx.x;
  const int row = blockIdx.x;
  const int bb = row >> 9;
  const int col = t * 4;
  const int h   = col >> 6;
  // ---- A: combine 2 partial planes ----
  const float l = lpart[(long)row * H_ + h] + lpart[((long)BN_ + row) * H_ + h];
  const float inv = 1.f / l;
  float4 a = *(const float4*)&opart[(long)row * D_ + col];
  float4 b = *(const float4*)&opart[((long)BN_ + row) * D_ + col];
  float o4[4] = { (a.x + b.x) * inv, (a.y + b.y) * inv,
                  (a.z + b.z) * inv, (a.w + b.w) * inv };
  short hh[4];
  hh[0] = bf16_rn(o4[0]);  hh[1] = bf16_rn(o4[1]);
  hh[2] = bf16_rn(o4[2]);  hh[3] = bf16_rn(o4[3]);
  *(s16x4*)&ohi[tiled_off(row, col)] = *(s16x4*)hh;
  // ---- B: G = o . H5 (block reduce) ----
  float s[5] = {0.f, 0.f, 0.f, 0.f, 0.f};
  #pragma unroll
  for (int cc = 0; cc < 4; cc++) {
    const float* hp = &H5[(long)(col + cc) * 5];
    #pragma unroll
    for (int j = 0; j < 5; j++) s[j] = fmaf(o4[cc], hp[j], s[j]);
  }
  #pragma unroll
  for (int j = 0; j < 5; j++)
    #pragma unroll
    for (int m = 1; m < 64; m <<= 1) s[j] += __shfl_xor(s[j], m);
  const int w64 = t >> 6, lane = t & 63;
  if (lane == 0)
    #pragma unroll
    for (int j = 0; j < 5; j++) red[w64][j] = s[j];
  __syncthreads();
  if (t < 5) Gs[t] = red[0][t] + red[1][t] + red[2][t] + red[3][t] + H5[5120 + t];
  __syncthreads();
  const float g0 = Gs[0], g1 = Gs[1], g2 = Gs[2], g3 = Gs[3], g4 = Gs[4];
  // ---- C: gate via 512 sigmoids spread over the block ----
  const float sc = 0.125f / 16.f;       // SCALE/H
  const float* mrow = mask + (long)bb * N_ * NI_;
  float sg = 0.f;
  #pragma unroll
  for (int q = 0; q < 2; q++) {
    const float4 mk = *(const float4*)&mrow[(t * 2 + q) * 4];
    const float z = fmaf(g0, mk.x, fmaf(g1, mk.y, fmaf(g2, mk.z, fmaf(g3, mk.w, g4))));
    sg += 1.f / (1.f + __expf(-z * sc));
  }
  #pragma unroll
  for (int m = 1; m < 64; m <<= 1) sg += __shfl_xor(sg, m);
  if (lane == 0) sred[w64] = sg;
  __syncthreads();
  if (t == 0)
    gate[row] = 1.f + (sred[0] + sred[1] + sred[2] + sred[3]) * (1.f / 512.f);
}

// =====================================================================
extern "C" void kernel_launch(void* const* d_in, const int* in_sizes, int n_in,
                              void* d_out, int out_size, void* d_ws, size_t ws_size,
                              hipStream_t stream)
{
  const float* x    = (const float*)d_in[0];
  const float* mask = (const float*)d_in[1];
  const float* Wq   = (const float*)d_in[2];
  const float* bq   = (const float*)d_in[3];
  const float* Wk   = (const float*)d_in[4];
  const float* bk   = (const float*)d_in[5];
  const float* Wv   = (const float*)d_in[6];
  const float* bv   = (const float*)d_in[7];
  const float* Wo   = (const float*)d_in[8];
  const float* bo   = (const float*)d_in[9];
  const float* Wiq  = (const float*)d_in[10];
  const float* biq  = (const float*)d_in[11];
  const float* Wik  = (const float*)d_in[12];
  const float* bik  = (const float*)d_in[13];
  const float* emb  = (const float*)d_in[14];
  const float* qnw  = (const float*)d_in[15];
  const float* knw  = (const float*)d_in[16];
  float* out = (float*)d_out;

  // Workspace (within the round-9-proven footprint).
  // Lifetime audit (launch #):
  //  [0,SZ)     qbuf: fp32 q (w:5(QKV z=0) r:6) -> ohi bf16 (w:7 r:8)
  //  [SZ,3SZ)   opart planes 0,1 (w:6 r:7). DEAD during QKV — fp32 k
  //             no longer exists (K-norm fused into QKV epilogue).
  //  [3SZ,4SZ)  Knb bf16 (w:5(QKV z=1 epilogue) r:6). Dead during the
  //             QKV STAGING reads (r18 lesson: must not overlay xhi).
  //  [4SZ,4.5SZ) xhi: x tiled bf16 (w:4 r:5)
  //  [4.5SZ,5SZ) Vtb bf16 (w:5(QKV z=2) r:6) — overlays dead xlo
  //  Wbig_hi:   QKV weights (w:4 r:5) -> gate + lpart[2] (w:7/6 r:8/7)
  //  Wbig_lo:   WoH (w:4 r:8) | F4 (w:2 r:3) | H5 (w:3 r:7) | F4p (w:1 r:2)
  float* ws = (float*)d_ws;
  const size_t SZ = (size_t)BN_ * D_;
  float* qbuf = ws;
  float* opart = ws + SZ;               // [2][BN][D] fp32 attn partials
  short* ohi  = (short*)qbuf;           // post-attn3: o bf16 tiled
  short* Knb  = (short*)(ws + 3 * SZ);  // [2][16][2048][64] bf16
  short* xhi  = (short*)(ws + 4 * SZ);
  short* Vtb  = xhi + SZ;               // [2][16][64][64][32] bf16
  short* Wbig_hi = (short*)(ws + 5 * SZ);
  short* Wbig_lo = Wbig_hi + (size_t)3 * D_ * D_;
  float* gate  = (float*)Wbig_hi;                       // [BN] (post-QKV)
  float* lpart = gate + BN_;                            // [2][BN][16]
  short* WoH = Wbig_lo;                                 // [D][D] tiled
  float* F4  = (float*)(Wbig_lo + (size_t)D_ * D_);     // [4][1024]
  float* H5  = F4 + 4 * D_;                             // [1025][5]
  float* F4p = H5 + 1025 * 5;                           // [64][4][1024]

  const dim3 blk(256);

  // 1-3) gate-path algebra prep (rank-5 collapse), parallel grids
  fprep_p<<<dim3(4, 64), blk, 0, stream>>>(Wik, emb, F4p);
  freduce<<<dim3(16), blk, 0, stream>>>(F4p, F4);
  hprep2<<<dim3(1025), blk, 0, stream>>>(Wiq, F4, bik, biq, H5);

  // 4) weight prep (Wq,Wk,Wv,Wo) + x -> tiled bf16, ONE dispatch
  wsplitAll<<<dim3(16, 16, 8), blk, 0, stream>>>(
      Wq, Wk, Wv, Wo, x, Wbig_hi, WoH, xhi);

  // 5) fused QKV projection; K plane -> Knb (norm fused), V plane -> Vtb
  mfgemm2<6><<<dim3(8, 32, 3), blk, 0, stream>>>(
      xhi, Wbig_hi, bq, bk, bv,
      qbuf, Vtb, Knb, knw, 8, (long)SZ, nullptr);

  // 6) attention, KV-split x2 -> fp32 partials
  attn3<<<dim3(N_ / 128, H_, B_ * 2), blk, 0, stream>>>(
      qbuf, Knb, Vtb, qnw, opart, lpart);

  // 7) combine partials -> o bf16 (into dead qbuf region), gate in-block
  attn_reduce2<<<BN_, blk, 0, stream>>>(opart, lpart, H5, mask, ohi, gate);

  // 8) final: gate[row]*(o@Wo) + bo -> d_out (plain bf16)
  mfgemm2<2><<<dim3(8, 32, 1), blk, 0, stream>>>(
      ohi, WoH, bo, nullptr, nullptr,
      out, nullptr, nullptr, nullptr, 0, 0, gate);
}

// Round 22
// 179.915 us; speedup vs baseline: 1.6906x; 1.0162x over previous
//
#include <hip/hip_runtime.h>
#include <cmath>

// Problem constants (fixed by the reference file)
#define B_   8
#define N_   512
#define D_   1024
#define H_   16
#define HD_  64
#define NI_  4
#define BN_  (B_*N_)      // 4096 rows when [B,N,*] is flattened
#define KVLEN (NI_*N_)    // 2048 keys per attention group

typedef __attribute__((ext_vector_type(8)))  short  bf16x8;   // 8 bf16 bit patterns
typedef __attribute__((ext_vector_type(8)))  __bf16 bf16x8_t; // builtin operand type
typedef __attribute__((ext_vector_type(16))) float  f32x16;
typedef __attribute__((ext_vector_type(4)))  short  s16x4;
typedef __attribute__((ext_vector_type(2)))  unsigned u32x2;

// round-to-nearest-even bf16 conversion (bit trick)
__device__ __forceinline__ short bf16_rn(float x) {
  unsigned u = __float_as_uint(x);
  unsigned r = (u + 0x7FFFu + ((u >> 16) & 1u)) >> 16;
  return (short)r;
}

__device__ __forceinline__ float bf2f(short x) {
  return __uint_as_float(((unsigned)(unsigned short)x) << 16);
}

__device__ __forceinline__ f32x16 mfma_bf16(bf16x8 a, bf16x8 b, f32x16 c) {
  return __builtin_amdgcn_mfma_f32_32x32x16_bf16(
      __builtin_bit_cast(bf16x8_t, a), __builtin_bit_cast(bf16x8_t, b), c, 0, 0, 0);
}

#define GLOAD16(gp, lp) __builtin_amdgcn_global_load_lds( \
  (const __attribute__((address_space(1))) unsigned*)(gp), \
  (__attribute__((address_space(3))) unsigned*)(lp), 16, 0, 0)

// TILED layout for all bf16 GEMM operands (K = 1024):
// addr(row,k) = (((row>>7)*128 + (k>>3))*128 + (row&127))*8 + (k&7).
// GEMM staging is then a LINEAR copy -> fully coalesced global_load_lds.
__device__ __forceinline__ long tiled_off(int row, int k) {
  return ((((long)(row >> 7) * 128 + (k >> 3)) * 128 + (row & 127)) * 8 + (k & 7));
}

// T1 XCD-aware block swizzle (MI355X: 8 XCDs, private L2s). Remap so each
// XCD gets a CONTIGUOUS tile range. REQUIRES nwg % 8 == 0.
__device__ __forceinline__ void xcd_swizzle(int& bx, int& by, int& bz) {
  const int gx = gridDim.x, gy = gridDim.y;
  const int nwg = gx * gy * gridDim.z;
  const int lin = blockIdx.x + gx * (blockIdx.y + gy * blockIdx.z);
  const int swz = (lin & 7) * (nwg >> 3) + (lin >> 3);
  bx = swz % gx;
  const int rest = swz / gx;
  by = rest % gy;
  bz = rest / gy;
}

// =====================================================================
// Weight + x prep, ONE dispatch (z=0..7):
//  z=0..2: Wq/Wk/Wv -> QKVh (combined [3072][1024] tiled, transposed)
//  z=3:    Wo -> WoH (tiled, transposed)
//  z=4..7: x rows (z-4)*1024.. -> Xh (tiled, direct convert)
// All hi-only bf16.
// =====================================================================
__global__ __launch_bounds__(256) void wsplitAll(
    const float* __restrict__ Wq, const float* __restrict__ Wk,
    const float* __restrict__ Wv, const float* __restrict__ Wo,
    const float* __restrict__ x,
    short* __restrict__ QKVh, short* __restrict__ WoH,
    short* __restrict__ Xh)
{
  const int z = blockIdx.z;
  const int t  = threadIdx.x;
  if (z >= 4) {
    const int rowB = (z - 4) * 1024 + blockIdx.y * 64;
    const int colB = blockIdx.x * 64;
    const int r0 = t >> 4;
    const int c4 = t & 15;
    #pragma unroll
    for (int i = 0; i < 4; i++) {
      const int row = rowB + r0 + i * 16;
      float4 v = *(const float4*)&x[(long)row * D_ + colB + c4 * 4];
      short h[4];
      h[0] = bf16_rn(v.x);  h[1] = bf16_rn(v.y);
      h[2] = bf16_rn(v.z);  h[3] = bf16_rn(v.w);
      *(s16x4*)&Xh[tiled_off(row, colB + c4 * 4)] = *(s16x4*)h;
    }
    return;
  }
  __shared__ float tile[64][65];
  const float* W = (z == 0) ? Wq : (z == 1) ? Wk : (z == 2) ? Wv : Wo;
  const int kb = blockIdx.y * 64;
  const int cb = blockIdx.x * 64;
  const int r0 = t >> 4;
  const int c4 = t & 15;
  #pragma unroll
  for (int i = 0; i < 4; i++) {
    const int r = r0 + i * 16;
    *(float4*)&tile[r][c4 * 4] = *(const float4*)&W[(long)(kb + r) * D_ + cb + c4 * 4];
  }
  __syncthreads();
  #pragma unroll
  for (int i = 0; i < 4; i++) {
    const int c = r0 + i * 16;
    short hi[4];
    #pragma unroll
    for (int e = 0; e < 4; e++)
      hi[e] = bf16_rn(tile[c4 * 4 + e][c]);
    if (z < 3)
      *(s16x4*)&QKVh[tiled_off(z * D_ + cb + c, kb + c4 * 4)] = *(s16x4*)hi;
    else
      *(s16x4*)&WoH[tiled_off(cb + c, kb + c4 * 4)] = *(s16x4*)hi;
  }
}

// =====================================================================
// Gate-path prep A: F4p[eb][j][d] = sum_{e in 16-chunk eb} emb[j][e] *
// Wik[e][d].  grid (4,64) = 256 blocks; coalesced 1KB row segments.
// =====================================================================
__global__ __launch_bounds__(256) void fprep_p(
    const float* __restrict__ Wik, const float* __restrict__ emb,
    float* __restrict__ F4p)
{
  const int d  = blockIdx.x * 256 + threadIdx.x;
  const int eb = blockIdx.y;
  float s0 = 0, s1 = 0, s2 = 0, s3 = 0;
  for (int e = eb * 16; e < eb * 16 + 16; e++) {
    const float w = Wik[(long)e * D_ + d];
    s0 = fmaf(emb[e], w, s0);
    s1 = fmaf(emb[D_ + e], w, s1);
    s2 = fmaf(emb[2 * D_ + e], w, s2);
    s3 = fmaf(emb[3 * D_ + e], w, s3);
  }
  float* p = F4p + (long)eb * 4 * D_;
  p[d] = s0;  p[D_ + d] = s1;  p[2 * D_ + d] = s2;  p[3 * D_ + d] = s3;
}

// freduce: F4[j][d] = sum of 64 e-chunk partials (fixed order).
__global__ __launch_bounds__(256) void freduce(
    const float* __restrict__ F4p, float* __restrict__ F4)
{
  const int i = blockIdx.x * 256 + threadIdx.x;   // 0..4095
  float s = 0.f;
  #pragma unroll
  for (int eb = 0; eb < 64; eb++) s += F4p[(long)eb * 4096 + i];
  F4[i] = s;
}

// =====================================================================
// Gate-path prep B: H5[d][j] = Wiq[d]·F4[j] (j<4); H5[d][4]=Wiq[d]·bik.
// Consts row H5[1024][j] = F4[j]·biq (j<4), H5[1024][4] = biq·bik.
// One block per d-row (1024 + 1 consts): coalesced 4KB row reads.
// =====================================================================
__global__ __launch_bounds__(256) void hprep2(
    const float* __restrict__ Wiq, const float* __restrict__ F4,
    const float* __restrict__ bik, const float* __restrict__ biq,
    float* __restrict__ H5)
{
  __shared__ float red[4][5];
  const int t = threadIdx.x;
  const int blk = blockIdx.x;
  float s[5] = {0.f, 0.f, 0.f, 0.f, 0.f};
  const float* vr = (blk < 1024) ? Wiq + (long)blk * D_ : biq;
  for (int e = t; e < D_; e += 256) {
    const float w = vr[e];
    s[0] = fmaf(w, F4[e], s[0]);
    s[1] = fmaf(w, F4[D_ + e], s[1]);
    s[2] = fmaf(w, F4[2 * D_ + e], s[2]);
    s[3] = fmaf(w, F4[3 * D_ + e], s[3]);
    s[4] = fmaf(w, bik[e], s[4]);
  }
  #pragma unroll
  for (int j = 0; j < 5; j++)
    #pragma unroll
    for (int m = 1; m < 64; m <<= 1) s[j] += __shfl_xor(s[j], m);
  const int w64 = t >> 6, lane = t & 63;
  if (lane == 0)
    #pragma unroll
    for (int j = 0; j < 5; j++) red[w64][j] = s[j];
  __syncthreads();
  if (t < 5)
    H5[(long)blk * 5 + t] = red[0][t] + red[1][t] + red[2][t] + red[3][t];
}

// =====================================================================
// MFMA GEMM v10. Tiled bf16 operands, linear global_load_lds staging,
// double-buffered LDS, counted vmcnt(4), XCD-swizzled blocks.
// Plain bf16 (1 MFMA/pair); waves 0,1 stage A halves, waves 2,3 stage
// B halves. 32 KB LDS.
// MODE 6: QKV fused.
//   z=0: Q-RMSNorm (+qnw, +folded 0.18033688 softmax scale) fused in
//        the epilogue -> Qnb bf16 [BN][1024]. (r22: attn3's per-block
//        norm deleted; same shfl-tree as the r21 K path; bit-identical
//        math on the same fp32 accs.)
//   z=1: K-RMSNorm fused -> Knb bf16 swizzled.
//   z=2: V -> Vtb bf16 transposed+swizzled.
// MODE 2: C = gate[row]*(A@B) + bias                  (final)
// =====================================================================
template<int MODE>
__global__ __launch_bounds__(256) void mfgemm2(
    const short* __restrict__ Ahi, const short* __restrict__ Bhi,
    const float* __restrict__ b0, const float* __restrict__ b1,
    const float* __restrict__ b2,
    float* __restrict__ C, short* __restrict__ Qout,
    short* __restrict__ Kout, short* __restrict__ Vout,
    const float* __restrict__ qnw, const float* __restrict__ knw,
    int bBlk, long sC, const float* __restrict__ gate_in)
{
  __shared__ short lds[2][2][4096];
  const int t = threadIdx.x, w = t >> 6, lane = t & 63;
  int bx, by, bz;
  xcd_swizzle(bx, by, bz);
  const int rowBase = by * 128;
  const int colBase = bx * 128;
  const long aoff = (long)by * 131072;   // 128 oct * 128 rows * 8
  const long boff = (long)(bz * bBlk + bx) * 131072;

  const int op = w >> 1, half = w & 1;
  const short* mySrc = op ? Bhi + boff : Ahi + aoff;

  auto stage = [&](int buf, int tt) {
    const short* g = mySrc + ((long)tt * 512 + half * 256 + lane) * 8;
    #pragma unroll
    for (int i = 0; i < 4; i++)
      GLOAD16(g + i * 512, &lds[buf][op][(half * 256 + i * 64) * 8]);
  };

  const int wr = w >> 1, wc = w & 1;
  const int lrow = lane & 31, lk = lane >> 5;

  f32x16 acc[2][2] = {};

  auto compute = [&](int buf) {
    #pragma unroll
    for (int kh = 0; kh < 2; kh++) {
      const int kq = 2 * kh + lk;
      bf16x8 ah[2], bh[2];
      #pragma unroll
      for (int m = 0; m < 2; m++)
        ah[m] = *(const bf16x8*)&lds[buf][0][(kq * 128 + wr * 64 + m * 32 + lrow) * 8];
      #pragma unroll
      for (int n = 0; n < 2; n++)
        bh[n] = *(const bf16x8*)&lds[buf][1][(kq * 128 + wc * 64 + n * 32 + lrow) * 8];
      #pragma unroll
      for (int m = 0; m < 2; m++)
        #pragma unroll
        for (int n = 0; n < 2; n++)
          acc[m][n] = mfma_bf16(ah[m], bh[n], acc[m][n]);
    }
  };

  const int NT = 32;   // K=1024 / BK=32
  stage(0, 0);
  for (int tt = 0; tt < NT - 1; ++tt) {
    stage((tt + 1) & 1, tt + 1);
    asm volatile("s_waitcnt vmcnt(4)" ::: "memory");
    __builtin_amdgcn_s_barrier();
    __builtin_amdgcn_sched_barrier(0);
    compute(tt & 1);
    __builtin_amdgcn_s_barrier();
  }
  asm volatile("s_waitcnt vmcnt(0)" ::: "memory");
  __builtin_amdgcn_s_barrier();
  __builtin_amdgcn_sched_barrier(0);
  compute((NT - 1) & 1);

  // ---------------- epilogue ----------------
  const float* bias = (bz == 1) ? b1 : (bz == 2) ? b2 : b0;
  float bcol[2];
  #pragma unroll
  for (int n = 0; n < 2; n++)
    bcol[n] = bias[colBase + wc * 64 + n * 32 + lrow];

  if (MODE == 6 && bz == 0) {
    // Q plane: RMSNorm (+qnw, +0.18033688 folded scale) -> Qnb bf16.
    // Row's 64 head-cols live across the 32 lrow-lanes of this lk
    // group -> shfl_xor masks 1..16 stay within the group.
    const float qw0 = qnw[lrow];
    const float qw1 = qnw[32 + lrow];
    const int col0 = colBase + wc * 64 + lrow;
    #pragma unroll
    for (int m = 0; m < 2; m++)
      #pragma unroll
      for (int r = 0; r < 16; r++) {
        const int row = rowBase + wr * 64 + m * 32 + (r & 3) + 8 * (r >> 2) + 4 * lk;
        const float v0 = acc[m][0][r] + bcol[0];
        const float v1 = acc[m][1][r] + bcol[1];
        float ss = v0 * v0 + v1 * v1;
        ss += __shfl_xor(ss, 1);
        ss += __shfl_xor(ss, 2);
        ss += __shfl_xor(ss, 4);
        ss += __shfl_xor(ss, 8);
        ss += __shfl_xor(ss, 16);
        const float qr = rsqrtf(ss * (1.f / 64.f) + 1e-6f) * 0.1803368801111244f;
        Qout[(long)row * D_ + col0]      = bf16_rn(v0 * qr * qw0);
        Qout[(long)row * D_ + col0 + 32] = bf16_rn(v1 * qr * qw1);
      }
    return;
  }

  if (MODE == 6 && bz == 1) {
    // K plane: RMSNorm (+knw) -> swizzled Knb (r21-proven).
    const float kw0 = knw[lrow];
    const float kw1 = knw[32 + lrow];
    const int h = (colBase + wc * 64) >> 6;
    #pragma unroll
    for (int m = 0; m < 2; m++)
      #pragma unroll
      for (int r = 0; r < 16; r++) {
        const int row = rowBase + wr * 64 + m * 32 + (r & 3) + 8 * (r >> 2) + 4 * lk;
        const int bb = row >> 9, g = bb >> 2;
        const int mkv = (bb & 3) * 512 + (row & 511);
        const float v0 = acc[m][0][r] + bcol[0];
        const float v1 = acc[m][1][r] + bcol[1];
        float ks2 = v0 * v0 + v1 * v1;
        ks2 += __shfl_xor(ks2, 1);
        ks2 += __shfl_xor(ks2, 2);
        ks2 += __shfl_xor(ks2, 4);
        ks2 += __shfl_xor(ks2, 8);
        ks2 += __shfl_xor(ks2, 16);
        const float kr = rsqrtf(ks2 * (1.f / 64.f) + 1e-6f);
        const long base = ((long)(g * H_ + h) * KVLEN + mkv) * 64;
        const int d0 = lrow, d1 = 32 + lrow;
        Kout[base + (((d0 >> 3) ^ (mkv & 7)) << 3) + (d0 & 7)] = bf16_rn(v0 * kr * kw0);
        Kout[base + (((d1 >> 3) ^ (mkv & 7)) << 3) + (d1 & 7)] = bf16_rn(v1 * kr * kw1);
      }
    return;
  }

  if (MODE == 6 && bz == 2) {
    // V plane: write straight to Vtb [g][h][tile][d][32kv] swizzled.
    #pragma unroll
    for (int m = 0; m < 2; m++)
      #pragma unroll
      for (int r = 0; r < 16; r++) {
        const int row = rowBase + wr * 64 + m * 32 + (r & 3) + 8 * (r >> 2) + 4 * lk;
        const int bb = row >> 9, g = bb >> 2;
        const int kv = (bb & 3) * 512 + (row & 511);
        const int tile = kv >> 5, vkv = kv & 31;
        #pragma unroll
        for (int n = 0; n < 2; n++) {
          const int col = colBase + wc * 64 + n * 32 + lrow;
          const int h = col >> 6, dl = col & 63;
          const long idx = ((long)(g * H_ + h) * 64 + tile) * 2048
                         + dl * 32 + (((vkv >> 3) ^ ((dl >> 1) & 3)) * 8) + (vkv & 7);
          Vout[idx] = bf16_rn(acc[m][n][r] + bcol[n]);
        }
      }
    return;
  }

  float* Cb = C + (long)bz * sC;
  #pragma unroll
  for (int m = 0; m < 2; m++) {
    #pragma unroll
    for (int r = 0; r < 16; r++) {
      const int row = rowBase + wr * 64 + m * 32 + (r & 3) + 8 * (r >> 2) + 4 * lk;
      float g = 1.f;
      if (MODE == 2) g = gate_in[row];
      #pragma unroll
      for (int n = 0; n < 2; n++) {
        const int col = colBase + wc * 64 + n * 32 + lrow;
        Cb[(long)row * D_ + col] = acc[m][n][r] * g + bcol[n];
      }
    }
  }
}

// =====================================================================
// MFMA grouped flash attention — KV-SPLIT x2, XCD-swizzled.
// r22: Q arrives pre-normalized/pre-scaled bf16 (QKV epilogue) — no
// per-block norm; l tree-summed (breaks the 16-deep fp add chain the
// compiler can't reassociate); o partials emitted bf16 (halves reduce
// traffic; partial rounding ~= the bf16 rounding o receives anyway,
// and absmax has sat at the compare floor since r4).
// 2-deep double-buffer, scalar l, permlane32_swap half-swap. STATIC
// max: partials combine exactly (o=sum, l=sum).
// =====================================================================
__global__ __launch_bounds__(256) void attn3(
    const short* __restrict__ q, const short* __restrict__ Knb,
    const short* __restrict__ Vtb,
    short* __restrict__ opart, float* __restrict__ lpart)
{
  int qb, h, bz;
  xcd_swizzle(qb, h, bz);
  const int b  = bz >> 1, s = bz & 1;
  const int g  = b >> 2;
  const int t  = threadIdx.x;
  const int w  = t >> 6;
  const int lane = t & 63;
  const int l31 = lane & 31, hi = lane >> 5;

  __shared__ short Kt[2][2048];
  __shared__ short Vt[2][2048];

  // ---- Q fragments: direct bf16 loads (pre-normalized, pre-scaled) ----
  const int qrow = qb * 128 + w * 32 + l31;
  const short* qp = q + ((long)b * N_ + qrow) * D_ + h * HD_ + hi * 8;
  bf16x8 qf[4];
  #pragma unroll
  for (int c = 0; c < 4; c++)
    qf[c] = *(const bf16x8*)&qp[c * 16];

  const short* Kg = Knb + (long)(g * H_ + h) * KVLEN * 64 + (long)s * 32 * 2048;
  const short* Vg = Vtb + (long)(g * H_ + h) * 64 * 2048 + (long)s * 32 * 2048;

  auto stage = [&](int buf, int i) {
    GLOAD16(Kg + (long)i * 2048 + t * 8, &Kt[buf][w * 512]);
    GLOAD16(Vg + (long)i * 2048 + t * 8, &Vt[buf][w * 512]);
  };

  f32x16 oacc[2] = {};
  float l = 0.f;

  stage(0, 0);
  for (int i = 0; i < 32; ++i) {
    const int buf = i & 1;
    if (i + 1 < 32) {
      stage(buf ^ 1, i + 1);
      asm volatile("s_waitcnt vmcnt(2)" ::: "memory");
    } else {
      asm volatile("s_waitcnt vmcnt(0)" ::: "memory");
    }
    __builtin_amdgcn_s_barrier();
    __builtin_amdgcn_sched_barrier(0);

    // ---- QK^T: scores[kv][q], pre-scaled via folded Q scale ----
    f32x16 sc = {};
    #pragma unroll
    for (int c = 0; c < 4; c++) {
      bf16x8 kfr = *(const bf16x8*)&Kt[buf][l31 * 64 + (((2 * c + hi) * 8) ^ ((l31 & 7) << 3))];
      sc = mfma_bf16(kfr, qf[c], sc);
    }
    // ---- softmax kernel: p~ = exp2(sc); l via balanced tree (ILP) ----
    float p[16];
    #pragma unroll
    for (int r = 0; r < 16; r++)
      p[r] = exp2f(sc[r]);
    l += ((((p[0] + p[1]) + (p[2] + p[3])) + ((p[4] + p[5]) + (p[6] + p[7])))
       + (((p[8] + p[9]) + (p[10] + p[11])) + ((p[12] + p[13]) + (p[14] + p[15]))));
    // ---- pack P pairs to bf16 (cvt_pk), half-swap via permlane32 ----
    unsigned wd[8];
    #pragma unroll
    for (int i2 = 0; i2 < 8; i2++)
      asm("v_cvt_pk_bf16_f32 %0, %1, %2" : "=v"(wd[i2]) : "v"(p[2 * i2]), "v"(p[2 * i2 + 1]));
    u32x2 r0 = __builtin_amdgcn_permlane32_swap(wd[0], wd[2], false, false);
    u32x2 r1 = __builtin_amdgcn_permlane32_swap(wd[1], wd[3], false, false);
    u32x2 r2 = __builtin_amdgcn_permlane32_swap(wd[4], wd[6], false, false);
    u32x2 r3 = __builtin_amdgcn_permlane32_swap(wd[5], wd[7], false, false);
    int4 f0 = { (int)r0.x, (int)r1.x, (int)r0.y, (int)r1.y };
    int4 f1 = { (int)r2.x, (int)r3.x, (int)r2.y, (int)r3.y };
    // ---- PV ----
    #pragma unroll
    for (int n = 0; n < 2; n++) {
      const int d = n * 32 + l31;
      const int fd = (d >> 1) & 3;
      bf16x8 v0 = *(const bf16x8*)&Vt[buf][d * 32 + ((hi ^ fd) * 8)];
      bf16x8 v1 = *(const bf16x8*)&Vt[buf][d * 32 + (((2 | hi) ^ fd) * 8)];
      oacc[n] = mfma_bf16(__builtin_bit_cast(bf16x8, f0), v0, oacc[n]);
      oacc[n] = mfma_bf16(__builtin_bit_cast(bf16x8, f1), v1, oacc[n]);
    }
    __builtin_amdgcn_s_barrier();
  }

  // ---- epilogue: write PARTIAL o (bf16, no divide) + l, plane s ----
  l += __shfl_xor(l, 32);
  #pragma unroll
  for (int r = 0; r < 16; r++) {
    const int qg = qb * 128 + w * 32 + (r & 3) + 8 * (r >> 2) + 4 * hi;
    short* op = opart + ((long)s * BN_ + b * N_ + qg) * D_ + h * HD_ + l31;
    op[0]  = bf16_rn(oacc[0][r]);
    op[32] = bf16_rn(oacc[1][r]);
  }
  if (hi == 0)
    lpart[((long)s * BN_ + b * N_ + qb * 128 + w * 32 + l31) * H_ + h] = l;
}

// =====================================================================
// attn_reduce2 — FUSED reduce + gate (bf16 partials; o hi-only).
//  A: o = (o0+o1)/(l0+l1) -> tiled bf16
//  B: G[0:5] = o·H5[:,j] + H5[1024][j]  (block reduce; G never stored)
//  C: gate[row] = 1 + mean_m sigmoid(sc*(G·mask[b][m] + G4))
// =====================================================================
__global__ __launch_bounds__(256) void attn_reduce2(
    const short* __restrict__ opart, const float* __restrict__ lpart,
    const float* __restrict__ H5, const float* __restrict__ mask,
    short* __restrict__ ohi, float* __restrict__ gate)
{
  __shared__ float red[4][5];
  __shared__ float Gs[5];
  __shared__ float sred[4];
  const int t = threadIdx.x;
  const int row = blockIdx.x;
  const int bb = row >> 9;
  const int col = t * 4;
  const int h   = col >> 6;
  // ---- A: combine 2 bf16 partial planes ----
  const float l = lpart[(long)row * H_ + h] + lpart[((long)BN_ + row) * H_ + h];
  const float inv = 1.f / l;
  s16x4 a4 = *(const s16x4*)&opart[(long)row * D_ + col];
  s16x4 b4 = *(const s16x4*)&opart[((long)BN_ + row) * D_ + col];
  float o4[4];
  #pragma unroll
  for (int c = 0; c < 4; c++)
    o4[c] = (bf2f(a4[c]) + bf2f(b4[c])) * inv;
  short hh[4];
  hh[0] = bf16_rn(o4[0]);  hh[1] = bf16_rn(o4[1]);
  hh[2] = bf16_rn(o4[2]);  hh[3] = bf16_rn(o4[3]);
  *(s16x4*)&ohi[tiled_off(row, col)] = *(s16x4*)hh;
  // ---- B: G = o . H5 (block reduce) ----
  float s[5] = {0.f, 0.f, 0.f, 0.f, 0.f};
  #pragma unroll
  for (int cc = 0; cc < 4; cc++) {
    const float* hp = &H5[(long)(col + cc) * 5];
    #pragma unroll
    for (int j = 0; j < 5; j++) s[j] = fmaf(o4[cc], hp[j], s[j]);
  }
  #pragma unroll
  for (int j = 0; j < 5; j++)
    #pragma unroll
    for (int m = 1; m < 64; m <<= 1) s[j] += __shfl_xor(s[j], m);
  const int w64 = t >> 6, lane = t & 63;
  if (lane == 0)
    #pragma unroll
    for (int j = 0; j < 5; j++) red[w64][j] = s[j];
  __syncthreads();
  if (t < 5) Gs[t] = red[0][t] + red[1][t] + red[2][t] + red[3][t] + H5[5120 + t];
  __syncthreads();
  const float g0 = Gs[0], g1 = Gs[1], g2 = Gs[2], g3 = Gs[3], g4 = Gs[4];
  // ---- C: gate via 512 sigmoids spread over the block ----
  const float sc = 0.125f / 16.f;       // SCALE/H
  const float* mrow = mask + (long)bb * N_ * NI_;
  float sg = 0.f;
  #pragma unroll
  for (int q = 0; q < 2; q++) {
    const float4 mk = *(const float4*)&mrow[(t * 2 + q) * 4];
    const float z = fmaf(g0, mk.x, fmaf(g1, mk.y, fmaf(g2, mk.z, fmaf(g3, mk.w, g4))));
    sg += 1.f / (1.f + __expf(-z * sc));
  }
  #pragma unroll
  for (int m = 1; m < 64; m <<= 1) sg += __shfl_xor(sg, m);
  if (lane == 0) sred[w64] = sg;
  __syncthreads();
  if (t == 0)
    gate[row] = 1.f + (sred[0] + sred[1] + sred[2] + sred[3]) * (1.f / 512.f);
}

// =====================================================================
extern "C" void kernel_launch(void* const* d_in, const int* in_sizes, int n_in,
                              void* d_out, int out_size, void* d_ws, size_t ws_size,
                              hipStream_t stream)
{
  const float* x    = (const float*)d_in[0];
  const float* mask = (const float*)d_in[1];
  const float* Wq   = (const float*)d_in[2];
  const float* bq   = (const float*)d_in[3];
  const float* Wk   = (const float*)d_in[4];
  const float* bk   = (const float*)d_in[5];
  const float* Wv   = (const float*)d_in[6];
  const float* bv   = (const float*)d_in[7];
  const float* Wo   = (const float*)d_in[8];
  const float* bo   = (const float*)d_in[9];
  const float* Wiq  = (const float*)d_in[10];
  const float* biq  = (const float*)d_in[11];
  const float* Wik  = (const float*)d_in[12];
  const float* bik  = (const float*)d_in[13];
  const float* emb  = (const float*)d_in[14];
  const float* qnw  = (const float*)d_in[15];
  const float* knw  = (const float*)d_in[16];
  float* out = (float*)d_out;

  // Workspace (within the round-9-proven footprint).
  // Lifetime audit (launch #):
  //  [0,SZ)     Qnb bf16 (w:5(QKV z=0 epi) r:6) -> ohi bf16 (w:7 r:8)
  //  [SZ,2SZ)   opart bf16 [2][BN][D] shorts (w:6 r:7). Dead during QKV.
  //  [3SZ,4SZ)  Knb bf16 (w:5(QKV z=1 epi) r:6). Dead during staging.
  //  [4SZ,4.5SZ) xhi: x tiled bf16 (w:4 r:5)
  //  [4.5SZ,5SZ) Vtb bf16 (w:5(QKV z=2 epi) r:6) — overlays dead xlo
  //  Wbig_hi:   QKV weights (w:4 r:5) -> gate + lpart[2] (w:7/6 r:8/7)
  //  Wbig_lo:   WoH (w:4 r:8) | F4 (w:2 r:3) | H5 (w:3 r:7) | F4p (w:1 r:2)
  float* ws = (float*)d_ws;
  const size_t SZ = (size_t)BN_ * D_;
  short* Qnb  = (short*)ws;             // [BN][1024] bf16 (normalized q)
  short* ohi  = (short*)ws;             // post-attn3: o bf16 tiled
  short* opart = (short*)(ws + SZ);     // [2][BN][D] bf16 attn partials
  short* Knb  = (short*)(ws + 3 * SZ);  // [2][16][2048][64] bf16
  short* xhi  = (short*)(ws + 4 * SZ);
  short* Vtb  = xhi + SZ;               // [2][16][64][64][32] bf16
  short* Wbig_hi = (short*)(ws + 5 * SZ);
  short* Wbig_lo = Wbig_hi + (size_t)3 * D_ * D_;
  float* gate  = (float*)Wbig_hi;                       // [BN] (post-QKV)
  float* lpart = gate + BN_;                            // [2][BN][16]
  short* WoH = Wbig_lo;                                 // [D][D] tiled
  float* F4  = (float*)(Wbig_lo + (size_t)D_ * D_);     // [4][1024]
  float* H5  = F4 + 4 * D_;                             // [1025][5]
  float* F4p = H5 + 1025 * 5;                           // [64][4][1024]

  const dim3 blk(256);

  // 1-3) gate-path algebra prep (rank-5 collapse), parallel grids
  fprep_p<<<dim3(4, 64), blk, 0, stream>>>(Wik, emb, F4p);
  freduce<<<dim3(16), blk, 0, stream>>>(F4p, F4);
  hprep2<<<dim3(1025), blk, 0, stream>>>(Wiq, F4, bik, biq, H5);

  // 4) weight prep (Wq,Wk,Wv,Wo) + x -> tiled bf16, ONE dispatch
  wsplitAll<<<dim3(16, 16, 8), blk, 0, stream>>>(
      Wq, Wk, Wv, Wo, x, Wbig_hi, WoH, xhi);

  // 5) fused QKV projection; Q-norm -> Qnb, K-norm -> Knb, V -> Vtb
  mfgemm2<6><<<dim3(8, 32, 3), blk, 0, stream>>>(
      xhi, Wbig_hi, bq, bk, bv,
      nullptr, Qnb, Knb, Vtb, qnw, knw, 8, 0, nullptr);

  // 6) attention, KV-split x2 -> bf16 partials
  attn3<<<dim3(N_ / 128, H_, B_ * 2), blk, 0, stream>>>(
      Qnb, Knb, Vtb, opart, lpart);

  // 7) combine partials -> o bf16 (over dead Qnb region), gate in-block
  attn_reduce2<<<BN_, blk, 0, stream>>>(opart, lpart, H5, mask, ohi, gate);

  // 8) final: gate[row]*(o@Wo) + bo -> d_out (plain bf16)
  mfgemm2<2><<<dim3(8, 32, 1), blk, 0, stream>>>(
      ohi, WoH, bo, nullptr, nullptr,
      out, nullptr, nullptr, nullptr, nullptr, nullptr, 0, 0, gate);
}

// Round 23
// 174.125 us; speedup vs baseline: 1.7468x; 1.0332x over previous
//
#include <hip/hip_runtime.h>
#include <cmath>

// Problem constants (fixed by the reference file)
#define B_   8
#define N_   512
#define D_   1024
#define H_   16
#define HD_  64
#define NI_  4
#define BN_  (B_*N_)      // 4096 rows when [B,N,*] is flattened
#define KVLEN (NI_*N_)    // 2048 keys per attention group

typedef __attribute__((ext_vector_type(8)))  short  bf16x8;   // 8 bf16 bit patterns
typedef __attribute__((ext_vector_type(8)))  __bf16 bf16x8_t; // builtin operand type
typedef __attribute__((ext_vector_type(16))) float  f32x16;
typedef __attribute__((ext_vector_type(4)))  short  s16x4;
typedef __attribute__((ext_vector_type(2)))  unsigned u32x2;

// round-to-nearest-even bf16 conversion (bit trick)
__device__ __forceinline__ short bf16_rn(float x) {
  unsigned u = __float_as_uint(x);
  unsigned r = (u + 0x7FFFu + ((u >> 16) & 1u)) >> 16;
  return (short)r;
}

__device__ __forceinline__ float bf2f(short x) {
  return __uint_as_float(((unsigned)(unsigned short)x) << 16);
}

__device__ __forceinline__ f32x16 mfma_bf16(bf16x8 a, bf16x8 b, f32x16 c) {
  return __builtin_amdgcn_mfma_f32_32x32x16_bf16(
      __builtin_bit_cast(bf16x8_t, a), __builtin_bit_cast(bf16x8_t, b), c, 0, 0, 0);
}

#define GLOAD16(gp, lp) __builtin_amdgcn_global_load_lds( \
  (const __attribute__((address_space(1))) unsigned*)(gp), \
  (__attribute__((address_space(3))) unsigned*)(lp), 16, 0, 0)

// TILED layout for all bf16 GEMM operands (K = 1024):
// addr(row,k) = (((row>>7)*128 + (k>>3))*128 + (row&127))*8 + (k&7).
// GEMM staging is then a LINEAR copy -> fully coalesced global_load_lds.
__device__ __forceinline__ long tiled_off(int row, int k) {
  return ((((long)(row >> 7) * 128 + (k >> 3)) * 128 + (row & 127)) * 8 + (k & 7));
}

// T1 XCD-aware block swizzle (MI355X: 8 XCDs, private L2s). Remap so each
// XCD gets a CONTIGUOUS tile range. REQUIRES nwg % 8 == 0.
__device__ __forceinline__ void xcd_swizzle(int& bx, int& by, int& bz) {
  const int gx = gridDim.x, gy = gridDim.y;
  const int nwg = gx * gy * gridDim.z;
  const int lin = blockIdx.x + gx * (blockIdx.y + gy * blockIdx.z);
  const int swz = (lin & 7) * (nwg >> 3) + (lin >> 3);
  bx = swz % gx;
  const int rest = swz / gx;
  by = rest % gy;
  bz = rest / gy;
}

// =====================================================================
// Weight + x prep, ONE dispatch (z=0..7):
//  z=0..2: Wq/Wk/Wv -> QKVh (combined [3072][1024] tiled, transposed)
//  z=3:    Wo -> WoH (tiled, transposed)
//  z=4..7: x rows (z-4)*1024.. -> Xh (tiled, direct convert)
// All hi-only bf16.
// =====================================================================
__global__ __launch_bounds__(256) void wsplitAll(
    const float* __restrict__ Wq, const float* __restrict__ Wk,
    const float* __restrict__ Wv, const float* __restrict__ Wo,
    const float* __restrict__ x,
    short* __restrict__ QKVh, short* __restrict__ WoH,
    short* __restrict__ Xh)
{
  const int z = blockIdx.z;
  const int t  = threadIdx.x;
  if (z >= 4) {
    const int rowB = (z - 4) * 1024 + blockIdx.y * 64;
    const int colB = blockIdx.x * 64;
    const int r0 = t >> 4;
    const int c4 = t & 15;
    #pragma unroll
    for (int i = 0; i < 4; i++) {
      const int row = rowB + r0 + i * 16;
      float4 v = *(const float4*)&x[(long)row * D_ + colB + c4 * 4];
      short h[4];
      h[0] = bf16_rn(v.x);  h[1] = bf16_rn(v.y);
      h[2] = bf16_rn(v.z);  h[3] = bf16_rn(v.w);
      *(s16x4*)&Xh[tiled_off(row, colB + c4 * 4)] = *(s16x4*)h;
    }
    return;
  }
  __shared__ float tile[64][65];
  const float* W = (z == 0) ? Wq : (z == 1) ? Wk : (z == 2) ? Wv : Wo;
  const int kb = blockIdx.y * 64;
  const int cb = blockIdx.x * 64;
  const int r0 = t >> 4;
  const int c4 = t & 15;
  #pragma unroll
  for (int i = 0; i < 4; i++) {
    const int r = r0 + i * 16;
    *(float4*)&tile[r][c4 * 4] = *(const float4*)&W[(long)(kb + r) * D_ + cb + c4 * 4];
  }
  __syncthreads();
  #pragma unroll
  for (int i = 0; i < 4; i++) {
    const int c = r0 + i * 16;
    short hi[4];
    #pragma unroll
    for (int e = 0; e < 4; e++)
      hi[e] = bf16_rn(tile[c4 * 4 + e][c]);
    if (z < 3)
      *(s16x4*)&QKVh[tiled_off(z * D_ + cb + c, kb + c4 * 4)] = *(s16x4*)hi;
    else
      *(s16x4*)&WoH[tiled_off(cb + c, kb + c4 * 4)] = *(s16x4*)hi;
  }
}

// =====================================================================
// Gate-path prep A: F4p[eb][j][d] = sum_{e in 16-chunk eb} emb[j][e] *
// Wik[e][d].  grid (4,64) = 256 blocks; coalesced 1KB row segments.
// =====================================================================
__global__ __launch_bounds__(256) void fprep_p(
    const float* __restrict__ Wik, const float* __restrict__ emb,
    float* __restrict__ F4p)
{
  const int d  = blockIdx.x * 256 + threadIdx.x;
  const int eb = blockIdx.y;
  float s0 = 0, s1 = 0, s2 = 0, s3 = 0;
  for (int e = eb * 16; e < eb * 16 + 16; e++) {
    const float w = Wik[(long)e * D_ + d];
    s0 = fmaf(emb[e], w, s0);
    s1 = fmaf(emb[D_ + e], w, s1);
    s2 = fmaf(emb[2 * D_ + e], w, s2);
    s3 = fmaf(emb[3 * D_ + e], w, s3);
  }
  float* p = F4p + (long)eb * 4 * D_;
  p[d] = s0;  p[D_ + d] = s1;  p[2 * D_ + d] = s2;  p[3 * D_ + d] = s3;
}

// freduce: F4[j][d] = sum of 64 e-chunk partials (fixed order).
__global__ __launch_bounds__(256) void freduce(
    const float* __restrict__ F4p, float* __restrict__ F4)
{
  const int i = blockIdx.x * 256 + threadIdx.x;   // 0..4095
  float s = 0.f;
  #pragma unroll
  for (int eb = 0; eb < 64; eb++) s += F4p[(long)eb * 4096 + i];
  F4[i] = s;
}

// =====================================================================
// Gate-path prep B: H5[d][j] = Wiq[d]·F4[j] (j<4); H5[d][4]=Wiq[d]·bik.
// Consts row H5[1024][j] = F4[j]·biq (j<4), H5[1024][4] = biq·bik.
// One block per d-row (1024 + 1 consts): coalesced 4KB row reads.
// =====================================================================
__global__ __launch_bounds__(256) void hprep2(
    const float* __restrict__ Wiq, const float* __restrict__ F4,
    const float* __restrict__ bik, const float* __restrict__ biq,
    float* __restrict__ H5)
{
  __shared__ float red[4][5];
  const int t = threadIdx.x;
  const int blk = blockIdx.x;
  float s[5] = {0.f, 0.f, 0.f, 0.f, 0.f};
  const float* vr = (blk < 1024) ? Wiq + (long)blk * D_ : biq;
  for (int e = t; e < D_; e += 256) {
    const float w = vr[e];
    s[0] = fmaf(w, F4[e], s[0]);
    s[1] = fmaf(w, F4[D_ + e], s[1]);
    s[2] = fmaf(w, F4[2 * D_ + e], s[2]);
    s[3] = fmaf(w, F4[3 * D_ + e], s[3]);
    s[4] = fmaf(w, bik[e], s[4]);
  }
  #pragma unroll
  for (int j = 0; j < 5; j++)
    #pragma unroll
    for (int m = 1; m < 64; m <<= 1) s[j] += __shfl_xor(s[j], m);
  const int w64 = t >> 6, lane = t & 63;
  if (lane == 0)
    #pragma unroll
    for (int j = 0; j < 5; j++) red[w64][j] = s[j];
  __syncthreads();
  if (t < 5)
    H5[(long)blk * 5 + t] = red[0][t] + red[1][t] + red[2][t] + red[3][t];
}

// =====================================================================
// MFMA GEMM v10. Tiled bf16 operands, linear global_load_lds staging,
// double-buffered LDS, counted vmcnt(4), XCD-swizzled blocks.
// Plain bf16 (1 MFMA/pair); waves 0,1 stage A halves, waves 2,3 stage
// B halves. 32 KB LDS.
// MODE 6: QKV fused.
//   z=0: Q-RMSNorm (+qnw, +folded 0.18033688 softmax scale) -> Qnb.
//   z=1: K-RMSNorm fused -> Knb bf16 swizzled.
//   z=2: V -> Vtb bf16 transposed+swizzled.
// MODE 2: C = gate[row]*(A@B) + bias                  (final)
// =====================================================================
template<int MODE>
__global__ __launch_bounds__(256) void mfgemm2(
    const short* __restrict__ Ahi, const short* __restrict__ Bhi,
    const float* __restrict__ b0, const float* __restrict__ b1,
    const float* __restrict__ b2,
    float* __restrict__ C, short* __restrict__ Qout,
    short* __restrict__ Kout, short* __restrict__ Vout,
    const float* __restrict__ qnw, const float* __restrict__ knw,
    int bBlk, long sC, const float* __restrict__ gate_in)
{
  __shared__ short lds[2][2][4096];
  const int t = threadIdx.x, w = t >> 6, lane = t & 63;
  int bx, by, bz;
  xcd_swizzle(bx, by, bz);
  const int rowBase = by * 128;
  const int colBase = bx * 128;
  const long aoff = (long)by * 131072;   // 128 oct * 128 rows * 8
  const long boff = (long)(bz * bBlk + bx) * 131072;

  const int op = w >> 1, half = w & 1;
  const short* mySrc = op ? Bhi + boff : Ahi + aoff;

  auto stage = [&](int buf, int tt) {
    const short* g = mySrc + ((long)tt * 512 + half * 256 + lane) * 8;
    #pragma unroll
    for (int i = 0; i < 4; i++)
      GLOAD16(g + i * 512, &lds[buf][op][(half * 256 + i * 64) * 8]);
  };

  const int wr = w >> 1, wc = w & 1;
  const int lrow = lane & 31, lk = lane >> 5;

  f32x16 acc[2][2] = {};

  auto compute = [&](int buf) {
    #pragma unroll
    for (int kh = 0; kh < 2; kh++) {
      const int kq = 2 * kh + lk;
      bf16x8 ah[2], bh[2];
      #pragma unroll
      for (int m = 0; m < 2; m++)
        ah[m] = *(const bf16x8*)&lds[buf][0][(kq * 128 + wr * 64 + m * 32 + lrow) * 8];
      #pragma unroll
      for (int n = 0; n < 2; n++)
        bh[n] = *(const bf16x8*)&lds[buf][1][(kq * 128 + wc * 64 + n * 32 + lrow) * 8];
      #pragma unroll
      for (int m = 0; m < 2; m++)
        #pragma unroll
        for (int n = 0; n < 2; n++)
          acc[m][n] = mfma_bf16(ah[m], bh[n], acc[m][n]);
    }
  };

  const int NT = 32;   // K=1024 / BK=32
  stage(0, 0);
  for (int tt = 0; tt < NT - 1; ++tt) {
    stage((tt + 1) & 1, tt + 1);
    asm volatile("s_waitcnt vmcnt(4)" ::: "memory");
    __builtin_amdgcn_s_barrier();
    __builtin_amdgcn_sched_barrier(0);
    compute(tt & 1);
    __builtin_amdgcn_s_barrier();
  }
  asm volatile("s_waitcnt vmcnt(0)" ::: "memory");
  __builtin_amdgcn_s_barrier();
  __builtin_amdgcn_sched_barrier(0);
  compute((NT - 1) & 1);

  // ---------------- epilogue ----------------
  const float* bias = (bz == 1) ? b1 : (bz == 2) ? b2 : b0;
  float bcol[2];
  #pragma unroll
  for (int n = 0; n < 2; n++)
    bcol[n] = bias[colBase + wc * 64 + n * 32 + lrow];

  if (MODE == 6 && bz == 0) {
    // Q plane: RMSNorm (+qnw, +0.18033688 folded scale) -> Qnb bf16.
    const float qw0 = qnw[lrow];
    const float qw1 = qnw[32 + lrow];
    const int col0 = colBase + wc * 64 + lrow;
    #pragma unroll
    for (int m = 0; m < 2; m++)
      #pragma unroll
      for (int r = 0; r < 16; r++) {
        const int row = rowBase + wr * 64 + m * 32 + (r & 3) + 8 * (r >> 2) + 4 * lk;
        const float v0 = acc[m][0][r] + bcol[0];
        const float v1 = acc[m][1][r] + bcol[1];
        float ss = v0 * v0 + v1 * v1;
        ss += __shfl_xor(ss, 1);
        ss += __shfl_xor(ss, 2);
        ss += __shfl_xor(ss, 4);
        ss += __shfl_xor(ss, 8);
        ss += __shfl_xor(ss, 16);
        const float qr = rsqrtf(ss * (1.f / 64.f) + 1e-6f) * 0.1803368801111244f;
        Qout[(long)row * D_ + col0]      = bf16_rn(v0 * qr * qw0);
        Qout[(long)row * D_ + col0 + 32] = bf16_rn(v1 * qr * qw1);
      }
    return;
  }

  if (MODE == 6 && bz == 1) {
    // K plane: RMSNorm (+knw) -> swizzled Knb (r21-proven).
    const float kw0 = knw[lrow];
    const float kw1 = knw[32 + lrow];
    const int h = (colBase + wc * 64) >> 6;
    #pragma unroll
    for (int m = 0; m < 2; m++)
      #pragma unroll
      for (int r = 0; r < 16; r++) {
        const int row = rowBase + wr * 64 + m * 32 + (r & 3) + 8 * (r >> 2) + 4 * lk;
        const int bb = row >> 9, g = bb >> 2;
        const int mkv = (bb & 3) * 512 + (row & 511);
        const float v0 = acc[m][0][r] + bcol[0];
        const float v1 = acc[m][1][r] + bcol[1];
        float ks2 = v0 * v0 + v1 * v1;
        ks2 += __shfl_xor(ks2, 1);
        ks2 += __shfl_xor(ks2, 2);
        ks2 += __shfl_xor(ks2, 4);
        ks2 += __shfl_xor(ks2, 8);
        ks2 += __shfl_xor(ks2, 16);
        const float kr = rsqrtf(ks2 * (1.f / 64.f) + 1e-6f);
        const long base = ((long)(g * H_ + h) * KVLEN + mkv) * 64;
        const int d0 = lrow, d1 = 32 + lrow;
        Kout[base + (((d0 >> 3) ^ (mkv & 7)) << 3) + (d0 & 7)] = bf16_rn(v0 * kr * kw0);
        Kout[base + (((d1 >> 3) ^ (mkv & 7)) << 3) + (d1 & 7)] = bf16_rn(v1 * kr * kw1);
      }
    return;
  }

  if (MODE == 6 && bz == 2) {
    // V plane: write straight to Vtb [g][h][tile][d][32kv] swizzled.
    #pragma unroll
    for (int m = 0; m < 2; m++)
      #pragma unroll
      for (int r = 0; r < 16; r++) {
        const int row = rowBase + wr * 64 + m * 32 + (r & 3) + 8 * (r >> 2) + 4 * lk;
        const int bb = row >> 9, g = bb >> 2;
        const int kv = (bb & 3) * 512 + (row & 511);
        const int tile = kv >> 5, vkv = kv & 31;
        #pragma unroll
        for (int n = 0; n < 2; n++) {
          const int col = colBase + wc * 64 + n * 32 + lrow;
          const int h = col >> 6, dl = col & 63;
          const long idx = ((long)(g * H_ + h) * 64 + tile) * 2048
                         + dl * 32 + (((vkv >> 3) ^ ((dl >> 1) & 3)) * 8) + (vkv & 7);
          Vout[idx] = bf16_rn(acc[m][n][r] + bcol[n]);
        }
      }
    return;
  }

  float* Cb = C + (long)bz * sC;
  #pragma unroll
  for (int m = 0; m < 2; m++) {
    #pragma unroll
    for (int r = 0; r < 16; r++) {
      const int row = rowBase + wr * 64 + m * 32 + (r & 3) + 8 * (r >> 2) + 4 * lk;
      float g = 1.f;
      if (MODE == 2) g = gate_in[row];
      #pragma unroll
      for (int n = 0; n < 2; n++) {
        const int col = colBase + wc * 64 + n * 32 + lrow;
        Cb[(long)row * D_ + col] = acc[m][n][r] * g + bcol[n];
      }
    }
  }
}

// =====================================================================
// MFMA grouped flash attention — KV-SPLIT x2, XCD-swizzled.
// r23: KVBLK=64 — two 32-kv sub-tiles per barrier pair (iterations
// 32->16, barriers halved; per-sub-tile body byte-identical, executed
// in the same kv order -> bit-identical l/oacc accumulation). LDS
// 32 KB (still 4 blocks/CU at grid limit). 4 gloads/stage, vmcnt(4).
// Q pre-normalized/pre-scaled bf16; tree-summed l; bf16 o partials.
// STATIC max: partials combine exactly (o=sum, l=sum).
// =====================================================================
__global__ __launch_bounds__(256) void attn3(
    const short* __restrict__ q, const short* __restrict__ Knb,
    const short* __restrict__ Vtb,
    short* __restrict__ opart, float* __restrict__ lpart)
{
  int qb, h, bz;
  xcd_swizzle(qb, h, bz);
  const int b  = bz >> 1, s = bz & 1;
  const int g  = b >> 2;
  const int t  = threadIdx.x;
  const int w  = t >> 6;
  const int lane = t & 63;
  const int l31 = lane & 31, hi = lane >> 5;

  __shared__ short Kt[2][4096];
  __shared__ short Vt[2][4096];

  // ---- Q fragments: direct bf16 loads (pre-normalized, pre-scaled) ----
  const int qrow = qb * 128 + w * 32 + l31;
  const short* qp = q + ((long)b * N_ + qrow) * D_ + h * HD_ + hi * 8;
  bf16x8 qf[4];
  #pragma unroll
  for (int c = 0; c < 4; c++)
    qf[c] = *(const bf16x8*)&qp[c * 16];

  const short* Kg = Knb + (long)(g * H_ + h) * KVLEN * 64 + (long)s * 32 * 2048;
  const short* Vg = Vtb + (long)(g * H_ + h) * 64 * 2048 + (long)s * 32 * 2048;

  auto stage = [&](int buf, int i) {   // i = 64-kv chunk, 0..15
    GLOAD16(Kg + (long)i * 4096 + t * 8,        &Kt[buf][w * 512]);
    GLOAD16(Kg + (long)i * 4096 + 2048 + t * 8, &Kt[buf][2048 + w * 512]);
    GLOAD16(Vg + (long)i * 4096 + t * 8,        &Vt[buf][w * 512]);
    GLOAD16(Vg + (long)i * 4096 + 2048 + t * 8, &Vt[buf][2048 + w * 512]);
  };

  f32x16 oacc[2] = {};
  float l = 0.f;

  stage(0, 0);
  for (int i = 0; i < 16; ++i) {
    const int buf = i & 1;
    if (i + 1 < 16) {
      stage(buf ^ 1, i + 1);
      asm volatile("s_waitcnt vmcnt(4)" ::: "memory");
    } else {
      asm volatile("s_waitcnt vmcnt(0)" ::: "memory");
    }
    __builtin_amdgcn_s_barrier();
    __builtin_amdgcn_sched_barrier(0);

    #pragma unroll
    for (int ss = 0; ss < 2; ss++) {
      const short* Ktb = &Kt[buf][ss * 2048];
      const short* Vsb = &Vt[buf][ss * 2048];
      // ---- QK^T: scores[kv][q], pre-scaled via folded Q scale ----
      f32x16 sc = {};
      #pragma unroll
      for (int c = 0; c < 4; c++) {
        bf16x8 kfr = *(const bf16x8*)&Ktb[l31 * 64 + (((2 * c + hi) * 8) ^ ((l31 & 7) << 3))];
        sc = mfma_bf16(kfr, qf[c], sc);
      }
      // ---- softmax kernel: p~ = exp2(sc); l via balanced tree ----
      float p[16];
      #pragma unroll
      for (int r = 0; r < 16; r++)
        p[r] = exp2f(sc[r]);
      l += ((((p[0] + p[1]) + (p[2] + p[3])) + ((p[4] + p[5]) + (p[6] + p[7])))
         + (((p[8] + p[9]) + (p[10] + p[11])) + ((p[12] + p[13]) + (p[14] + p[15]))));
      // ---- pack P pairs to bf16 (cvt_pk), half-swap via permlane32 ----
      unsigned wd[8];
      #pragma unroll
      for (int i2 = 0; i2 < 8; i2++)
        asm("v_cvt_pk_bf16_f32 %0, %1, %2" : "=v"(wd[i2]) : "v"(p[2 * i2]), "v"(p[2 * i2 + 1]));
      u32x2 r0 = __builtin_amdgcn_permlane32_swap(wd[0], wd[2], false, false);
      u32x2 r1 = __builtin_amdgcn_permlane32_swap(wd[1], wd[3], false, false);
      u32x2 r2 = __builtin_amdgcn_permlane32_swap(wd[4], wd[6], false, false);
      u32x2 r3 = __builtin_amdgcn_permlane32_swap(wd[5], wd[7], false, false);
      int4 f0 = { (int)r0.x, (int)r1.x, (int)r0.y, (int)r1.y };
      int4 f1 = { (int)r2.x, (int)r3.x, (int)r2.y, (int)r3.y };
      // ---- PV ----
      #pragma unroll
      for (int n = 0; n < 2; n++) {
        const int d = n * 32 + l31;
        const int fd = (d >> 1) & 3;
        bf16x8 v0 = *(const bf16x8*)&Vsb[d * 32 + ((hi ^ fd) * 8)];
        bf16x8 v1 = *(const bf16x8*)&Vsb[d * 32 + (((2 | hi) ^ fd) * 8)];
        oacc[n] = mfma_bf16(__builtin_bit_cast(bf16x8, f0), v0, oacc[n]);
        oacc[n] = mfma_bf16(__builtin_bit_cast(bf16x8, f1), v1, oacc[n]);
      }
    }
    __builtin_amdgcn_s_barrier();
  }

  // ---- epilogue: write PARTIAL o (bf16, no divide) + l, plane s ----
  l += __shfl_xor(l, 32);
  #pragma unroll
  for (int r = 0; r < 16; r++) {
    const int qg = qb * 128 + w * 32 + (r & 3) + 8 * (r >> 2) + 4 * hi;
    short* op = opart + ((long)s * BN_ + b * N_ + qg) * D_ + h * HD_ + l31;
    op[0]  = bf16_rn(oacc[0][r]);
    op[32] = bf16_rn(oacc[1][r]);
  }
  if (hi == 0)
    lpart[((long)s * BN_ + b * N_ + qb * 128 + w * 32 + l31) * H_ + h] = l;
}

// =====================================================================
// attn_reduce2 — FUSED reduce + gate (bf16 partials; o hi-only).
//  A: o = (o0+o1)/(l0+l1) -> tiled bf16
//  B: G[0:5] = o·H5[:,j] + H5[1024][j]  (block reduce; G never stored)
//  C: gate[row] = 1 + mean_m sigmoid(sc*(G·mask[b][m] + G4))
// =====================================================================
__global__ __launch_bounds__(256) void attn_reduce2(
    const short* __restrict__ opart, const float* __restrict__ lpart,
    const float* __restrict__ H5, const float* __restrict__ mask,
    short* __restrict__ ohi, float* __restrict__ gate)
{
  __shared__ float red[4][5];
  __shared__ float Gs[5];
  __shared__ float sred[4];
  const int t = threadIdx.x;
  const int row = blockIdx.x;
  const int bb = row >> 9;
  const int col = t * 4;
  const int h   = col >> 6;
  // ---- A: combine 2 bf16 partial planes ----
  const float l = lpart[(long)row * H_ + h] + lpart[((long)BN_ + row) * H_ + h];
  const float inv = 1.f / l;
  s16x4 a4 = *(const s16x4*)&opart[(long)row * D_ + col];
  s16x4 b4 = *(const s16x4*)&opart[((long)BN_ + row) * D_ + col];
  float o4[4];
  #pragma unroll
  for (int c = 0; c < 4; c++)
    o4[c] = (bf2f(a4[c]) + bf2f(b4[c])) * inv;
  short hh[4];
  hh[0] = bf16_rn(o4[0]);  hh[1] = bf16_rn(o4[1]);
  hh[2] = bf16_rn(o4[2]);  hh[3] = bf16_rn(o4[3]);
  *(s16x4*)&ohi[tiled_off(row, col)] = *(s16x4*)hh;
  // ---- B: G = o . H5 (block reduce) ----
  float s[5] = {0.f, 0.f, 0.f, 0.f, 0.f};
  #pragma unroll
  for (int cc = 0; cc < 4; cc++) {
    const float* hp = &H5[(long)(col + cc) * 5];
    #pragma unroll
    for (int j = 0; j < 5; j++) s[j] = fmaf(o4[cc], hp[j], s[j]);
  }
  #pragma unroll
  for (int j = 0; j < 5; j++)
    #pragma unroll
    for (int m = 1; m < 64; m <<= 1) s[j] += __shfl_xor(s[j], m);
  const int w64 = t >> 6, lane = t & 63;
  if (lane == 0)
    #pragma unroll
    for (int j = 0; j < 5; j++) red[w64][j] = s[j];
  __syncthreads();
  if (t < 5) Gs[t] = red[0][t] + red[1][t] + red[2][t] + red[3][t] + H5[5120 + t];
  __syncthreads();
  const float g0 = Gs[0], g1 = Gs[1], g2 = Gs[2], g3 = Gs[3], g4 = Gs[4];
  // ---- C: gate via 512 sigmoids spread over the block ----
  const float sc = 0.125f / 16.f;       // SCALE/H
  const float* mrow = mask + (long)bb * N_ * NI_;
  float sg = 0.f;
  #pragma unroll
  for (int q = 0; q < 2; q++) {
    const float4 mk = *(const float4*)&mrow[(t * 2 + q) * 4];
    const float z = fmaf(g0, mk.x, fmaf(g1, mk.y, fmaf(g2, mk.z, fmaf(g3, mk.w, g4))));
    sg += 1.f / (1.f + __expf(-z * sc));
  }
  #pragma unroll
  for (int m = 1; m < 64; m <<= 1) sg += __shfl_xor(sg, m);
  if (lane == 0) sred[w64] = sg;
  __syncthreads();
  if (t == 0)
    gate[row] = 1.f + (sred[0] + sred[1] + sred[2] + sred[3]) * (1.f / 512.f);
}

// =====================================================================
extern "C" void kernel_launch(void* const* d_in, const int* in_sizes, int n_in,
                              void* d_out, int out_size, void* d_ws, size_t ws_size,
                              hipStream_t stream)
{
  const float* x    = (const float*)d_in[0];
  const float* mask = (const float*)d_in[1];
  const float* Wq   = (const float*)d_in[2];
  const float* bq   = (const float*)d_in[3];
  const float* Wk   = (const float*)d_in[4];
  const float* bk   = (const float*)d_in[5];
  const float* Wv   = (const float*)d_in[6];
  const float* bv   = (const float*)d_in[7];
  const float* Wo   = (const float*)d_in[8];
  const float* bo   = (const float*)d_in[9];
  const float* Wiq  = (const float*)d_in[10];
  const float* biq  = (const float*)d_in[11];
  const float* Wik  = (const float*)d_in[12];
  const float* bik  = (const float*)d_in[13];
  const float* emb  = (const float*)d_in[14];
  const float* qnw  = (const float*)d_in[15];
  const float* knw  = (const float*)d_in[16];
  float* out = (float*)d_out;

  // Workspace (within the round-9-proven footprint).
  // Lifetime audit (launch #):
  //  [0,SZ)     Qnb bf16 (w:5(QKV z=0 epi) r:6) -> ohi bf16 (w:7 r:8)
  //  [SZ,2SZ)   opart bf16 [2][BN][D] shorts (w:6 r:7). Dead during QKV.
  //  [3SZ,4SZ)  Knb bf16 (w:5(QKV z=1 epi) r:6). Dead during staging.
  //  [4SZ,4.5SZ) xhi: x tiled bf16 (w:4 r:5)
  //  [4.5SZ,5SZ) Vtb bf16 (w:5(QKV z=2 epi) r:6) — overlays dead xlo
  //  Wbig_hi:   QKV weights (w:4 r:5) -> gate + lpart[2] (w:7/6 r:8/7)
  //  Wbig_lo:   WoH (w:4 r:8) | F4 (w:2 r:3) | H5 (w:3 r:7) | F4p (w:1 r:2)
  float* ws = (float*)d_ws;
  const size_t SZ = (size_t)BN_ * D_;
  short* Qnb  = (short*)ws;             // [BN][1024] bf16 (normalized q)
  short* ohi  = (short*)ws;             // post-attn3: o bf16 tiled
  short* opart = (short*)(ws + SZ);     // [2][BN][D] bf16 attn partials
  short* Knb  = (short*)(ws + 3 * SZ);  // [2][16][2048][64] bf16
  short* xhi  = (short*)(ws + 4 * SZ);
  short* Vtb  = xhi + SZ;               // [2][16][64][64][32] bf16
  short* Wbig_hi = (short*)(ws + 5 * SZ);
  short* Wbig_lo = Wbig_hi + (size_t)3 * D_ * D_;
  float* gate  = (float*)Wbig_hi;                       // [BN] (post-QKV)
  float* lpart = gate + BN_;                            // [2][BN][16]
  short* WoH = Wbig_lo;                                 // [D][D] tiled
  float* F4  = (float*)(Wbig_lo + (size_t)D_ * D_);     // [4][1024]
  float* H5  = F4 + 4 * D_;                             // [1025][5]
  float* F4p = H5 + 1025 * 5;                           // [64][4][1024]

  const dim3 blk(256);

  // 1-3) gate-path algebra prep (rank-5 collapse), parallel grids
  fprep_p<<<dim3(4, 64), blk, 0, stream>>>(Wik, emb, F4p);
  freduce<<<dim3(16), blk, 0, stream>>>(F4p, F4);
  hprep2<<<dim3(1025), blk, 0, stream>>>(Wiq, F4, bik, biq, H5);

  // 4) weight prep (Wq,Wk,Wv,Wo) + x -> tiled bf16, ONE dispatch
  wsplitAll<<<dim3(16, 16, 8), blk, 0, stream>>>(
      Wq, Wk, Wv, Wo, x, Wbig_hi, WoH, xhi);

  // 5) fused QKV projection; Q-norm -> Qnb, K-norm -> Knb, V -> Vtb
  mfgemm2<6><<<dim3(8, 32, 3), blk, 0, stream>>>(
      xhi, Wbig_hi, bq, bk, bv,
      nullptr, Qnb, Knb, Vtb, qnw, knw, 8, 0, nullptr);

  // 6) attention, KV-split x2, KVBLK=64 -> bf16 partials
  attn3<<<dim3(N_ / 128, H_, B_ * 2), blk, 0, stream>>>(
      Qnb, Knb, Vtb, opart, lpart);

  // 7) combine partials -> o bf16 (over dead Qnb region), gate in-block
  attn_reduce2<<<BN_, blk, 0, stream>>>(opart, lpart, H5, mask, ohi, gate);

  // 8) final: gate[row]*(o@Wo) + bo -> d_out (plain bf16)
  mfgemm2<2><<<dim3(8, 32, 1), blk, 0, stream>>>(
      ohi, WoH, bo, nullptr, nullptr,
      out, nullptr, nullptr, nullptr, nullptr, nullptr, 0, 0, gate);
}